// Round 14
// baseline (475.405 us; speedup 1.0000x reference)
//
#include <hip/hip_runtime.h>
#include <hip/hip_bf16.h>
#include <math.h>

typedef unsigned short u16;
typedef __bf16 bf16x8_t __attribute__((ext_vector_type(8)));
typedef u16 u16x8 __attribute__((ext_vector_type(8)));
typedef u16 u16x4 __attribute__((ext_vector_type(4)));
typedef float f32x4 __attribute__((ext_vector_type(4)));

#define NH 12
#define LQ 2048
#define DM 768
#define DH 64
#define NR 4095           // 2L-1
#define LN2F 0.6931471805599453f

__device__ __forceinline__ u16 f2bf(float f){
  unsigned x = __float_as_uint(f);
  return (u16)((x + 0x7fffu + ((x >> 16) & 1u)) >> 16);   // RTNE
}
__device__ __forceinline__ float bf2f(u16 u){ return __uint_as_float(((unsigned)u) << 16); }

__device__ __forceinline__ f32x4 MFMA(u16x8 a, u16x8 b, f32x4 c){
  return __builtin_amdgcn_mfma_f32_16x16x32_bf16(
      __builtin_bit_cast(bf16x8_t, a), __builtin_bit_cast(bf16x8_t, b), c, 0, 0, 0);
}

// ---------------- gamma tables: logx[2048] f64, Cf[128] f64 ----------------
__global__ void gamma_tables_kernel(double* __restrict__ logx, double* __restrict__ Cf){
  int i = blockIdx.x * 256 + threadIdx.x;
  if (i < 2048) logx[i] = (i > 0) ? log((double)i) : 0.0;
  if (i < 128){
    double fp1 = (double)(i + 1);
    double conc = 4.0 * fp1 * fp1;
    double rate = 0.25 * fp1;
    Cf[i] = conc * log(rate) - lgamma(conc);
  }
}

// ---------------- gamma pdf table (unnormalized) + global max ----------------
__global__ void gamma_probs_kernel(const double* __restrict__ logx,
                                   const double* __restrict__ Cf,
                                   float* __restrict__ gamtab,
                                   unsigned long long* __restrict__ gmax){
  int idx = blockIdx.x * 256 + threadIdx.x;   // 2048*128
  int x = idx >> 7, f = idx & 127;
  double fp1 = (double)(f + 1);
  double conc = 4.0 * fp1 * fp1;
  double rate = 0.25 * fp1;
  double xl = (x > 0) ? (conc - 1.0) * logx[x] : 0.0;   // xlogy(a,0)=0
  double p = exp(xl - rate * (double)x + Cf[f]);
  gamtab[idx] = (float)p;
  double m = p;
  #pragma unroll
  for (int off = 1; off < 64; off <<= 1) m = fmax(m, __shfl_xor(m, off));
  if ((threadIdx.x & 63) == 0)
    atomicMax(gmax, (unsigned long long)__double_as_longlong(m));
}

// ---------------- positional encodings pe[4095][768] ----------------
__global__ void pe_kernel(const float* __restrict__ gamtab,
                          const unsigned long long* __restrict__ gmax,
                          float* __restrict__ pe){
  int idx = blockIdx.x * 256 + threadIdx.x;
  if (idx >= NR * DM) return;
  int p = idx / DM;
  int c = idx - p * DM;
  int f = c & 127;
  int kind = c >> 7;
  int pos = p - (LQ - 1);
  int apos = pos < 0 ? -pos : pos;
  float sgn = (pos > 0) ? 1.f : ((pos < 0) ? -1.f : 0.f);
  float v;
  int grp = kind >> 1;
  if (grp == 0){
    float hl = exp2f(3.f + 8.f * (float)f / 127.f);
    v = expf(-(LN2F / hl) * (float)apos);
  } else if (grp == 1){
    float cw = exp2f((float)(f + 1)) - 1.f;
    v = (cw > (float)apos) ? 1.f : 0.f;
  } else {
    float gm = (float)__longlong_as_double((long long)*gmax);
    v = gamtab[apos * 128 + f] / gm;
  }
  if (kind & 1) v *= sgn;
  pe[idx] = v;
}

// ---------------- 128x128-tile bf16 GEMM, BK=32 ----------------
// mode 0: outb bf16 head-major [(n>>6)*M + m][n&63], *scale
// mode 1: outf f32 flat [m*768+n] + bias (NT store)
// mode 2: outb bf16 transposed [(n>>6)*64 + (n&63)][2048] (vt)
#define ASTR 40   // u16 row stride (32 k + 8 pad); 80B rows, 16B-aligned
__launch_bounds__(256)
__global__ void gemm128_kernel(const float* __restrict__ A, const float* __restrict__ W,
                               u16* __restrict__ outb, float* __restrict__ outf,
                               const float* __restrict__ bias,
                               int M, float scale, int mode){
  __shared__ u16 At[128 * ASTR];
  __shared__ u16 Wt[128 * ASTR];
  const int m0 = blockIdx.x * 128, n0 = blockIdx.y * 128;
  const int tid = threadIdx.x;
  const int w = tid >> 6, l = tid & 63, lr = l & 15, lg = l >> 4;
  const int moff = (w & 1) * 64, noff = (w >> 1) * 64;
  f32x4 acc[4][4] = {};
  const int am = tid >> 2, akq = (tid & 3) * 8;      // A: rows am, am+64
  const int wn = tid & 127, wks = (tid >> 7) * 16;   // W: col n0+wn, k-seg
  const int wc0 = wks >> 3;                          // chunk 0 or 2
  const int wxr = (wn >> 3) & 3;                     // XOR swizzle key
  for (int k0 = 0; k0 < DM; k0 += 32){
    #pragma unroll
    for (int rr = 0; rr < 2; rr++){
      int m = m0 + am + rr * 64;
      u16x8 av;
      if (m < M){
        const float* ap = A + (size_t)m * DM + k0 + akq;
        #pragma unroll
        for (int j = 0; j < 8; j++) av[j] = f2bf(ap[j]);
      } else {
        #pragma unroll
        for (int j = 0; j < 8; j++) av[j] = 0;
      }
      *(u16x8*)&At[(am + rr * 64) * ASTR + akq] = av;
    }
    {
      u16x8 wv0, wv1;
      const float* wp = W + (size_t)(k0 + wks) * DM + n0 + wn;
      #pragma unroll
      for (int i = 0; i < 8; i++){
        wv0[i] = f2bf(wp[(size_t)i * DM]);
        wv1[i] = f2bf(wp[(size_t)(i + 8) * DM]);
      }
      *(u16x8*)&Wt[wn * ASTR + ((wc0) ^ wxr) * 8] = wv0;       // XOR-swizzled k-chunks
      *(u16x8*)&Wt[wn * ASTR + ((wc0 + 1) ^ wxr) * 8] = wv1;
    }
    __syncthreads();
    u16x8 af[4], bf[4];
    #pragma unroll
    for (int mi = 0; mi < 4; mi++)
      af[mi] = *(u16x8*)&At[(moff + mi * 16 + lr) * ASTR + lg * 8];
    #pragma unroll
    for (int ni = 0; ni < 4; ni++){
      int n = noff + ni * 16 + lr;
      bf[ni] = *(u16x8*)&Wt[n * ASTR + (lg ^ ((n >> 3) & 3)) * 8];
    }
    #pragma unroll
    for (int mi = 0; mi < 4; mi++)
      #pragma unroll
      for (int ni = 0; ni < 4; ni++)
        acc[mi][ni] = MFMA(af[mi], bf[ni], acc[mi][ni]);
    __syncthreads();
  }
  if (mode == 2){
    #pragma unroll
    for (int mi = 0; mi < 4; mi++)
      #pragma unroll
      for (int ni = 0; ni < 4; ni++){
        int m = m0 + moff + mi * 16 + lg * 4;
        int n = n0 + noff + ni * 16 + lr;
        u16x4 ov;
        #pragma unroll
        for (int j = 0; j < 4; j++) ov[j] = f2bf(acc[mi][ni][j]);
        *(u16x4*)(outb + ((size_t)(n >> 6) * DH + (n & 63)) * LQ + m) = ov;
      }
  } else if (mode == 0){
    #pragma unroll
    for (int mi = 0; mi < 4; mi++)
      #pragma unroll
      for (int ni = 0; ni < 4; ni++)
        #pragma unroll
        for (int j = 0; j < 4; j++){
          int m = m0 + moff + mi * 16 + lg * 4 + j;
          int n = n0 + noff + ni * 16 + lr;
          if (m < M)
            outb[((size_t)(n >> 6) * M + m) * DH + (n & 63)] = f2bf(acc[mi][ni][j] * scale);
        }
  } else {
    #pragma unroll
    for (int mi = 0; mi < 4; mi++)
      #pragma unroll
      for (int ni = 0; ni < 4; ni++)
        #pragma unroll
        for (int j = 0; j < 4; j++){
          int m = m0 + moff + mi * 16 + lg * 4 + j;
          int n = n0 + noff + ni * 16 + lr;
          if (m < M)
            __builtin_nontemporal_store(acc[mi][ni][j] + bias[n], &outf[(size_t)m * DM + n]);
        }
  }
}

// ---------------- fused rel-pos attention (r13, unchanged) ----------------
#define QB 16
#define SSTR 280
#define SLAB (QB * SSTR)                       // u16 per wave slab
#define SMEM_ATTN (8 * SLAB * 2 + 1024)
__launch_bounds__(512, 4)
__global__ void attn_kernel(const u16* __restrict__ qh, const u16* __restrict__ kh,
                            const u16* __restrict__ vt, const u16* __restrict__ rk,
                            const int* __restrict__ mask,
                            const float* __restrict__ r_w, const float* __restrict__ r_r,
                            float* __restrict__ map, float* __restrict__ att){
  extern __shared__ char smem[];
  u16* RP = (u16*)smem;                         // 8 slabs
  float* redm = (float*)(smem + 8 * SLAB * 2);  // [8][16]
  float* redl = redm + 128;                     // [8][16]
  const int bid = blockIdx.x;
  const int swz = (bid & 7) * 192 + (bid >> 3); // XCD-aware: same head per XCD
  const int h = swz >> 7, q0 = (swz & 127) * QB;
  const int tid = threadIdx.x, w = tid >> 6, l = tid & 63, lr = l & 15, lg = l >> 4;
  const int roff = (LQ - 1) - q0 - (QB - 1);    // 2032 - q0
  const int kb = w * 256;
  u16* slab = RP + w * SLAB;

  u16x8 a1[2], a2[2];
  #pragma unroll
  for (int kc = 0; kc < 2; kc++){
    u16x8 qv = *(const u16x8*)(qh + (size_t)(h * LQ + q0 + lr) * DH + kc * 32 + lg * 8);
    #pragma unroll
    for (int j = 0; j < 8; j++){
      int d = kc * 32 + lg * 8 + j;
      float f = bf2f(qv[j]);
      a1[kc][j] = f2bf(f + r_w[h * DH + d]);
      a2[kc][j] = f2bf(f + r_r[h * DH + d]);
    }
  }

  #pragma unroll 4
  for (int t = 0; t < 17; t++){
    int r = roff + kb + t * 16 + lr;
    if (r > NR - 1) r = NR - 1;
    const u16* rp = rk + (size_t)(h * NR + r) * DH + lg * 8;
    u16x8 b0 = *(const u16x8*)(rp);
    u16x8 b1 = *(const u16x8*)(rp + 32);
    f32x4 racc = {};
    racc = MFMA(a2[0], b0, racc);
    racc = MFMA(a2[1], b1, racc);
    #pragma unroll
    for (int j = 0; j < 4; j++)
      slab[(lg * 4 + j) * SSTR + t * 16 + lr] = f2bf(racc[j]);
  }
  __asm__ volatile("s_waitcnt lgkmcnt(0)" ::: "memory");
  __builtin_amdgcn_sched_barrier(0);

  f32x4 s[16];
  #pragma unroll
  for (int nt = 0; nt < 16; nt++){
    const u16* kp = kh + (size_t)(h * LQ + kb + nt * 16 + lr) * DH + lg * 8;
    u16x8 b0 = *(const u16x8*)(kp);
    u16x8 b1 = *(const u16x8*)(kp + 32);
    f32x4 sv = {};
    sv = MFMA(a1[0], b0, sv);
    sv = MFMA(a1[1], b1, sv);
    int mv = mask[kb + nt * 16 + lr];
    #pragma unroll
    for (int j = 0; j < 4; j++){
      int ql = lg * 4 + j;
      float x = sv[j] + bf2f(slab[ql * SSTR + nt * 16 + lr + 15 - ql]);
      sv[j] = (mv == 1) ? -10000.f : x;
    }
    s[nt] = sv;
  }

  float fm[4];
  #pragma unroll
  for (int j = 0; j < 4; j++){
    float mx = -3.0e38f;
    #pragma unroll
    for (int nt = 0; nt < 16; nt++) mx = fmaxf(mx, s[nt][j]);
    #pragma unroll
    for (int off = 1; off < 16; off <<= 1) mx = fmaxf(mx, __shfl_xor(mx, off));
    if (lr == 0) redm[w * QB + lg * 4 + j] = mx;
  }
  __syncthreads();
  #pragma unroll
  for (int j = 0; j < 4; j++){
    int ql = lg * 4 + j;
    float mx = redm[ql];
    #pragma unroll
    for (int w2 = 1; w2 < 8; w2++) mx = fmaxf(mx, redm[w2 * QB + ql]);
    fm[j] = mx;
  }

  float ls[4] = {0.f, 0.f, 0.f, 0.f};
  #pragma unroll
  for (int nt = 0; nt < 16; nt++)
    #pragma unroll
    for (int j = 0; j < 4; j++){
      float p = __expf(s[nt][j] - fm[j]);
      ls[j] += p;
      slab[(lg * 4 + j) * SSTR + nt * 16 + lr] = f2bf(p);
    }
  #pragma unroll
  for (int j = 0; j < 4; j++){
    float sum = ls[j];
    #pragma unroll
    for (int off = 1; off < 16; off <<= 1) sum += __shfl_xor(sum, off);
    if (lr == 0) redl[w * QB + lg * 4 + j] = sum;
  }
  __syncthreads();
  float inv[4];
  #pragma unroll
  for (int j = 0; j < 4; j++){
    int ql = lg * 4 + j;
    float d = redl[ql];
    #pragma unroll
    for (int w2 = 1; w2 < 8; w2++) d += redl[w2 * QB + ql];
    inv[j] = 1.f / d;
  }

  {
    int qrow = tid >> 5, cb = (tid & 31) * 8;
    float dsum = redl[qrow];
    #pragma unroll
    for (int w2 = 1; w2 < 8; w2++) dsum += redl[w2 * QB + qrow];
    float invr = 1.f / dsum;
    float* mrow = map + (size_t)(h * LQ + q0 + qrow) * LQ;
    #pragma unroll
    for (int it = 0; it < 8; it++){
      u16x8 pv = *(u16x8*)&RP[it * SLAB + qrow * SSTR + cb];
      f32x4 o0, o1;
      #pragma unroll
      for (int j = 0; j < 4; j++){
        o0[j] = bf2f(pv[j]) * invr;
        o1[j] = bf2f(pv[4 + j]) * invr;
      }
      int c = cb + it * 256;
      __builtin_nontemporal_store(o0, (f32x4*)(mrow + c));
      __builtin_nontemporal_store(o1, (f32x4*)(mrow + c + 4));
    }
  }

  f32x4 o[4] = {};
  #pragma unroll
  for (int kc2 = 0; kc2 < 8; kc2++){
    u16x8 pa = *(u16x8*)&slab[lr * SSTR + kc2 * 32 + lg * 8];
    #pragma unroll
    for (int ni = 0; ni < 4; ni++){
      u16x8 vv = *(const u16x8*)(vt + (size_t)(h * DH + ni * 16 + lr) * LQ + kb + kc2 * 32 + lg * 8);
      o[ni] = MFMA(pa, vv, o[ni]);
    }
  }
  __syncthreads();

  float* Op = (float*)smem;    // [8][16][64]
  #pragma unroll
  for (int ni = 0; ni < 4; ni++)
    #pragma unroll
    for (int j = 0; j < 4; j++)
      Op[(w * QB + lg * 4 + j) * 64 + ni * 16 + lr] = o[ni][j] * inv[j];
  __syncthreads();
  {
    int q = tid >> 5, dg = (tid & 31) * 2;
    float acc0 = 0.f, acc1 = 0.f;
    #pragma unroll
    for (int w2 = 0; w2 < 8; w2++){
      acc0 += Op[(w2 * QB + q) * 64 + dg];
      acc1 += Op[(w2 * QB + q) * 64 + dg + 1];
    }
    float* ap = att + (size_t)(q0 + q) * DM + h * DH + dg;
    ap[0] = acc0;
    ap[1] = acc1;
  }
}

extern "C" void kernel_launch(void* const* d_in, const int* in_sizes, int n_in,
                              void* d_out, int out_size, void* d_ws, size_t ws_size,
                              hipStream_t stream){
  const float* v_in = (const float*)d_in[0];
  const float* k_in = (const float*)d_in[1];
  const float* q_in = (const float*)d_in[2];
  const int*   mask = (const int*)d_in[3];
  const float* Wq   = (const float*)d_in[4];
  const float* Wk   = (const float*)d_in[5];
  const float* Wv   = (const float*)d_in[6];
  const float* Wrk  = (const float*)d_in[7];
  const float* r_w  = (const float*)d_in[8];
  const float* r_r  = (const float*)d_in[9];
  const float* Wo   = (const float*)d_in[10];
  const float* bo   = (const float*)d_in[11];

  char* ws = (char*)d_ws;
  u16* qh = (u16*)(ws + 0);              // [12][2048][64] bf16
  u16* kh = (u16*)(ws + 3145728);
  u16* vt = (u16*)(ws + 6291456);        // [12][64][2048] bf16
  u16* rk = (u16*)(ws + 9437184);        // [12][4095][64] bf16
  float* pe = (float*)(ws + 15727104);   // [4095][768] f32
  float* att = (float*)(ws + 28306944);  // [2048][768] f32
  float* gamtab = (float*)(ws + 34598400);           // [2048][128] f32
  unsigned long long* gmax = (unsigned long long*)(ws + 35646976);
  double* logx = (double*)(ws + 35647040);           // [2048] f64
  double* Cf   = (double*)(ws + 35663424);           // [128] f64

  float* out0 = (float*)d_out;                     // [2048][768] f32
  float* map  = out0 + (size_t)LQ * DM;            // [12][2048][2048] f32

  hipMemsetAsync(gmax, 0, 8, stream);
  gamma_tables_kernel<<<8, 256, 0, stream>>>(logx, Cf);
  gamma_probs_kernel<<<1024, 256, 0, stream>>>(logx, Cf, gamtab, gmax);
  pe_kernel<<<(NR * DM + 255) / 256, 256, 0, stream>>>(gamtab, gmax, pe);

  gemm128_kernel<<<dim3(16, 6), 256, 0, stream>>>(q_in, Wq, qh, nullptr, nullptr, LQ, 0.125f, 0);
  gemm128_kernel<<<dim3(16, 6), 256, 0, stream>>>(k_in, Wk, kh, nullptr, nullptr, LQ, 1.f, 0);
  gemm128_kernel<<<dim3(16, 6), 256, 0, stream>>>(v_in, Wv, vt, nullptr, nullptr, LQ, 1.f, 2);
  gemm128_kernel<<<dim3(32, 6), 256, 0, stream>>>(pe, Wrk, rk, nullptr, nullptr, NR, 1.f, 0);

  hipFuncSetAttribute((const void*)attn_kernel,
                      hipFuncAttributeMaxDynamicSharedMemorySize, SMEM_ATTN);
  attn_kernel<<<dim3((LQ / QB) * NH), 512, SMEM_ATTN, stream>>>(qh, kh, vt, rk, mask,
                                                                r_w, r_r, map, att);
  gemm128_kernel<<<dim3(16, 6), 256, 0, stream>>>(att, Wo, nullptr, out0, bo, LQ, 1.f, 1);
}

// Round 15
// 380.445 us; speedup vs baseline: 1.2496x; 1.2496x over previous
//
#include <hip/hip_runtime.h>
#include <hip/hip_bf16.h>
#include <math.h>

typedef unsigned short u16;
typedef __bf16 bf16x8_t __attribute__((ext_vector_type(8)));
typedef u16 u16x8 __attribute__((ext_vector_type(8)));
typedef u16 u16x4 __attribute__((ext_vector_type(4)));
typedef float f32x4 __attribute__((ext_vector_type(4)));

#define NH 12
#define LQ 2048
#define DM 768
#define DH 64
#define NR 4095           // 2L-1
#define LN2F 0.6931471805599453f

__device__ __forceinline__ u16 f2bf(float f){
  unsigned x = __float_as_uint(f);
  return (u16)((x + 0x7fffu + ((x >> 16) & 1u)) >> 16);   // RTNE
}
__device__ __forceinline__ float bf2f(u16 u){ return __uint_as_float(((unsigned)u) << 16); }

__device__ __forceinline__ f32x4 MFMA(u16x8 a, u16x8 b, f32x4 c){
  return __builtin_amdgcn_mfma_f32_16x16x32_bf16(
      __builtin_bit_cast(bf16x8_t, a), __builtin_bit_cast(bf16x8_t, b), c, 0, 0, 0);
}

// ---------------- gamma tables: logx[2048] f64, Cf[128] f64 ----------------
__global__ void gamma_tables_kernel(double* __restrict__ logx, double* __restrict__ Cf){
  int i = blockIdx.x * 256 + threadIdx.x;
  if (i < 2048) logx[i] = (i > 0) ? log((double)i) : 0.0;
  if (i < 128){
    double fp1 = (double)(i + 1);
    double conc = 4.0 * fp1 * fp1;
    double rate = 0.25 * fp1;
    Cf[i] = conc * log(rate) - lgamma(conc);
  }
}

// ---------------- gamma pdf table (unnormalized) + global max ----------------
__global__ void gamma_probs_kernel(const double* __restrict__ logx,
                                   const double* __restrict__ Cf,
                                   float* __restrict__ gamtab,
                                   unsigned long long* __restrict__ gmax){
  int idx = blockIdx.x * 256 + threadIdx.x;   // 2048*128
  int x = idx >> 7, f = idx & 127;
  double fp1 = (double)(f + 1);
  double conc = 4.0 * fp1 * fp1;
  double rate = 0.25 * fp1;
  double xl = (x > 0) ? (conc - 1.0) * logx[x] : 0.0;   // xlogy(a,0)=0
  double p = exp(xl - rate * (double)x + Cf[f]);
  gamtab[idx] = (float)p;
  double m = p;
  #pragma unroll
  for (int off = 1; off < 64; off <<= 1) m = fmax(m, __shfl_xor(m, off));
  if ((threadIdx.x & 63) == 0)
    atomicMax(gmax, (unsigned long long)__double_as_longlong(m));
}

// ---------------- positional encodings -> bf16 peb[4095][768] ----------------
__global__ void pe_kernel(const float* __restrict__ gamtab,
                          const unsigned long long* __restrict__ gmax,
                          u16* __restrict__ peb){
  int idx = blockIdx.x * 256 + threadIdx.x;
  if (idx >= NR * DM) return;
  int p = idx / DM;
  int c = idx - p * DM;
  int f = c & 127;
  int kind = c >> 7;
  int pos = p - (LQ - 1);
  int apos = pos < 0 ? -pos : pos;
  float sgn = (pos > 0) ? 1.f : ((pos < 0) ? -1.f : 0.f);
  float v;
  int grp = kind >> 1;
  if (grp == 0){
    float hl = exp2f(3.f + 8.f * (float)f / 127.f);
    v = expf(-(LN2F / hl) * (float)apos);
  } else if (grp == 1){
    float cw = exp2f((float)(f + 1)) - 1.f;
    v = (cw > (float)apos) ? 1.f : 0.f;
  } else {
    float gm = (float)__longlong_as_double((long long)*gmax);
    v = gamtab[apos * 128 + f] / gm;
  }
  if (kind & 1) v *= sgn;
  peb[idx] = f2bf(v);
}

// ---------------- batched f32 -> bf16 convert (grid.z picks tensor) ----------
__global__ void cvt_kernel(const float* s0, const float* s1, const float* s2,
                           const float* s3, const float* s4, const float* s5,
                           const float* s6, const float* s7,
                           u16* d0, u16* d1, u16* d2, u16* d3,
                           u16* d4, u16* d5, u16* d6, u16* d7){
  const int z = blockIdx.z;
  const float* src = (z==0)?s0:(z==1)?s1:(z==2)?s2:(z==3)?s3:(z==4)?s4:(z==5)?s5:(z==6)?s6:s7;
  u16* dst = (z==0)?d0:(z==1)?d1:(z==2)?d2:(z==3)?d3:(z==4)?d4:(z==5)?d5:(z==6)?d6:d7;
  int n = (z < 3) ? (LQ * DM) : (DM * DM);
  int base = (blockIdx.x * 256 + threadIdx.x) * 8;
  if (base >= n) return;
  f32x4 a = *(const f32x4*)(src + base);
  f32x4 b = *(const f32x4*)(src + base + 4);
  u16x8 o;
  #pragma unroll
  for (int j = 0; j < 4; j++){ o[j] = f2bf(a[j]); o[4 + j] = f2bf(b[j]); }
  *(u16x8*)(dst + base) = o;
}

// ---------------- 64x64-tile bf16-input GEMM ----------------
// mode 0: outb bf16 head-major [(n>>6)*M + m][n&63], *scale
// mode 1: outf f32 flat [m*768+n] + bias (NT)
// mode 2: outb bf16 transposed vt [(n>>6)*64 + (n&63)][2048]
#define GSTR 56
__launch_bounds__(256)
__global__ void gemm_kernel(const u16* __restrict__ A, const u16* __restrict__ W,
                            u16* __restrict__ outb, float* __restrict__ outf,
                            int M, float scale,
                            const float* __restrict__ bias, int mode){
  __shared__ u16 At[64 * GSTR];
  __shared__ u16 Wt[64 * GSTR];
  const int m0 = blockIdx.x * 64, n0 = blockIdx.y * 64;
  const int tid = threadIdx.x;
  const int w = tid >> 6, l = tid & 63, lr = l & 15, lg = l >> 4;
  const int moff = (w & 1) * 32, noff = (w >> 1) * 32;
  f32x4 acc[2][2] = {};
  const int arow = tid >> 2, akg = (tid & 3) * 8;
  const int wn = tid & 63, wkg = (tid >> 6) * 8;
  for (int k0 = 0; k0 < DM; k0 += 32){
    u16x8 av = {};
    if (m0 + arow < M)
      av = *(const u16x8*)(A + (size_t)(m0 + arow) * DM + k0 + akg);
    *(u16x8*)&At[arow * GSTR + akg] = av;
    u16x8 wv;
    #pragma unroll
    for (int i = 0; i < 8; i++)
      wv[i] = W[(size_t)(k0 + wkg + i) * DM + n0 + wn];
    *(u16x8*)&Wt[wn * GSTR + wkg] = wv;
    __syncthreads();
    u16x8 af0 = *(u16x8*)&At[(moff + lr) * GSTR + lg * 8];
    u16x8 af1 = *(u16x8*)&At[(moff + 16 + lr) * GSTR + lg * 8];
    u16x8 bf0 = *(u16x8*)&Wt[(noff + lr) * GSTR + lg * 8];
    u16x8 bf1 = *(u16x8*)&Wt[(noff + 16 + lr) * GSTR + lg * 8];
    acc[0][0] = MFMA(af0, bf0, acc[0][0]);
    acc[0][1] = MFMA(af0, bf1, acc[0][1]);
    acc[1][0] = MFMA(af1, bf0, acc[1][0]);
    acc[1][1] = MFMA(af1, bf1, acc[1][1]);
    __syncthreads();
  }
  if (mode == 2){
    #pragma unroll
    for (int mi = 0; mi < 2; mi++)
      #pragma unroll
      for (int ni = 0; ni < 2; ni++){
        int m = m0 + moff + mi * 16 + lg * 4;
        int n = n0 + noff + ni * 16 + lr;
        u16x4 ov;
        #pragma unroll
        for (int j = 0; j < 4; j++) ov[j] = f2bf(acc[mi][ni][j]);
        *(u16x4*)(outb + ((size_t)(n >> 6) * DH + (n & 63)) * LQ + m) = ov;
      }
  } else {
    #pragma unroll
    for (int mi = 0; mi < 2; mi++)
      #pragma unroll
      for (int ni = 0; ni < 2; ni++)
        #pragma unroll
        for (int j = 0; j < 4; j++){
          int m = m0 + moff + mi * 16 + lg * 4 + j;
          int n = n0 + noff + ni * 16 + lr;
          if (m < M){
            float v = acc[mi][ni][j] * scale;
            if (mode == 1)
              __builtin_nontemporal_store(v + bias[n], &outf[(size_t)m * DM + n]);
            else
              outb[((size_t)(n >> 6) * M + m) * DH + (n & 63)] = f2bf(v);
          }
        }
  }
}

// ---------------- fused rel-pos attention: NORMALIZED P export (bf16) --------
// r13 structure; P now fully normalized in-slab (inv folded into 2nd exp pass),
// exported bf16 to Pbuf (100 MB) instead of f32 map (201 MB). Map produced by
// the standalone expand kernel (pure stream — measures the write ceiling).
#define QB 16
#define SSTR 280
#define SLAB (QB * SSTR)
#define SMEM_ATTN (8 * SLAB * 2 + 1024)
__launch_bounds__(512, 4)
__global__ void attn_kernel(const u16* __restrict__ qh, const u16* __restrict__ kh,
                            const u16* __restrict__ vt, const u16* __restrict__ rk,
                            const int* __restrict__ mask,
                            const float* __restrict__ r_w, const float* __restrict__ r_r,
                            u16* __restrict__ Pbuf, u16* __restrict__ att){
  extern __shared__ char smem[];
  u16* RP = (u16*)smem;
  float* redm = (float*)(smem + 8 * SLAB * 2);
  float* redl = redm + 128;
  const int bid = blockIdx.x;
  const int swz = (bid & 7) * 192 + (bid >> 3);
  const int h = swz >> 7, q0 = (swz & 127) * QB;
  const int tid = threadIdx.x, w = tid >> 6, l = tid & 63, lr = l & 15, lg = l >> 4;
  const int roff = (LQ - 1) - q0 - (QB - 1);
  const int kb = w * 256;
  u16* slab = RP + w * SLAB;

  u16x8 a1[2], a2[2];
  #pragma unroll
  for (int kc = 0; kc < 2; kc++){
    u16x8 qv = *(const u16x8*)(qh + (size_t)(h * LQ + q0 + lr) * DH + kc * 32 + lg * 8);
    #pragma unroll
    for (int j = 0; j < 8; j++){
      int d = kc * 32 + lg * 8 + j;
      float f = bf2f(qv[j]);
      a1[kc][j] = f2bf(f + r_w[h * DH + d]);
      a2[kc][j] = f2bf(f + r_r[h * DH + d]);
    }
  }

  #pragma unroll 4
  for (int t = 0; t < 17; t++){
    int r = roff + kb + t * 16 + lr;
    if (r > NR - 1) r = NR - 1;
    const u16* rp = rk + (size_t)(h * NR + r) * DH + lg * 8;
    u16x8 b0 = *(const u16x8*)(rp);
    u16x8 b1 = *(const u16x8*)(rp + 32);
    f32x4 racc = {};
    racc = MFMA(a2[0], b0, racc);
    racc = MFMA(a2[1], b1, racc);
    #pragma unroll
    for (int j = 0; j < 4; j++)
      slab[(lg * 4 + j) * SSTR + t * 16 + lr] = f2bf(racc[j]);
  }
  __asm__ volatile("s_waitcnt lgkmcnt(0)" ::: "memory");
  __builtin_amdgcn_sched_barrier(0);

  f32x4 s[16];
  #pragma unroll
  for (int nt = 0; nt < 16; nt++){
    const u16* kp = kh + (size_t)(h * LQ + kb + nt * 16 + lr) * DH + lg * 8;
    u16x8 b0 = *(const u16x8*)(kp);
    u16x8 b1 = *(const u16x8*)(kp + 32);
    f32x4 sv = {};
    sv = MFMA(a1[0], b0, sv);
    sv = MFMA(a1[1], b1, sv);
    int mv = mask[kb + nt * 16 + lr];
    #pragma unroll
    for (int j = 0; j < 4; j++){
      int ql = lg * 4 + j;
      float x = sv[j] + bf2f(slab[ql * SSTR + nt * 16 + lr + 15 - ql]);
      sv[j] = (mv == 1) ? -10000.f : x;
    }
    s[nt] = sv;
  }

  float fm[4];
  #pragma unroll
  for (int j = 0; j < 4; j++){
    float mx = -3.0e38f;
    #pragma unroll
    for (int nt = 0; nt < 16; nt++) mx = fmaxf(mx, s[nt][j]);
    #pragma unroll
    for (int off = 1; off < 16; off <<= 1) mx = fmaxf(mx, __shfl_xor(mx, off));
    if (lr == 0) redm[w * QB + lg * 4 + j] = mx;
  }
  __syncthreads();
  #pragma unroll
  for (int j = 0; j < 4; j++){
    int ql = lg * 4 + j;
    float mx = redm[ql];
    #pragma unroll
    for (int w2 = 1; w2 < 8; w2++) mx = fmaxf(mx, redm[w2 * QB + ql]);
    fm[j] = mx;
  }

  // pass 1: sums only (no store)
  float ls[4] = {0.f, 0.f, 0.f, 0.f};
  #pragma unroll
  for (int nt = 0; nt < 16; nt++)
    #pragma unroll
    for (int j = 0; j < 4; j++)
      ls[j] += __expf(s[nt][j] - fm[j]);
  #pragma unroll
  for (int j = 0; j < 4; j++){
    float sum = ls[j];
    #pragma unroll
    for (int off = 1; off < 16; off <<= 1) sum += __shfl_xor(sum, off);
    if (lr == 0) redl[w * QB + lg * 4 + j] = sum;
  }
  __syncthreads();
  float inv[4];
  #pragma unroll
  for (int j = 0; j < 4; j++){
    int ql = lg * 4 + j;
    float d = redl[ql];
    #pragma unroll
    for (int w2 = 1; w2 < 8; w2++) d += redl[w2 * QB + ql];
    inv[j] = 1.f / d;
  }

  // pass 2: normalized P -> own slab
  #pragma unroll
  for (int nt = 0; nt < 16; nt++)
    #pragma unroll
    for (int j = 0; j < 4; j++)
      slab[(lg * 4 + j) * SSTR + nt * 16 + lr] = f2bf(__expf(s[nt][j] - fm[j]) * inv[j]);

  // PV with normalized P (own slab; in-wave lgkmcnt ordering)
  f32x4 o[4] = {};
  #pragma unroll
  for (int kc2 = 0; kc2 < 8; kc2++){
    u16x8 pa = *(u16x8*)&slab[lr * SSTR + kc2 * 32 + lg * 8];
    #pragma unroll
    for (int ni = 0; ni < 4; ni++){
      u16x8 vv = *(const u16x8*)(vt + (size_t)(h * DH + ni * 16 + lr) * LQ + kb + kc2 * 32 + lg * 8);
      o[ni] = MFMA(pa, vv, o[ni]);
    }
  }
  __syncthreads();                      // all waves' P final

  // export normalized P (bf16, NT) — cross-slab reads
  {
    int qrow = tid >> 5, cb = (tid & 31) * 8;
    u16* prow = Pbuf + (size_t)(h * LQ + q0 + qrow) * LQ;
    #pragma unroll
    for (int it = 0; it < 8; it++){
      u16x8 pv = *(u16x8*)&RP[it * SLAB + qrow * SSTR + cb];
      __builtin_nontemporal_store(pv, (u16x8*)(prow + cb + it * 256));
    }
  }
  __syncthreads();                      // export LDS-reads done before Op overwrite

  float* Op = (float*)smem;             // [8][16][64] overlays slabs
  #pragma unroll
  for (int ni = 0; ni < 4; ni++)
    #pragma unroll
    for (int j = 0; j < 4; j++)
      Op[(w * QB + lg * 4 + j) * 64 + ni * 16 + lr] = o[ni][j];
  __syncthreads();
  {
    int q = tid >> 5, dg = (tid & 31) * 2;
    float acc0 = 0.f, acc1 = 0.f;
    #pragma unroll
    for (int w2 = 0; w2 < 8; w2++){
      acc0 += Op[(w2 * QB + q) * 64 + dg];
      acc1 += Op[(w2 * QB + q) * 64 + dg + 1];
    }
    unsigned pk = (unsigned)f2bf(acc0) | ((unsigned)f2bf(acc1) << 16);
    *(unsigned*)(att + (size_t)(q0 + q) * DM + h * DH + dg) = pk;
  }
}

// ---------------- expand: map f32 = bf2f(Pbuf bf16) — pure stream ----------
__global__ void expand_kernel(const u16* __restrict__ Pbuf, float* __restrict__ map){
  size_t base = ((size_t)blockIdx.x * 256 + threadIdx.x) * 8;
  u16x8 pv = *(const u16x8*)(Pbuf + base);
  f32x4 o0, o1;
  #pragma unroll
  for (int j = 0; j < 4; j++){ o0[j] = bf2f(pv[j]); o1[j] = bf2f(pv[4 + j]); }
  __builtin_nontemporal_store(o0, (f32x4*)(map + base));
  __builtin_nontemporal_store(o1, (f32x4*)(map + base + 4));
}

extern "C" void kernel_launch(void* const* d_in, const int* in_sizes, int n_in,
                              void* d_out, int out_size, void* d_ws, size_t ws_size,
                              hipStream_t stream){
  const float* v_in = (const float*)d_in[0];
  const float* k_in = (const float*)d_in[1];
  const float* q_in = (const float*)d_in[2];
  const int*   mask = (const int*)d_in[3];
  const float* Wq   = (const float*)d_in[4];
  const float* Wk   = (const float*)d_in[5];
  const float* Wv   = (const float*)d_in[6];
  const float* Wrk  = (const float*)d_in[7];
  const float* r_w  = (const float*)d_in[8];
  const float* r_r  = (const float*)d_in[9];
  const float* Wo   = (const float*)d_in[10];
  const float* bo   = (const float*)d_in[11];

  char* ws = (char*)d_ws;
  u16* qh  = (u16*)(ws + 0);             // [12][2048][64] bf16
  u16* kh  = (u16*)(ws + 3145728);
  u16* vt  = (u16*)(ws + 6291456);       // [12][64][2048] bf16
  u16* rk  = (u16*)(ws + 9437184);       // [12][4095][64] bf16
  u16* qb  = (u16*)(ws + 15727104);      // [2048][768] bf16 inputs
  u16* kb  = (u16*)(ws + 18872832);
  u16* vb  = (u16*)(ws + 22018560);
  u16* Wqb = (u16*)(ws + 25165824);      // [768][768] bf16 weights
  u16* Wkb = (u16*)(ws + 26345472);
  u16* Wvb = (u16*)(ws + 27525120);
  u16* Wrkb= (u16*)(ws + 28704768);
  u16* Wob = (u16*)(ws + 29884416);
  u16* peb = (u16*)(ws + 31064064);      // [4095][768] bf16
  u16* att = (u16*)(ws + 37353984);      // [2048][768] bf16
  float* gamtab = (float*)(ws + 40499712);
  unsigned long long* gmax = (unsigned long long*)(ws + 41548288);
  double* logx = (double*)(ws + 41548352);
  double* Cf   = (double*)(ws + 41564736);
  u16* Pbuf = (u16*)(ws + 41943040);     // [12][2048][2048] bf16 (100.7 MB)

  float* out0 = (float*)d_out;                     // [2048][768] f32
  float* map  = out0 + (size_t)LQ * DM;            // [12][2048][2048] f32

  hipMemsetAsync(gmax, 0, 8, stream);
  gamma_tables_kernel<<<8, 256, 0, stream>>>(logx, Cf);
  gamma_probs_kernel<<<1024, 256, 0, stream>>>(logx, Cf, gamtab, gmax);
  pe_kernel<<<(NR * DM + 255) / 256, 256, 0, stream>>>(gamtab, gmax, peb);

  cvt_kernel<<<dim3(768, 1, 8), 256, 0, stream>>>(q_in, k_in, v_in, Wq, Wk, Wv, Wrk, Wo,
                                                  qb, kb, vb, Wqb, Wkb, Wvb, Wrkb, Wob);

  gemm_kernel<<<dim3(32, 12), 256, 0, stream>>>(qb, Wqb, qh, nullptr, LQ, 0.125f, nullptr, 0);
  gemm_kernel<<<dim3(32, 12), 256, 0, stream>>>(kb, Wkb, kh, nullptr, LQ, 1.f, nullptr, 0);
  gemm_kernel<<<dim3(32, 12), 256, 0, stream>>>(vb, Wvb, vt, nullptr, LQ, 1.f, nullptr, 2);
  gemm_kernel<<<dim3(64, 12), 256, 0, stream>>>(peb, Wrkb, rk, nullptr, NR, 1.f, nullptr, 0);

  hipFuncSetAttribute((const void*)attn_kernel,
                      hipFuncAttributeMaxDynamicSharedMemorySize, SMEM_ATTN);
  attn_kernel<<<dim3((LQ / QB) * NH), 512, SMEM_ATTN, stream>>>(qh, kh, vt, rk, mask,
                                                                r_w, r_r, Pbuf, att);
  gemm_kernel<<<dim3(32, 12), 256, 0, stream>>>(att, Wob, nullptr, out0, LQ, 1.f, bo, 1);
  expand_kernel<<<(NH * LQ * LQ) / (256 * 8), 256, 0, stream>>>(Pbuf, map);
}

// Round 16
// 353.278 us; speedup vs baseline: 1.3457x; 1.0769x over previous
//
#include <hip/hip_runtime.h>
#include <hip/hip_bf16.h>
#include <math.h>

typedef unsigned short u16;
typedef __bf16 bf16x8_t __attribute__((ext_vector_type(8)));
typedef u16 u16x8 __attribute__((ext_vector_type(8)));
typedef u16 u16x4 __attribute__((ext_vector_type(4)));
typedef float f32x4 __attribute__((ext_vector_type(4)));

#define NH 12
#define LQ 2048
#define DM 768
#define DH 64
#define NR 4095           // 2L-1
#define LN2F 0.6931471805599453f

__device__ __forceinline__ u16 f2bf(float f){
  unsigned x = __float_as_uint(f);
  return (u16)((x + 0x7fffu + ((x >> 16) & 1u)) >> 16);   // RTNE
}
__device__ __forceinline__ float bf2f(u16 u){ return __uint_as_float(((unsigned)u) << 16); }

__device__ __forceinline__ f32x4 MFMA(u16x8 a, u16x8 b, f32x4 c){
  return __builtin_amdgcn_mfma_f32_16x16x32_bf16(
      __builtin_bit_cast(bf16x8_t, a), __builtin_bit_cast(bf16x8_t, b), c, 0, 0, 0);
}

// ---------------- gamma tables: logx[2048] f64, Cf[128] f64 ----------------
__global__ void gamma_tables_kernel(double* __restrict__ logx, double* __restrict__ Cf){
  int i = blockIdx.x * 256 + threadIdx.x;
  if (i < 2048) logx[i] = (i > 0) ? log((double)i) : 0.0;
  if (i < 128){
    double fp1 = (double)(i + 1);
    double conc = 4.0 * fp1 * fp1;
    double rate = 0.25 * fp1;
    Cf[i] = conc * log(rate) - lgamma(conc);
  }
}

// ---------------- gamma pdf table (unnormalized) + global max ----------------
__global__ void gamma_probs_kernel(const double* __restrict__ logx,
                                   const double* __restrict__ Cf,
                                   float* __restrict__ gamtab,
                                   unsigned long long* __restrict__ gmax){
  int idx = blockIdx.x * 256 + threadIdx.x;   // 2048*128
  int x = idx >> 7, f = idx & 127;
  double fp1 = (double)(f + 1);
  double conc = 4.0 * fp1 * fp1;
  double rate = 0.25 * fp1;
  double xl = (x > 0) ? (conc - 1.0) * logx[x] : 0.0;   // xlogy(a,0)=0
  double p = exp(xl - rate * (double)x + Cf[f]);
  gamtab[idx] = (float)p;
  double m = p;
  #pragma unroll
  for (int off = 1; off < 64; off <<= 1) m = fmax(m, __shfl_xor(m, off));
  if ((threadIdx.x & 63) == 0)
    atomicMax(gmax, (unsigned long long)__double_as_longlong(m));
}

// ---------------- positional encodings -> bf16 peb[4095][768] ----------------
__global__ void pe_kernel(const float* __restrict__ gamtab,
                          const unsigned long long* __restrict__ gmax,
                          u16* __restrict__ peb){
  int idx = blockIdx.x * 256 + threadIdx.x;
  if (idx >= NR * DM) return;
  int p = idx / DM;
  int c = idx - p * DM;
  int f = c & 127;
  int kind = c >> 7;
  int pos = p - (LQ - 1);
  int apos = pos < 0 ? -pos : pos;
  float sgn = (pos > 0) ? 1.f : ((pos < 0) ? -1.f : 0.f);
  float v;
  int grp = kind >> 1;
  if (grp == 0){
    float hl = exp2f(3.f + 8.f * (float)f / 127.f);
    v = expf(-(LN2F / hl) * (float)apos);
  } else if (grp == 1){
    float cw = exp2f((float)(f + 1)) - 1.f;
    v = (cw > (float)apos) ? 1.f : 0.f;
  } else {
    float gm = (float)__longlong_as_double((long long)*gmax);
    v = gamtab[apos * 128 + f] / gm;
  }
  if (kind & 1) v *= sgn;
  peb[idx] = f2bf(v);
}

// ---------------- batched f32 -> bf16 convert (grid.z picks tensor) ----------
__global__ void cvt_kernel(const float* s0, const float* s1, const float* s2,
                           const float* s3, const float* s4, const float* s5,
                           const float* s6, const float* s7,
                           u16* d0, u16* d1, u16* d2, u16* d3,
                           u16* d4, u16* d5, u16* d6, u16* d7){
  const int z = blockIdx.z;
  const float* src = (z==0)?s0:(z==1)?s1:(z==2)?s2:(z==3)?s3:(z==4)?s4:(z==5)?s5:(z==6)?s6:s7;
  u16* dst = (z==0)?d0:(z==1)?d1:(z==2)?d2:(z==3)?d3:(z==4)?d4:(z==5)?d5:(z==6)?d6:d7;
  int n = (z < 3) ? (LQ * DM) : (DM * DM);
  int base = (blockIdx.x * 256 + threadIdx.x) * 8;
  if (base >= n) return;
  f32x4 a = *(const f32x4*)(src + base);
  f32x4 b = *(const f32x4*)(src + base + 4);
  u16x8 o;
  #pragma unroll
  for (int j = 0; j < 4; j++){ o[j] = f2bf(a[j]); o[4 + j] = f2bf(b[j]); }
  *(u16x8*)(dst + base) = o;
}

// ---------------- 64x64-tile bf16-input GEMM ----------------
// mode 0: outb bf16 head-major [(n>>6)*M + m][n&63], *scale
// mode 1: outf f32 flat [m*768+n] + bias (NT)
// mode 2: outb bf16 transposed vt [(n>>6)*64 + (n&63)][2048]
#define GSTR 56
__launch_bounds__(256)
__global__ void gemm_kernel(const u16* __restrict__ A, const u16* __restrict__ W,
                            u16* __restrict__ outb, float* __restrict__ outf,
                            int M, float scale,
                            const float* __restrict__ bias, int mode){
  __shared__ u16 At[64 * GSTR];
  __shared__ u16 Wt[64 * GSTR];
  const int m0 = blockIdx.x * 64, n0 = blockIdx.y * 64;
  const int tid = threadIdx.x;
  const int w = tid >> 6, l = tid & 63, lr = l & 15, lg = l >> 4;
  const int moff = (w & 1) * 32, noff = (w >> 1) * 32;
  f32x4 acc[2][2] = {};
  const int arow = tid >> 2, akg = (tid & 3) * 8;
  const int wn = tid & 63, wkg = (tid >> 6) * 8;
  for (int k0 = 0; k0 < DM; k0 += 32){
    u16x8 av = {};
    if (m0 + arow < M)
      av = *(const u16x8*)(A + (size_t)(m0 + arow) * DM + k0 + akg);
    *(u16x8*)&At[arow * GSTR + akg] = av;
    u16x8 wv;
    #pragma unroll
    for (int i = 0; i < 8; i++)
      wv[i] = W[(size_t)(k0 + wkg + i) * DM + n0 + wn];
    *(u16x8*)&Wt[wn * GSTR + wkg] = wv;
    __syncthreads();
    u16x8 af0 = *(u16x8*)&At[(moff + lr) * GSTR + lg * 8];
    u16x8 af1 = *(u16x8*)&At[(moff + 16 + lr) * GSTR + lg * 8];
    u16x8 bf0 = *(u16x8*)&Wt[(noff + lr) * GSTR + lg * 8];
    u16x8 bf1 = *(u16x8*)&Wt[(noff + 16 + lr) * GSTR + lg * 8];
    acc[0][0] = MFMA(af0, bf0, acc[0][0]);
    acc[0][1] = MFMA(af0, bf1, acc[0][1]);
    acc[1][0] = MFMA(af1, bf0, acc[1][0]);
    acc[1][1] = MFMA(af1, bf1, acc[1][1]);
    __syncthreads();
  }
  if (mode == 2){
    #pragma unroll
    for (int mi = 0; mi < 2; mi++)
      #pragma unroll
      for (int ni = 0; ni < 2; ni++){
        int m = m0 + moff + mi * 16 + lg * 4;
        int n = n0 + noff + ni * 16 + lr;
        u16x4 ov;
        #pragma unroll
        for (int j = 0; j < 4; j++) ov[j] = f2bf(acc[mi][ni][j]);
        *(u16x4*)(outb + ((size_t)(n >> 6) * DH + (n & 63)) * LQ + m) = ov;
      }
  } else {
    #pragma unroll
    for (int mi = 0; mi < 2; mi++)
      #pragma unroll
      for (int ni = 0; ni < 2; ni++)
        #pragma unroll
        for (int j = 0; j < 4; j++){
          int m = m0 + moff + mi * 16 + lg * 4 + j;
          int n = n0 + noff + ni * 16 + lr;
          if (m < M){
            float v = acc[mi][ni][j] * scale;
            if (mode == 1)
              __builtin_nontemporal_store(v + bias[n], &outf[(size_t)m * DM + n]);
            else
              outb[((size_t)(n >> 6) * M + m) * DH + (n & 63)] = f2bf(v);
          }
        }
  }
}

// ---------------- fused rel-pos attention (r13 + wide VGPR budget) ----------
// __launch_bounds__(512,2): up to 256 regs/wave -> ~20 global loads in flight
// (was 64 arch VGPRs -> ~4). LDS 72KB still allows 2 WG/CU.
#define QB 16
#define SSTR 280
#define SLAB (QB * SSTR)
#define SMEM_ATTN (8 * SLAB * 2 + 1024)
__launch_bounds__(512, 2)
__global__ void attn_kernel(const u16* __restrict__ qh, const u16* __restrict__ kh,
                            const u16* __restrict__ vt, const u16* __restrict__ rk,
                            const int* __restrict__ mask,
                            const float* __restrict__ r_w, const float* __restrict__ r_r,
                            float* __restrict__ map, u16* __restrict__ att){
  extern __shared__ char smem[];
  u16* RP = (u16*)smem;
  float* redm = (float*)(smem + 8 * SLAB * 2);
  float* redl = redm + 128;
  const int bid = blockIdx.x;
  const int swz = (bid & 7) * 192 + (bid >> 3);
  const int h = swz >> 7, q0 = (swz & 127) * QB;
  const int tid = threadIdx.x, w = tid >> 6, l = tid & 63, lr = l & 15, lg = l >> 4;
  const int roff = (LQ - 1) - q0 - (QB - 1);
  const int kb = w * 256;
  u16* slab = RP + w * SLAB;

  u16x8 a1[2], a2[2];
  #pragma unroll
  for (int kc = 0; kc < 2; kc++){
    u16x8 qv = *(const u16x8*)(qh + (size_t)(h * LQ + q0 + lr) * DH + kc * 32 + lg * 8);
    #pragma unroll
    for (int j = 0; j < 8; j++){
      int d = kc * 32 + lg * 8 + j;
      float f = bf2f(qv[j]);
      a1[kc][j] = f2bf(f + r_w[h * DH + d]);
      a2[kc][j] = f2bf(f + r_r[h * DH + d]);
    }
  }

  // band slab: 17 tiles, fully unrolled for load hoisting
  #pragma unroll
  for (int t = 0; t < 17; t++){
    int r = roff + kb + t * 16 + lr;
    if (r > NR - 1) r = NR - 1;
    const u16* rp = rk + (size_t)(h * NR + r) * DH + lg * 8;
    u16x8 b0 = *(const u16x8*)(rp);
    u16x8 b1 = *(const u16x8*)(rp + 32);
    f32x4 racc = {};
    racc = MFMA(a2[0], b0, racc);
    racc = MFMA(a2[1], b1, racc);
    #pragma unroll
    for (int j = 0; j < 4; j++)
      slab[(lg * 4 + j) * SSTR + t * 16 + lr] = f2bf(racc[j]);
  }
  __asm__ volatile("s_waitcnt lgkmcnt(0)" ::: "memory");
  __builtin_amdgcn_sched_barrier(0);

  f32x4 s[16];
  #pragma unroll
  for (int nt = 0; nt < 16; nt++){
    const u16* kp = kh + (size_t)(h * LQ + kb + nt * 16 + lr) * DH + lg * 8;
    u16x8 b0 = *(const u16x8*)(kp);
    u16x8 b1 = *(const u16x8*)(kp + 32);
    f32x4 sv = {};
    sv = MFMA(a1[0], b0, sv);
    sv = MFMA(a1[1], b1, sv);
    int mv = mask[kb + nt * 16 + lr];
    #pragma unroll
    for (int j = 0; j < 4; j++){
      int ql = lg * 4 + j;
      float x = sv[j] + bf2f(slab[ql * SSTR + nt * 16 + lr + 15 - ql]);
      sv[j] = (mv == 1) ? -10000.f : x;
    }
    s[nt] = sv;
  }

  float fm[4];
  #pragma unroll
  for (int j = 0; j < 4; j++){
    float mx = -3.0e38f;
    #pragma unroll
    for (int nt = 0; nt < 16; nt++) mx = fmaxf(mx, s[nt][j]);
    #pragma unroll
    for (int off = 1; off < 16; off <<= 1) mx = fmaxf(mx, __shfl_xor(mx, off));
    if (lr == 0) redm[w * QB + lg * 4 + j] = mx;
  }
  __syncthreads();
  #pragma unroll
  for (int j = 0; j < 4; j++){
    int ql = lg * 4 + j;
    float mx = redm[ql];
    #pragma unroll
    for (int w2 = 1; w2 < 8; w2++) mx = fmaxf(mx, redm[w2 * QB + ql]);
    fm[j] = mx;
  }

  float ls[4] = {0.f, 0.f, 0.f, 0.f};
  #pragma unroll
  for (int nt = 0; nt < 16; nt++)
    #pragma unroll
    for (int j = 0; j < 4; j++){
      float p = __expf(s[nt][j] - fm[j]);
      ls[j] += p;
      slab[(lg * 4 + j) * SSTR + nt * 16 + lr] = f2bf(p);
    }
  #pragma unroll
  for (int j = 0; j < 4; j++){
    float sum = ls[j];
    #pragma unroll
    for (int off = 1; off < 16; off <<= 1) sum += __shfl_xor(sum, off);
    if (lr == 0) redl[w * QB + lg * 4 + j] = sum;
  }
  __syncthreads();
  float inv[4];
  #pragma unroll
  for (int j = 0; j < 4; j++){
    int ql = lg * 4 + j;
    float d = redl[ql];
    #pragma unroll
    for (int w2 = 1; w2 < 8; w2++) d += redl[w2 * QB + ql];
    inv[j] = 1.f / d;
  }

  // map write (NT f32) before PV — drains under the PV MFMAs
  {
    int qrow = tid >> 5, cb = (tid & 31) * 8;
    float dsum = redl[qrow];
    #pragma unroll
    for (int w2 = 1; w2 < 8; w2++) dsum += redl[w2 * QB + qrow];
    float invr = 1.f / dsum;
    float* mrow = map + (size_t)(h * LQ + q0 + qrow) * LQ;
    #pragma unroll
    for (int it = 0; it < 8; it++){
      u16x8 pv = *(u16x8*)&RP[it * SLAB + qrow * SSTR + cb];
      f32x4 o0, o1;
      #pragma unroll
      for (int j = 0; j < 4; j++){
        o0[j] = bf2f(pv[j]) * invr;
        o1[j] = bf2f(pv[4 + j]) * invr;
      }
      int c = cb + it * 256;
      __builtin_nontemporal_store(o0, (f32x4*)(mrow + c));
      __builtin_nontemporal_store(o1, (f32x4*)(mrow + c + 4));
    }
  }

  f32x4 o[4] = {};
  #pragma unroll
  for (int kc2 = 0; kc2 < 8; kc2++){
    u16x8 pa = *(u16x8*)&slab[lr * SSTR + kc2 * 32 + lg * 8];
    #pragma unroll
    for (int ni = 0; ni < 4; ni++){
      u16x8 vv = *(const u16x8*)(vt + (size_t)(h * DH + ni * 16 + lr) * LQ + kb + kc2 * 32 + lg * 8);
      o[ni] = MFMA(pa, vv, o[ni]);
    }
  }
  __syncthreads();

  float* Op = (float*)smem;    // [8][16][64]
  #pragma unroll
  for (int ni = 0; ni < 4; ni++)
    #pragma unroll
    for (int j = 0; j < 4; j++)
      Op[(w * QB + lg * 4 + j) * 64 + ni * 16 + lr] = o[ni][j] * inv[j];
  __syncthreads();
  {
    int q = tid >> 5, dg = (tid & 31) * 2;
    float acc0 = 0.f, acc1 = 0.f;
    #pragma unroll
    for (int w2 = 0; w2 < 8; w2++){
      acc0 += Op[(w2 * QB + q) * 64 + dg];
      acc1 += Op[(w2 * QB + q) * 64 + dg + 1];
    }
    unsigned pk = (unsigned)f2bf(acc0) | ((unsigned)f2bf(acc1) << 16);
    *(unsigned*)(att + (size_t)(q0 + q) * DM + h * DH + dg) = pk;
  }
}

extern "C" void kernel_launch(void* const* d_in, const int* in_sizes, int n_in,
                              void* d_out, int out_size, void* d_ws, size_t ws_size,
                              hipStream_t stream){
  const float* v_in = (const float*)d_in[0];
  const float* k_in = (const float*)d_in[1];
  const float* q_in = (const float*)d_in[2];
  const int*   mask = (const int*)d_in[3];
  const float* Wq   = (const float*)d_in[4];
  const float* Wk   = (const float*)d_in[5];
  const float* Wv   = (const float*)d_in[6];
  const float* Wrk  = (const float*)d_in[7];
  const float* r_w  = (const float*)d_in[8];
  const float* r_r  = (const float*)d_in[9];
  const float* Wo   = (const float*)d_in[10];
  const float* bo   = (const float*)d_in[11];

  char* ws = (char*)d_ws;
  u16* qh  = (u16*)(ws + 0);             // [12][2048][64] bf16
  u16* kh  = (u16*)(ws + 3145728);
  u16* vt  = (u16*)(ws + 6291456);       // [12][64][2048] bf16
  u16* rk  = (u16*)(ws + 9437184);       // [12][4095][64] bf16
  u16* qb  = (u16*)(ws + 15727104);      // [2048][768] bf16 inputs
  u16* kb  = (u16*)(ws + 18872832);
  u16* vb  = (u16*)(ws + 22018560);
  u16* Wqb = (u16*)(ws + 25165824);      // [768][768] bf16 weights
  u16* Wkb = (u16*)(ws + 26345472);
  u16* Wvb = (u16*)(ws + 27525120);
  u16* Wrkb= (u16*)(ws + 28704768);
  u16* Wob = (u16*)(ws + 29884416);
  u16* peb = (u16*)(ws + 31064064);      // [4095][768] bf16
  u16* att = (u16*)(ws + 37353984);      // [2048][768] bf16
  float* gamtab = (float*)(ws + 40499712);
  unsigned long long* gmax = (unsigned long long*)(ws + 41548288);
  double* logx = (double*)(ws + 41548352);
  double* Cf   = (double*)(ws + 41564736);

  float* out0 = (float*)d_out;                     // [2048][768] f32
  float* map  = out0 + (size_t)LQ * DM;            // [12][2048][2048] f32

  hipMemsetAsync(gmax, 0, 8, stream);
  gamma_tables_kernel<<<8, 256, 0, stream>>>(logx, Cf);
  gamma_probs_kernel<<<1024, 256, 0, stream>>>(logx, Cf, gamtab, gmax);
  pe_kernel<<<(NR * DM + 255) / 256, 256, 0, stream>>>(gamtab, gmax, peb);

  cvt_kernel<<<dim3(768, 1, 8), 256, 0, stream>>>(q_in, k_in, v_in, Wq, Wk, Wv, Wrk, Wo,
                                                  qb, kb, vb, Wqb, Wkb, Wvb, Wrkb, Wob);

  gemm_kernel<<<dim3(32, 12), 256, 0, stream>>>(qb, Wqb, qh, nullptr, LQ, 0.125f, nullptr, 0);
  gemm_kernel<<<dim3(32, 12), 256, 0, stream>>>(kb, Wkb, kh, nullptr, LQ, 1.f, nullptr, 0);
  gemm_kernel<<<dim3(32, 12), 256, 0, stream>>>(vb, Wvb, vt, nullptr, LQ, 1.f, nullptr, 2);
  gemm_kernel<<<dim3(64, 12), 256, 0, stream>>>(peb, Wrkb, rk, nullptr, NR, 1.f, nullptr, 0);

  hipFuncSetAttribute((const void*)attn_kernel,
                      hipFuncAttributeMaxDynamicSharedMemorySize, SMEM_ATTN);
  attn_kernel<<<dim3((LQ / QB) * NH), 512, SMEM_ATTN, stream>>>(qh, kh, vt, rk, mask,
                                                                r_w, r_r, map, att);
  gemm_kernel<<<dim3(32, 12), 256, 0, stream>>>(att, Wob, nullptr, out0, LQ, 1.f, bo, 1);
}

// Round 17
// 315.713 us; speedup vs baseline: 1.5058x; 1.1190x over previous
//
#include <hip/hip_runtime.h>
#include <hip/hip_bf16.h>
#include <math.h>

typedef unsigned short u16;
typedef __bf16 bf16x8_t __attribute__((ext_vector_type(8)));
typedef u16 u16x8 __attribute__((ext_vector_type(8)));
typedef u16 u16x4 __attribute__((ext_vector_type(4)));
typedef float f32x4 __attribute__((ext_vector_type(4)));

#define NH 12
#define LQ 2048
#define DM 768
#define DH 64
#define NR 4095           // 2L-1
#define LN2F 0.6931471805599453f

__device__ __forceinline__ u16 f2bf(float f){
  unsigned x = __float_as_uint(f);
  return (u16)((x + 0x7fffu + ((x >> 16) & 1u)) >> 16);   // RTNE
}
__device__ __forceinline__ float bf2f(u16 u){ return __uint_as_float(((unsigned)u) << 16); }

__device__ __forceinline__ f32x4 MFMA(u16x8 a, u16x8 b, f32x4 c){
  return __builtin_amdgcn_mfma_f32_16x16x32_bf16(
      __builtin_bit_cast(bf16x8_t, a), __builtin_bit_cast(bf16x8_t, b), c, 0, 0, 0);
}

// ---------------- gamma tables: logx[2048] f64, Cf[128] f64 ----------------
__global__ void gamma_tables_kernel(double* __restrict__ logx, double* __restrict__ Cf){
  int i = blockIdx.x * 256 + threadIdx.x;
  if (i < 2048) logx[i] = (i > 0) ? log((double)i) : 0.0;
  if (i < 128){
    double fp1 = (double)(i + 1);
    double conc = 4.0 * fp1 * fp1;
    double rate = 0.25 * fp1;
    Cf[i] = conc * log(rate) - lgamma(conc);
  }
}

// ---------------- gamma pdf table (unnormalized) + global max ----------------
__global__ void gamma_probs_kernel(const double* __restrict__ logx,
                                   const double* __restrict__ Cf,
                                   float* __restrict__ gamtab,
                                   unsigned long long* __restrict__ gmax){
  int idx = blockIdx.x * 256 + threadIdx.x;   // 2048*128
  int x = idx >> 7, f = idx & 127;
  double fp1 = (double)(f + 1);
  double conc = 4.0 * fp1 * fp1;
  double rate = 0.25 * fp1;
  double xl = (x > 0) ? (conc - 1.0) * logx[x] : 0.0;   // xlogy(a,0)=0
  double p = exp(xl - rate * (double)x + Cf[f]);
  gamtab[idx] = (float)p;
  double m = p;
  #pragma unroll
  for (int off = 1; off < 64; off <<= 1) m = fmax(m, __shfl_xor(m, off));
  if ((threadIdx.x & 63) == 0)
    atomicMax(gmax, (unsigned long long)__double_as_longlong(m));
}

// ---------------- pe(p, c) inline (for fused rk GEMM staging) ----------------
__device__ __forceinline__ float pe_val(int p, int c, const float* __restrict__ gamtab,
                                        float gm){
  int f = c & 127;
  int kind = c >> 7;                 // 0:exp 1:exp*sgn 2:cm 3:cm*sgn 4:gam 5:gam*sgn
  int pos = p - (LQ - 1);
  int apos = pos < 0 ? -pos : pos;
  float sgn = (pos > 0) ? 1.f : ((pos < 0) ? -1.f : 0.f);
  float v;
  int grp = kind >> 1;
  if (grp == 0){
    float hl = exp2f(3.f + 8.f * (float)f / 127.f);
    v = expf(-(LN2F / hl) * (float)apos);
  } else if (grp == 1){
    float cw = exp2f((float)(f + 1)) - 1.f;
    v = (cw > (float)apos) ? 1.f : 0.f;
  } else {
    v = gamtab[apos * 128 + f] * gm;
  }
  if (kind & 1) v *= sgn;
  return v;
}

// ---------------- fused q/k/v projection GEMM (grid.z picks input) ----------
#define GSTR 56
__launch_bounds__(256)
__global__ void proj3_kernel(const float* __restrict__ q_in, const float* __restrict__ k_in,
                             const float* __restrict__ v_in,
                             const float* __restrict__ Wq, const float* __restrict__ Wk,
                             const float* __restrict__ Wv,
                             u16* __restrict__ qh, u16* __restrict__ kh,
                             u16* __restrict__ vt){
  __shared__ u16 At[64 * GSTR];
  __shared__ u16 Wt[64 * GSTR];
  const int z = blockIdx.z;
  const float* A = (z == 0) ? q_in : (z == 1) ? k_in : v_in;
  const float* W = (z == 0) ? Wq : (z == 1) ? Wk : Wv;
  const float scale = (z == 0) ? 0.125f : 1.f;
  const int m0 = blockIdx.x * 64, n0 = blockIdx.y * 64;
  const int tid = threadIdx.x;
  const int w = tid >> 6, l = tid & 63, lr = l & 15, lg = l >> 4;
  const int moff = (w & 1) * 32, noff = (w >> 1) * 32;
  f32x4 acc[2][2] = {};
  const int arow = tid >> 2, akg = (tid & 3) * 8;
  const int wn = tid & 63, wkg = (tid >> 6) * 8;
  for (int k0 = 0; k0 < DM; k0 += 32){
    u16x8 av;
    {
      const float* ap = A + (size_t)(m0 + arow) * DM + k0 + akg;
      #pragma unroll
      for (int j = 0; j < 8; j++) av[j] = f2bf(ap[j]);
    }
    *(u16x8*)&At[arow * GSTR + akg] = av;
    u16x8 wv;
    #pragma unroll
    for (int i = 0; i < 8; i++)
      wv[i] = f2bf(W[(size_t)(k0 + wkg + i) * DM + n0 + wn]);
    *(u16x8*)&Wt[wn * GSTR + wkg] = wv;
    __syncthreads();
    u16x8 af0 = *(u16x8*)&At[(moff + lr) * GSTR + lg * 8];
    u16x8 af1 = *(u16x8*)&At[(moff + 16 + lr) * GSTR + lg * 8];
    u16x8 bf0 = *(u16x8*)&Wt[(noff + lr) * GSTR + lg * 8];
    u16x8 bf1 = *(u16x8*)&Wt[(noff + 16 + lr) * GSTR + lg * 8];
    acc[0][0] = MFMA(af0, bf0, acc[0][0]);
    acc[0][1] = MFMA(af0, bf1, acc[0][1]);
    acc[1][0] = MFMA(af1, bf0, acc[1][0]);
    acc[1][1] = MFMA(af1, bf1, acc[1][1]);
    __syncthreads();
  }
  u16* outb = (z == 0) ? qh : kh;
  #pragma unroll
  for (int mi = 0; mi < 2; mi++)
    #pragma unroll
    for (int ni = 0; ni < 2; ni++){
      if (z < 2){
        #pragma unroll
        for (int j = 0; j < 4; j++){
          int m = m0 + moff + mi * 16 + lg * 4 + j;
          int n = n0 + noff + ni * 16 + lr;
          outb[((size_t)(n >> 6) * LQ + m) * DH + (n & 63)] = f2bf(acc[mi][ni][j] * scale);
        }
      } else {
        int m = m0 + moff + mi * 16 + lg * 4;
        int n = n0 + noff + ni * 16 + lr;
        u16x4 ov;
        #pragma unroll
        for (int j = 0; j < 4; j++) ov[j] = f2bf(acc[mi][ni][j]);
        *(u16x4*)(vt + ((size_t)(n >> 6) * DH + (n & 63)) * LQ + m) = ov;
      }
    }
}

// ---------------- rk GEMM with pe() computed inline in A staging ------------
__launch_bounds__(256)
__global__ void gemm_pe_kernel(const float* __restrict__ gamtab,
                               const unsigned long long* __restrict__ gmax,
                               const float* __restrict__ W, u16* __restrict__ outb){
  __shared__ u16 At[64 * GSTR];
  __shared__ u16 Wt[64 * GSTR];
  const int m0 = blockIdx.x * 64, n0 = blockIdx.y * 64;
  const int tid = threadIdx.x;
  const int w = tid >> 6, l = tid & 63, lr = l & 15, lg = l >> 4;
  const int moff = (w & 1) * 32, noff = (w >> 1) * 32;
  f32x4 acc[2][2] = {};
  const int arow = tid >> 2, akg = (tid & 3) * 8;
  const int wn = tid & 63, wkg = (tid >> 6) * 8;
  const float gm = 1.f / (float)__longlong_as_double((long long)*gmax);
  for (int k0 = 0; k0 < DM; k0 += 32){
    u16x8 av;
    {
      int m = m0 + arow;
      if (m < NR){
        #pragma unroll
        for (int j = 0; j < 8; j++) av[j] = f2bf(pe_val(m, k0 + akg + j, gamtab, gm));
      } else {
        #pragma unroll
        for (int j = 0; j < 8; j++) av[j] = 0;
      }
    }
    *(u16x8*)&At[arow * GSTR + akg] = av;
    u16x8 wv;
    #pragma unroll
    for (int i = 0; i < 8; i++)
      wv[i] = f2bf(W[(size_t)(k0 + wkg + i) * DM + n0 + wn]);
    *(u16x8*)&Wt[wn * GSTR + wkg] = wv;
    __syncthreads();
    u16x8 af0 = *(u16x8*)&At[(moff + lr) * GSTR + lg * 8];
    u16x8 af1 = *(u16x8*)&At[(moff + 16 + lr) * GSTR + lg * 8];
    u16x8 bf0 = *(u16x8*)&Wt[(noff + lr) * GSTR + lg * 8];
    u16x8 bf1 = *(u16x8*)&Wt[(noff + 16 + lr) * GSTR + lg * 8];
    acc[0][0] = MFMA(af0, bf0, acc[0][0]);
    acc[0][1] = MFMA(af0, bf1, acc[0][1]);
    acc[1][0] = MFMA(af1, bf0, acc[1][0]);
    acc[1][1] = MFMA(af1, bf1, acc[1][1]);
    __syncthreads();
  }
  #pragma unroll
  for (int mi = 0; mi < 2; mi++)
    #pragma unroll
    for (int ni = 0; ni < 2; ni++)
      #pragma unroll
      for (int j = 0; j < 4; j++){
        int m = m0 + moff + mi * 16 + lg * 4 + j;
        int n = n0 + noff + ni * 16 + lr;
        if (m < NR)
          outb[((size_t)(n >> 6) * NR + m) * DH + (n & 63)] = f2bf(acc[mi][ni][j]);
      }
}

// ---------------- out-projection GEMM (f32 A, f32 out + bias) ----------------
__launch_bounds__(256)
__global__ void gemm_kernel(const float* __restrict__ A, const float* __restrict__ W,
                            float* __restrict__ outf, int M,
                            const float* __restrict__ bias){
  __shared__ u16 At[64 * GSTR];
  __shared__ u16 Wt[64 * GSTR];
  const int m0 = blockIdx.x * 64, n0 = blockIdx.y * 64;
  const int tid = threadIdx.x;
  const int w = tid >> 6, l = tid & 63, lr = l & 15, lg = l >> 4;
  const int moff = (w & 1) * 32, noff = (w >> 1) * 32;
  f32x4 acc[2][2] = {};
  const int arow = tid >> 2, akg = (tid & 3) * 8;
  const int wn = tid & 63, wkg = (tid >> 6) * 8;
  for (int k0 = 0; k0 < DM; k0 += 32){
    u16x8 av;
    {
      const float* ap = A + (size_t)(m0 + arow) * DM + k0 + akg;
      #pragma unroll
      for (int j = 0; j < 8; j++) av[j] = f2bf(ap[j]);
    }
    *(u16x8*)&At[arow * GSTR + akg] = av;
    u16x8 wv;
    #pragma unroll
    for (int i = 0; i < 8; i++)
      wv[i] = f2bf(W[(size_t)(k0 + wkg + i) * DM + n0 + wn]);
    *(u16x8*)&Wt[wn * GSTR + wkg] = wv;
    __syncthreads();
    u16x8 af0 = *(u16x8*)&At[(moff + lr) * GSTR + lg * 8];
    u16x8 af1 = *(u16x8*)&At[(moff + 16 + lr) * GSTR + lg * 8];
    u16x8 bf0 = *(u16x8*)&Wt[(noff + lr) * GSTR + lg * 8];
    u16x8 bf1 = *(u16x8*)&Wt[(noff + 16 + lr) * GSTR + lg * 8];
    acc[0][0] = MFMA(af0, bf0, acc[0][0]);
    acc[0][1] = MFMA(af0, bf1, acc[0][1]);
    acc[1][0] = MFMA(af1, bf0, acc[1][0]);
    acc[1][1] = MFMA(af1, bf1, acc[1][1]);
    __syncthreads();
  }
  #pragma unroll
  for (int mi = 0; mi < 2; mi++)
    #pragma unroll
    for (int ni = 0; ni < 2; ni++)
      #pragma unroll
      for (int j = 0; j < 4; j++){
        int m = m0 + moff + mi * 16 + lg * 4 + j;
        int n = n0 + noff + ni * 16 + lr;
        __builtin_nontemporal_store(acc[mi][ni][j] + bias[n], &outf[(size_t)m * DM + n]);
      }
}

// ---------------- fused rel-pos attention: DIAGONAL band slab ---------------
// r13 structure; band stored diagonally slabD[cc=lc+ql][ql] so the QK-loop
// gather is ONE ds_read_b64 (u16x4) instead of 4 scalar u16 reads.
// After the max barrier, P overwrites the slab in row-major [16][PSTR].
#define QB 16
#define DSTR 16            // diag cols (u16)
#define DROWS 288
#define PSTR 264
#define SLABU (DROWS * DSTR)               // 4608 u16 = 9216 B per wave
#define SMEM_ATTN (8 * SLABU * 2 + 1024)   // 74752 B -> 2 WG/CU
__launch_bounds__(512, 4)
__global__ void attn_kernel(const u16* __restrict__ qh, const u16* __restrict__ kh,
                            const u16* __restrict__ vt, const u16* __restrict__ rk,
                            const int* __restrict__ mask,
                            const float* __restrict__ r_w, const float* __restrict__ r_r,
                            float* __restrict__ map, float* __restrict__ att){
  extern __shared__ char smem[];
  u16* RP = (u16*)smem;                          // 8 wave slabs
  float* redm = (float*)(smem + 8 * SLABU * 2);  // [8][16]
  float* redl = redm + 128;                      // [8][16]
  const int bid = blockIdx.x;
  const int swz = (bid & 7) * 192 + (bid >> 3);  // XCD-aware
  const int h = swz >> 7, q0 = (swz & 127) * QB;
  const int tid = threadIdx.x, w = tid >> 6, l = tid & 63, lr = l & 15, lg = l >> 4;
  const int roff = (LQ - 1) - q0 - (QB - 1);     // 2032 - q0
  const int kb = w * 256;
  u16* slab = RP + w * SLABU;

  u16x8 a1[2], a2[2];
  #pragma unroll
  for (int kc = 0; kc < 2; kc++){
    u16x8 qv = *(const u16x8*)(qh + (size_t)(h * LQ + q0 + lr) * DH + kc * 32 + lg * 8);
    #pragma unroll
    for (int j = 0; j < 8; j++){
      int d = kc * 32 + lg * 8 + j;
      float f = bf2f(qv[j]);
      a1[kc][j] = f2bf(f + r_w[h * DH + d]);
      a2[kc][j] = f2bf(f + r_r[h * DH + d]);
    }
  }

  // band slab (diagonal): 17 tiles covering local cols [0, 272)
  #pragma unroll 4
  for (int t = 0; t < 17; t++){
    int r = roff + kb + t * 16 + lr;
    if (r > NR - 1) r = NR - 1;                  // never-gathered corner only
    const u16* rp = rk + (size_t)(h * NR + r) * DH + lg * 8;
    u16x8 b0 = *(const u16x8*)(rp);
    u16x8 b1 = *(const u16x8*)(rp + 32);
    f32x4 racc = {};
    racc = MFMA(a2[0], b0, racc);
    racc = MFMA(a2[1], b1, racc);
    int lc = t * 16 + lr;
    #pragma unroll
    for (int j = 0; j < 4; j++){
      int ql = lg * 4 + j;
      slab[(lc + ql) * DSTR + ql] = f2bf(racc[j]);   // diagonal store
    }
  }
  __asm__ volatile("s_waitcnt lgkmcnt(0)" ::: "memory");
  __builtin_amdgcn_sched_barrier(0);

  // QK loop: content logits + single-b64 band gather + mask -> S in AGPRs
  f32x4 s[16];
  #pragma unroll
  for (int nt = 0; nt < 16; nt++){
    const u16* kp = kh + (size_t)(h * LQ + kb + nt * 16 + lr) * DH + lg * 8;
    u16x8 b0 = *(const u16x8*)(kp);
    u16x8 b1 = *(const u16x8*)(kp + 32);
    f32x4 sv = {};
    sv = MFMA(a1[0], b0, sv);
    sv = MFMA(a1[1], b1, sv);
    int mv = mask[kb + nt * 16 + lr];
    u16x4 g = *(u16x4*)&slab[(nt * 16 + lr + (QB - 1)) * DSTR + lg * 4];
    #pragma unroll
    for (int j = 0; j < 4; j++){
      float x = sv[j] + bf2f(g[j]);
      sv[j] = (mv == 1) ? -10000.f : x;
    }
    s[nt] = sv;
  }

  float fm[4];
  #pragma unroll
  for (int j = 0; j < 4; j++){
    float mx = -3.0e38f;
    #pragma unroll
    for (int nt = 0; nt < 16; nt++) mx = fmaxf(mx, s[nt][j]);
    #pragma unroll
    for (int off = 1; off < 16; off <<= 1) mx = fmaxf(mx, __shfl_xor(mx, off));
    if (lr == 0) redm[w * QB + lg * 4 + j] = mx;
  }
  __syncthreads();
  #pragma unroll
  for (int j = 0; j < 4; j++){
    int ql = lg * 4 + j;
    float mx = redm[ql];
    #pragma unroll
    for (int w2 = 1; w2 < 8; w2++) mx = fmaxf(mx, redm[w2 * QB + ql]);
    fm[j] = mx;
  }

  // exp + P store (row-major [16][PSTR], overwrites diag band — gathers done)
  float ls[4] = {0.f, 0.f, 0.f, 0.f};
  #pragma unroll
  for (int nt = 0; nt < 16; nt++)
    #pragma unroll
    for (int j = 0; j < 4; j++){
      float p = __expf(s[nt][j] - fm[j]);
      ls[j] += p;
      slab[(lg * 4 + j) * PSTR + nt * 16 + lr] = f2bf(p);
    }
  #pragma unroll
  for (int j = 0; j < 4; j++){
    float sum = ls[j];
    #pragma unroll
    for (int off = 1; off < 16; off <<= 1) sum += __shfl_xor(sum, off);
    if (lr == 0) redl[w * QB + lg * 4 + j] = sum;
  }
  __syncthreads();
  float inv[4];
  #pragma unroll
  for (int j = 0; j < 4; j++){
    int ql = lg * 4 + j;
    float d = redl[ql];
    #pragma unroll
    for (int w2 = 1; w2 < 8; w2++) d += redl[w2 * QB + ql];
    inv[j] = 1.f / d;
  }

  // map write (NT f32) before PV — drains under the PV MFMAs
  {
    int qrow = tid >> 5, cb = (tid & 31) * 8;
    float dsum = redl[qrow];
    #pragma unroll
    for (int w2 = 1; w2 < 8; w2++) dsum += redl[w2 * QB + qrow];
    float invr = 1.f / dsum;
    float* mrow = map + (size_t)(h * LQ + q0 + qrow) * LQ;
    #pragma unroll
    for (int it = 0; it < 8; it++){
      u16x8 pv = *(u16x8*)&RP[it * SLABU + qrow * PSTR + cb];
      f32x4 o0, o1;
      #pragma unroll
      for (int j = 0; j < 4; j++){
        o0[j] = bf2f(pv[j]) * invr;
        o1[j] = bf2f(pv[4 + j]) * invr;
      }
      int c = cb + it * 256;
      __builtin_nontemporal_store(o0, (f32x4*)(mrow + c));
      __builtin_nontemporal_store(o1, (f32x4*)(mrow + c + 4));
    }
  }

  // PV (A-frags = P rows from own slab)
  f32x4 o[4] = {};
  #pragma unroll
  for (int kc2 = 0; kc2 < 8; kc2++){
    u16x8 pa = *(u16x8*)&slab[lr * PSTR + kc2 * 32 + lg * 8];
    #pragma unroll
    for (int ni = 0; ni < 4; ni++){
      u16x8 vv = *(const u16x8*)(vt + (size_t)(h * DH + ni * 16 + lr) * LQ + kb + kc2 * 32 + lg * 8);
      o[ni] = MFMA(pa, vv, o[ni]);
    }
  }
  __syncthreads();

  float* Op = (float*)smem;    // [8][16][64] overlays slabs
  #pragma unroll
  for (int ni = 0; ni < 4; ni++)
    #pragma unroll
    for (int j = 0; j < 4; j++)
      Op[(w * QB + lg * 4 + j) * 64 + ni * 16 + lr] = o[ni][j] * inv[j];
  __syncthreads();
  {
    int q = tid >> 5, dg = (tid & 31) * 2;
    float acc0 = 0.f, acc1 = 0.f;
    #pragma unroll
    for (int w2 = 0; w2 < 8; w2++){
      acc0 += Op[(w2 * QB + q) * 64 + dg];
      acc1 += Op[(w2 * QB + q) * 64 + dg + 1];
    }
    float* ap = att + (size_t)(q0 + q) * DM + h * DH + dg;
    ap[0] = acc0;
    ap[1] = acc1;
  }
}

extern "C" void kernel_launch(void* const* d_in, const int* in_sizes, int n_in,
                              void* d_out, int out_size, void* d_ws, size_t ws_size,
                              hipStream_t stream){
  const float* v_in = (const float*)d_in[0];
  const float* k_in = (const float*)d_in[1];
  const float* q_in = (const float*)d_in[2];
  const int*   mask = (const int*)d_in[3];
  const float* Wq   = (const float*)d_in[4];
  const float* Wk   = (const float*)d_in[5];
  const float* Wv   = (const float*)d_in[6];
  const float* Wrk  = (const float*)d_in[7];
  const float* r_w  = (const float*)d_in[8];
  const float* r_r  = (const float*)d_in[9];
  const float* Wo   = (const float*)d_in[10];
  const float* bo   = (const float*)d_in[11];

  char* ws = (char*)d_ws;
  u16* qh = (u16*)(ws + 0);              // [12][2048][64] bf16
  u16* kh = (u16*)(ws + 3145728);
  u16* vt = (u16*)(ws + 6291456);        // [12][64][2048] bf16
  u16* rk = (u16*)(ws + 9437184);        // [12][4095][64] bf16
  float* att = (float*)(ws + 28306944);  // [2048][768] f32
  float* gamtab = (float*)(ws + 34598400);           // [2048][128] f32
  unsigned long long* gmax = (unsigned long long*)(ws + 35646976);
  double* logx = (double*)(ws + 35647040);           // [2048] f64
  double* Cf   = (double*)(ws + 35663424);           // [128] f64

  float* out0 = (float*)d_out;                     // [2048][768] f32
  float* map  = out0 + (size_t)LQ * DM;            // [12][2048][2048] f32

  hipMemsetAsync(gmax, 0, 8, stream);
  gamma_tables_kernel<<<8, 256, 0, stream>>>(logx, Cf);
  gamma_probs_kernel<<<1024, 256, 0, stream>>>(logx, Cf, gamtab, gmax);

  proj3_kernel<<<dim3(32, 12, 3), 256, 0, stream>>>(q_in, k_in, v_in, Wq, Wk, Wv,
                                                    qh, kh, vt);
  gemm_pe_kernel<<<dim3(64, 12), 256, 0, stream>>>(gamtab, gmax, Wrk, rk);

  hipFuncSetAttribute((const void*)attn_kernel,
                      hipFuncAttributeMaxDynamicSharedMemorySize, SMEM_ATTN);
  attn_kernel<<<dim3((LQ / QB) * NH), 512, SMEM_ATTN, stream>>>(qh, kh, vt, rk, mask,
                                                                r_w, r_r, map, att);
  gemm_kernel<<<dim3(32, 12), 256, 0, stream>>>(att, Wo, out0, LQ, bo);
}

// Round 18
// 288.475 us; speedup vs baseline: 1.6480x; 1.0944x over previous
//
#include <hip/hip_runtime.h>
#include <hip/hip_bf16.h>
#include <math.h>

typedef unsigned short u16;
typedef __bf16 bf16x8_t __attribute__((ext_vector_type(8)));
typedef u16 u16x8 __attribute__((ext_vector_type(8)));
typedef u16 u16x4 __attribute__((ext_vector_type(4)));
typedef float f32x4 __attribute__((ext_vector_type(4)));

#define NH 12
#define LQ 2048
#define DM 768
#define DH 64
#define NR 4095           // 2L-1
#define LN2F 0.6931471805599453f

__device__ __forceinline__ u16 f2bf(float f){
  unsigned x = __float_as_uint(f);
  return (u16)((x + 0x7fffu + ((x >> 16) & 1u)) >> 16);   // RTNE
}
__device__ __forceinline__ float bf2f(u16 u){ return __uint_as_float(((unsigned)u) << 16); }

__device__ __forceinline__ f32x4 MFMA(u16x8 a, u16x8 b, f32x4 c){
  return __builtin_amdgcn_mfma_f32_16x16x32_bf16(
      __builtin_bit_cast(bf16x8_t, a), __builtin_bit_cast(bf16x8_t, b), c, 0, 0, 0);
}

// ---------------- gamma tables: logx[2048] f64, Cf[128] f64 ----------------
__global__ void gamma_tables_kernel(double* __restrict__ logx, double* __restrict__ Cf){
  int i = blockIdx.x * 256 + threadIdx.x;
  if (i < 2048) logx[i] = (i > 0) ? log((double)i) : 0.0;
  if (i < 128){
    double fp1 = (double)(i + 1);
    double conc = 4.0 * fp1 * fp1;
    double rate = 0.25 * fp1;
    Cf[i] = conc * log(rate) - lgamma(conc);
  }
}

// ---------------- gamma pdf table (unnormalized) + global max ----------------
__global__ void gamma_probs_kernel(const double* __restrict__ logx,
                                   const double* __restrict__ Cf,
                                   float* __restrict__ gamtab,
                                   unsigned long long* __restrict__ gmax){
  int idx = blockIdx.x * 256 + threadIdx.x;   // 2048*128
  int x = idx >> 7, f = idx & 127;
  double fp1 = (double)(f + 1);
  double conc = 4.0 * fp1 * fp1;
  double rate = 0.25 * fp1;
  double xl = (x > 0) ? (conc - 1.0) * logx[x] : 0.0;   // xlogy(a,0)=0
  double p = exp(xl - rate * (double)x + Cf[f]);
  gamtab[idx] = (float)p;
  double m = p;
  #pragma unroll
  for (int off = 1; off < 64; off <<= 1) m = fmax(m, __shfl_xor(m, off));
  if ((threadIdx.x & 63) == 0)
    atomicMax(gmax, (unsigned long long)__double_as_longlong(m));
}

// ---------------- positional encodings -> bf16 peb[4095][768] ----------------
__global__ void pe_kernel(const float* __restrict__ gamtab,
                          const unsigned long long* __restrict__ gmax,
                          u16* __restrict__ peb){
  int idx = blockIdx.x * 256 + threadIdx.x;
  if (idx >= NR * DM) return;
  int p = idx / DM;
  int c = idx - p * DM;
  int f = c & 127;
  int kind = c >> 7;
  int pos = p - (LQ - 1);
  int apos = pos < 0 ? -pos : pos;
  float sgn = (pos > 0) ? 1.f : ((pos < 0) ? -1.f : 0.f);
  float v;
  int grp = kind >> 1;
  if (grp == 0){
    float hl = exp2f(3.f + 8.f * (float)f / 127.f);
    v = expf(-(LN2F / hl) * (float)apos);
  } else if (grp == 1){
    float cw = exp2f((float)(f + 1)) - 1.f;
    v = (cw > (float)apos) ? 1.f : 0.f;
  } else {
    float gm = (float)__longlong_as_double((long long)*gmax);
    v = gamtab[apos * 128 + f] / gm;
  }
  if (kind & 1) v *= sgn;
  peb[idx] = f2bf(v);
}

// ---------------- input cvt: q/k/v f32 -> bf16 flat ----------------
__global__ void cvt_in_kernel(const float* q, const float* k, const float* v,
                              u16* qb, u16* kb, u16* vb){
  const int z = blockIdx.z;
  const float* src = (z == 0) ? q : (z == 1) ? k : v;
  u16* dst = (z == 0) ? qb : (z == 1) ? kb : vb;
  int base = (blockIdx.x * 256 + threadIdx.x) * 8;
  f32x4 a = *(const f32x4*)(src + base);
  f32x4 b = *(const f32x4*)(src + base + 4);
  u16x8 o;
  #pragma unroll
  for (int j = 0; j < 4; j++){ o[j] = f2bf(a[j]); o[4 + j] = f2bf(b[j]); }
  *(u16x8*)(dst + base) = o;
}

// ---------------- weight transpose+cvt: WT[n][k] bf16 = f2bf(W[k][n]) --------
__global__ void cvtw_kernel(const float* W0, const float* W1, const float* W2,
                            const float* W3, const float* W4,
                            u16* T0, u16* T1, u16* T2, u16* T3, u16* T4){
  __shared__ u16 tile[64 * 72];
  const int z = blockIdx.z;
  const float* W = (z == 0) ? W0 : (z == 1) ? W1 : (z == 2) ? W2 : (z == 3) ? W3 : W4;
  u16* T = (z == 0) ? T0 : (z == 1) ? T1 : (z == 2) ? T2 : (z == 3) ? T3 : T4;
  const int k0 = blockIdx.x * 64, n0 = blockIdx.y * 64;
  const int t = threadIdx.x;
  {
    int kr = t >> 2, ng = (t & 3) * 16;
    const float* p = W + (size_t)(k0 + kr) * DM + n0 + ng;
    u16x8 o0, o1;
    #pragma unroll
    for (int j = 0; j < 8; j++){ o0[j] = f2bf(p[j]); o1[j] = f2bf(p[8 + j]); }
    *(u16x8*)&tile[kr * 72 + ng] = o0;
    *(u16x8*)&tile[kr * 72 + ng + 8] = o1;
  }
  __syncthreads();
  {
    int nr = t >> 2, kg = (t & 3) * 16;
    u16x8 o0, o1;
    #pragma unroll
    for (int j = 0; j < 8; j++){
      o0[j] = tile[(kg + j) * 72 + nr];
      o1[j] = tile[(kg + j + 8) * 72 + nr];
    }
    u16* qp = T + (size_t)(n0 + nr) * DM + k0 + kg;
    *(u16x8*)qp = o0;
    *(u16x8*)(qp + 8) = o1;
  }
}

// ---------------- proj3: bf16 A x bf16 WT, BK=64 (grid.z picks tensor) -------
// z=0: qh bf16 head-major *0.125; z=1: kh; z=2: vt transposed [h*64+d][2048]
#define GSTRB 72
__launch_bounds__(256)
__global__ void proj3_kernel(const u16* __restrict__ qb, const u16* __restrict__ kb,
                             const u16* __restrict__ vb,
                             const u16* __restrict__ WqT, const u16* __restrict__ WkT,
                             const u16* __restrict__ WvT,
                             u16* __restrict__ qh, u16* __restrict__ kh,
                             u16* __restrict__ vt){
  __shared__ u16 At[64 * GSTRB];
  __shared__ u16 Wt[64 * GSTRB];
  const int z = blockIdx.z;
  const u16* A = (z == 0) ? qb : (z == 1) ? kb : vb;
  const u16* WT = (z == 0) ? WqT : (z == 1) ? WkT : WvT;
  const float scale = (z == 0) ? 0.125f : 1.f;
  const int m0 = blockIdx.x * 64, n0 = blockIdx.y * 64;
  const int tid = threadIdx.x;
  const int w = tid >> 6, l = tid & 63, lr = l & 15, lg = l >> 4;
  const int moff = (w & 1) * 32, noff = (w >> 1) * 32;
  f32x4 acc[2][2] = {};
  const int arow = tid >> 2, akg = (tid & 3) * 16;
  for (int k0 = 0; k0 < DM; k0 += 64){
    {
      const u16* ap = A + (size_t)(m0 + arow) * DM + k0 + akg;
      *(u16x8*)&At[arow * GSTRB + akg] = *(const u16x8*)ap;
      *(u16x8*)&At[arow * GSTRB + akg + 8] = *(const u16x8*)(ap + 8);
      const u16* wp = WT + (size_t)(n0 + arow) * DM + k0 + akg;
      *(u16x8*)&Wt[arow * GSTRB + akg] = *(const u16x8*)wp;
      *(u16x8*)&Wt[arow * GSTRB + akg + 8] = *(const u16x8*)(wp + 8);
    }
    __syncthreads();
    #pragma unroll
    for (int kc = 0; kc < 2; kc++){
      u16x8 af0 = *(u16x8*)&At[(moff + lr) * GSTRB + kc * 32 + lg * 8];
      u16x8 af1 = *(u16x8*)&At[(moff + 16 + lr) * GSTRB + kc * 32 + lg * 8];
      u16x8 bf0 = *(u16x8*)&Wt[(noff + lr) * GSTRB + kc * 32 + lg * 8];
      u16x8 bf1 = *(u16x8*)&Wt[(noff + 16 + lr) * GSTRB + kc * 32 + lg * 8];
      acc[0][0] = MFMA(af0, bf0, acc[0][0]);
      acc[0][1] = MFMA(af0, bf1, acc[0][1]);
      acc[1][0] = MFMA(af1, bf0, acc[1][0]);
      acc[1][1] = MFMA(af1, bf1, acc[1][1]);
    }
    __syncthreads();
  }
  #pragma unroll
  for (int mi = 0; mi < 2; mi++)
    #pragma unroll
    for (int ni = 0; ni < 2; ni++){
      if (z < 2){
        u16* outb = (z == 0) ? qh : kh;
        #pragma unroll
        for (int j = 0; j < 4; j++){
          int m = m0 + moff + mi * 16 + lg * 4 + j;
          int n = n0 + noff + ni * 16 + lr;
          outb[((size_t)(n >> 6) * LQ + m) * DH + (n & 63)] = f2bf(acc[mi][ni][j] * scale);
        }
      } else {
        int m = m0 + moff + mi * 16 + lg * 4;
        int n = n0 + noff + ni * 16 + lr;
        u16x4 ov;
        #pragma unroll
        for (int j = 0; j < 4; j++) ov[j] = f2bf(acc[mi][ni][j]);
        *(u16x4*)(vt + ((size_t)(n >> 6) * DH + (n & 63)) * LQ + m) = ov;
      }
    }
}

// ---------------- rk GEMM: peb bf16 x WrkT bf16, BK=64, out head-major -------
__launch_bounds__(256)
__global__ void gemm_rk_kernel(const u16* __restrict__ peb, const u16* __restrict__ WT,
                               u16* __restrict__ rk){
  __shared__ u16 At[64 * GSTRB];
  __shared__ u16 Wt[64 * GSTRB];
  const int m0 = blockIdx.x * 64, n0 = blockIdx.y * 64;
  const int tid = threadIdx.x;
  const int w = tid >> 6, l = tid & 63, lr = l & 15, lg = l >> 4;
  const int moff = (w & 1) * 32, noff = (w >> 1) * 32;
  f32x4 acc[2][2] = {};
  const int arow = tid >> 2, akg = (tid & 3) * 16;
  for (int k0 = 0; k0 < DM; k0 += 64){
    {
      int m = m0 + arow;
      u16x8 a0 = {}, a1 = {};
      if (m < NR){
        const u16* ap = peb + (size_t)m * DM + k0 + akg;
        a0 = *(const u16x8*)ap;
        a1 = *(const u16x8*)(ap + 8);
      }
      *(u16x8*)&At[arow * GSTRB + akg] = a0;
      *(u16x8*)&At[arow * GSTRB + akg + 8] = a1;
      const u16* wp = WT + (size_t)(n0 + arow) * DM + k0 + akg;
      *(u16x8*)&Wt[arow * GSTRB + akg] = *(const u16x8*)wp;
      *(u16x8*)&Wt[arow * GSTRB + akg + 8] = *(const u16x8*)(wp + 8);
    }
    __syncthreads();
    #pragma unroll
    for (int kc = 0; kc < 2; kc++){
      u16x8 af0 = *(u16x8*)&At[(moff + lr) * GSTRB + kc * 32 + lg * 8];
      u16x8 af1 = *(u16x8*)&At[(moff + 16 + lr) * GSTRB + kc * 32 + lg * 8];
      u16x8 bf0 = *(u16x8*)&Wt[(noff + lr) * GSTRB + kc * 32 + lg * 8];
      u16x8 bf1 = *(u16x8*)&Wt[(noff + 16 + lr) * GSTRB + kc * 32 + lg * 8];
      acc[0][0] = MFMA(af0, bf0, acc[0][0]);
      acc[0][1] = MFMA(af0, bf1, acc[0][1]);
      acc[1][0] = MFMA(af1, bf0, acc[1][0]);
      acc[1][1] = MFMA(af1, bf1, acc[1][1]);
    }
    __syncthreads();
  }
  #pragma unroll
  for (int mi = 0; mi < 2; mi++)
    #pragma unroll
    for (int ni = 0; ni < 2; ni++)
      #pragma unroll
      for (int j = 0; j < 4; j++){
        int m = m0 + moff + mi * 16 + lg * 4 + j;
        int n = n0 + noff + ni * 16 + lr;
        if (m < NR)
          rk[((size_t)(n >> 6) * NR + m) * DH + (n & 63)] = f2bf(acc[mi][ni][j]);
      }
}

// ---------------- out-proj GEMM: f32 att x WoT bf16, f32 out + bias ----------
__launch_bounds__(256)
__global__ void gemm_out_kernel(const float* __restrict__ A, const u16* __restrict__ WT,
                                float* __restrict__ outf, const float* __restrict__ bias){
  __shared__ u16 At[64 * GSTRB];
  __shared__ u16 Wt[64 * GSTRB];
  const int m0 = blockIdx.x * 64, n0 = blockIdx.y * 64;
  const int tid = threadIdx.x;
  const int w = tid >> 6, l = tid & 63, lr = l & 15, lg = l >> 4;
  const int moff = (w & 1) * 32, noff = (w >> 1) * 32;
  f32x4 acc[2][2] = {};
  const int arow = tid >> 2, akg = (tid & 3) * 16;
  for (int k0 = 0; k0 < DM; k0 += 64){
    {
      const float* ap = A + (size_t)(m0 + arow) * DM + k0 + akg;
      u16x8 a0, a1;
      #pragma unroll
      for (int j = 0; j < 8; j++){ a0[j] = f2bf(ap[j]); a1[j] = f2bf(ap[8 + j]); }
      *(u16x8*)&At[arow * GSTRB + akg] = a0;
      *(u16x8*)&At[arow * GSTRB + akg + 8] = a1;
      const u16* wp = WT + (size_t)(n0 + arow) * DM + k0 + akg;
      *(u16x8*)&Wt[arow * GSTRB + akg] = *(const u16x8*)wp;
      *(u16x8*)&Wt[arow * GSTRB + akg + 8] = *(const u16x8*)(wp + 8);
    }
    __syncthreads();
    #pragma unroll
    for (int kc = 0; kc < 2; kc++){
      u16x8 af0 = *(u16x8*)&At[(moff + lr) * GSTRB + kc * 32 + lg * 8];
      u16x8 af1 = *(u16x8*)&At[(moff + 16 + lr) * GSTRB + kc * 32 + lg * 8];
      u16x8 bf0 = *(u16x8*)&Wt[(noff + lr) * GSTRB + kc * 32 + lg * 8];
      u16x8 bf1 = *(u16x8*)&Wt[(noff + 16 + lr) * GSTRB + kc * 32 + lg * 8];
      acc[0][0] = MFMA(af0, bf0, acc[0][0]);
      acc[0][1] = MFMA(af0, bf1, acc[0][1]);
      acc[1][0] = MFMA(af1, bf0, acc[1][0]);
      acc[1][1] = MFMA(af1, bf1, acc[1][1]);
    }
    __syncthreads();
  }
  #pragma unroll
  for (int mi = 0; mi < 2; mi++)
    #pragma unroll
    for (int ni = 0; ni < 2; ni++)
      #pragma unroll
      for (int j = 0; j < 4; j++){
        int m = m0 + moff + mi * 16 + lg * 4 + j;
        int n = n0 + noff + ni * 16 + lr;
        __builtin_nontemporal_store(acc[mi][ni][j] + bias[n], &outf[(size_t)m * DM + n]);
      }
}

// ---------------- fused rel-pos attention (r17, unchanged) -------------------
#define QB 16
#define DSTR 16
#define DROWS 288
#define PSTR 264
#define SLABU (DROWS * DSTR)
#define SMEM_ATTN (8 * SLABU * 2 + 1024)
__launch_bounds__(512, 4)
__global__ void attn_kernel(const u16* __restrict__ qh, const u16* __restrict__ kh,
                            const u16* __restrict__ vt, const u16* __restrict__ rk,
                            const int* __restrict__ mask,
                            const float* __restrict__ r_w, const float* __restrict__ r_r,
                            float* __restrict__ map, float* __restrict__ att){
  extern __shared__ char smem[];
  u16* RP = (u16*)smem;
  float* redm = (float*)(smem + 8 * SLABU * 2);
  float* redl = redm + 128;
  const int bid = blockIdx.x;
  const int swz = (bid & 7) * 192 + (bid >> 3);
  const int h = swz >> 7, q0 = (swz & 127) * QB;
  const int tid = threadIdx.x, w = tid >> 6, l = tid & 63, lr = l & 15, lg = l >> 4;
  const int roff = (LQ - 1) - q0 - (QB - 1);
  const int kb = w * 256;
  u16* slab = RP + w * SLABU;

  u16x8 a1[2], a2[2];
  #pragma unroll
  for (int kc = 0; kc < 2; kc++){
    u16x8 qv = *(const u16x8*)(qh + (size_t)(h * LQ + q0 + lr) * DH + kc * 32 + lg * 8);
    #pragma unroll
    for (int j = 0; j < 8; j++){
      int d = kc * 32 + lg * 8 + j;
      float f = bf2f(qv[j]);
      a1[kc][j] = f2bf(f + r_w[h * DH + d]);
      a2[kc][j] = f2bf(f + r_r[h * DH + d]);
    }
  }

  #pragma unroll 4
  for (int t = 0; t < 17; t++){
    int r = roff + kb + t * 16 + lr;
    if (r > NR - 1) r = NR - 1;
    const u16* rp = rk + (size_t)(h * NR + r) * DH + lg * 8;
    u16x8 b0 = *(const u16x8*)(rp);
    u16x8 b1 = *(const u16x8*)(rp + 32);
    f32x4 racc = {};
    racc = MFMA(a2[0], b0, racc);
    racc = MFMA(a2[1], b1, racc);
    int lc = t * 16 + lr;
    #pragma unroll
    for (int j = 0; j < 4; j++){
      int ql = lg * 4 + j;
      slab[(lc + ql) * DSTR + ql] = f2bf(racc[j]);
    }
  }
  __asm__ volatile("s_waitcnt lgkmcnt(0)" ::: "memory");
  __builtin_amdgcn_sched_barrier(0);

  f32x4 s[16];
  #pragma unroll
  for (int nt = 0; nt < 16; nt++){
    const u16* kp = kh + (size_t)(h * LQ + kb + nt * 16 + lr) * DH + lg * 8;
    u16x8 b0 = *(const u16x8*)(kp);
    u16x8 b1 = *(const u16x8*)(kp + 32);
    f32x4 sv = {};
    sv = MFMA(a1[0], b0, sv);
    sv = MFMA(a1[1], b1, sv);
    int mv = mask[kb + nt * 16 + lr];
    u16x4 g = *(u16x4*)&slab[(nt * 16 + lr + (QB - 1)) * DSTR + lg * 4];
    #pragma unroll
    for (int j = 0; j < 4; j++){
      float x = sv[j] + bf2f(g[j]);
      sv[j] = (mv == 1) ? -10000.f : x;
    }
    s[nt] = sv;
  }

  float fm[4];
  #pragma unroll
  for (int j = 0; j < 4; j++){
    float mx = -3.0e38f;
    #pragma unroll
    for (int nt = 0; nt < 16; nt++) mx = fmaxf(mx, s[nt][j]);
    #pragma unroll
    for (int off = 1; off < 16; off <<= 1) mx = fmaxf(mx, __shfl_xor(mx, off));
    if (lr == 0) redm[w * QB + lg * 4 + j] = mx;
  }
  __syncthreads();
  #pragma unroll
  for (int j = 0; j < 4; j++){
    int ql = lg * 4 + j;
    float mx = redm[ql];
    #pragma unroll
    for (int w2 = 1; w2 < 8; w2++) mx = fmaxf(mx, redm[w2 * QB + ql]);
    fm[j] = mx;
  }

  float ls[4] = {0.f, 0.f, 0.f, 0.f};
  #pragma unroll
  for (int nt = 0; nt < 16; nt++)
    #pragma unroll
    for (int j = 0; j < 4; j++){
      float p = __expf(s[nt][j] - fm[j]);
      ls[j] += p;
      slab[(lg * 4 + j) * PSTR + nt * 16 + lr] = f2bf(p);
    }
  #pragma unroll
  for (int j = 0; j < 4; j++){
    float sum = ls[j];
    #pragma unroll
    for (int off = 1; off < 16; off <<= 1) sum += __shfl_xor(sum, off);
    if (lr == 0) redl[w * QB + lg * 4 + j] = sum;
  }
  __syncthreads();
  float inv[4];
  #pragma unroll
  for (int j = 0; j < 4; j++){
    int ql = lg * 4 + j;
    float d = redl[ql];
    #pragma unroll
    for (int w2 = 1; w2 < 8; w2++) d += redl[w2 * QB + ql];
    inv[j] = 1.f / d;
  }

  {
    int qrow = tid >> 5, cb = (tid & 31) * 8;
    float dsum = redl[qrow];
    #pragma unroll
    for (int w2 = 1; w2 < 8; w2++) dsum += redl[w2 * QB + qrow];
    float invr = 1.f / dsum;
    float* mrow = map + (size_t)(h * LQ + q0 + qrow) * LQ;
    #pragma unroll
    for (int it = 0; it < 8; it++){
      u16x8 pv = *(u16x8*)&RP[it * SLABU + qrow * PSTR + cb];
      f32x4 o0, o1;
      #pragma unroll
      for (int j = 0; j < 4; j++){
        o0[j] = bf2f(pv[j]) * invr;
        o1[j] = bf2f(pv[4 + j]) * invr;
      }
      int c = cb + it * 256;
      __builtin_nontemporal_store(o0, (f32x4*)(mrow + c));
      __builtin_nontemporal_store(o1, (f32x4*)(mrow + c + 4));
    }
  }

  f32x4 o[4] = {};
  #pragma unroll
  for (int kc2 = 0; kc2 < 8; kc2++){
    u16x8 pa = *(u16x8*)&slab[lr * PSTR + kc2 * 32 + lg * 8];
    #pragma unroll
    for (int ni = 0; ni < 4; ni++){
      u16x8 vv = *(const u16x8*)(vt + (size_t)(h * DH + ni * 16 + lr) * LQ + kb + kc2 * 32 + lg * 8);
      o[ni] = MFMA(pa, vv, o[ni]);
    }
  }
  __syncthreads();

  float* Op = (float*)smem;
  #pragma unroll
  for (int ni = 0; ni < 4; ni++)
    #pragma unroll
    for (int j = 0; j < 4; j++)
      Op[(w * QB + lg * 4 + j) * 64 + ni * 16 + lr] = o[ni][j] * inv[j];
  __syncthreads();
  {
    int q = tid >> 5, dg = (tid & 31) * 2;
    float acc0 = 0.f, acc1 = 0.f;
    #pragma unroll
    for (int w2 = 0; w2 < 8; w2++){
      acc0 += Op[(w2 * QB + q) * 64 + dg];
      acc1 += Op[(w2 * QB + q) * 64 + dg + 1];
    }
    float* ap = att + (size_t)(q0 + q) * DM + h * DH + dg;
    ap[0] = acc0;
    ap[1] = acc1;
  }
}

extern "C" void kernel_launch(void* const* d_in, const int* in_sizes, int n_in,
                              void* d_out, int out_size, void* d_ws, size_t ws_size,
                              hipStream_t stream){
  const float* v_in = (const float*)d_in[0];
  const float* k_in = (const float*)d_in[1];
  const float* q_in = (const float*)d_in[2];
  const int*   mask = (const int*)d_in[3];
  const float* Wq   = (const float*)d_in[4];
  const float* Wk   = (const float*)d_in[5];
  const float* Wv   = (const float*)d_in[6];
  const float* Wrk  = (const float*)d_in[7];
  const float* r_w  = (const float*)d_in[8];
  const float* r_r  = (const float*)d_in[9];
  const float* Wo   = (const float*)d_in[10];
  const float* bo   = (const float*)d_in[11];

  char* ws = (char*)d_ws;
  u16* qh  = (u16*)(ws + 0);             // [12][2048][64] bf16
  u16* kh  = (u16*)(ws + 3145728);
  u16* vt  = (u16*)(ws + 6291456);       // [12][64][2048] bf16
  u16* rk  = (u16*)(ws + 9437184);       // [12][4095][64] bf16
  u16* qb  = (u16*)(ws + 15728640);      // [2048][768] bf16 inputs
  u16* kb  = (u16*)(ws + 18874368);
  u16* vb  = (u16*)(ws + 22020096);
  u16* WqT = (u16*)(ws + 25165824);      // [768][768] bf16 transposed weights
  u16* WkT = (u16*)(ws + 26345472);
  u16* WvT = (u16*)(ws + 27525120);
  u16* WrkT= (u16*)(ws + 28704768);
  u16* WoT = (u16*)(ws + 29884416);
  u16* peb = (u16*)(ws + 31064064);      // [4095][768] bf16
  float* att = (float*)(ws + 37355520);  // [2048][768] f32
  float* gamtab = (float*)(ws + 43646976);
  unsigned long long* gmax = (unsigned long long*)(ws + 44695552);
  double* logx = (double*)(ws + 44695616);
  double* Cf   = (double*)(ws + 44712000);

  float* out0 = (float*)d_out;                     // [2048][768] f32
  float* map  = out0 + (size_t)LQ * DM;            // [12][2048][2048] f32

  hipMemsetAsync(gmax, 0, 8, stream);
  gamma_tables_kernel<<<8, 256, 0, stream>>>(logx, Cf);
  gamma_probs_kernel<<<1024, 256, 0, stream>>>(logx, Cf, gamtab, gmax);
  pe_kernel<<<(NR * DM + 255) / 256, 256, 0, stream>>>(gamtab, gmax, peb);

  cvt_in_kernel<<<dim3(LQ * DM / 2048, 1, 3), 256, 0, stream>>>(q_in, k_in, v_in,
                                                                qb, kb, vb);
  cvtw_kernel<<<dim3(12, 12, 5), 256, 0, stream>>>(Wq, Wk, Wv, Wrk, Wo,
                                                   WqT, WkT, WvT, WrkT, WoT);

  proj3_kernel<<<dim3(32, 12, 3), 256, 0, stream>>>(qb, kb, vb, WqT, WkT, WvT,
                                                    qh, kh, vt);
  gemm_rk_kernel<<<dim3(64, 12), 256, 0, stream>>>(peb, WrkT, rk);

  hipFuncSetAttribute((const void*)attn_kernel,
                      hipFuncAttributeMaxDynamicSharedMemorySize, SMEM_ATTN);
  attn_kernel<<<dim3((LQ / QB) * NH), 512, SMEM_ATTN, stream>>>(qh, kh, vt, rk, mask,
                                                                r_w, r_r, map, att);
  gemm_out_kernel<<<dim3(32, 12), 256, 0, stream>>>(att, WoT, out0, bo);
}

// Round 19
// 284.784 us; speedup vs baseline: 1.6693x; 1.0130x over previous
//
#include <hip/hip_runtime.h>
#include <hip/hip_bf16.h>
#include <math.h>

typedef unsigned short u16;
typedef __bf16 bf16x8_t __attribute__((ext_vector_type(8)));
typedef u16 u16x8 __attribute__((ext_vector_type(8)));
typedef u16 u16x4 __attribute__((ext_vector_type(4)));
typedef float f32x4 __attribute__((ext_vector_type(4)));

#define NH 12
#define LQ 2048
#define DM 768
#define DH 64
#define NR 4095           // 2L-1
#define LN2F 0.6931471805599453f

__device__ __forceinline__ u16 f2bf(float f){
  unsigned x = __float_as_uint(f);
  return (u16)((x + 0x7fffu + ((x >> 16) & 1u)) >> 16);   // RTNE
}
__device__ __forceinline__ float bf2f(u16 u){ return __uint_as_float(((unsigned)u) << 16); }

__device__ __forceinline__ f32x4 MFMA(u16x8 a, u16x8 b, f32x4 c){
  return __builtin_amdgcn_mfma_f32_16x16x32_bf16(
      __builtin_bit_cast(bf16x8_t, a), __builtin_bit_cast(bf16x8_t, b), c, 0, 0, 0);
}

// ---------------- gamma tables: logx[2048] f64, Cf[128] f64 ----------------
__global__ void gamma_tables_kernel(double* __restrict__ logx, double* __restrict__ Cf){
  int i = blockIdx.x * 256 + threadIdx.x;
  if (i < 2048) logx[i] = (i > 0) ? log((double)i) : 0.0;
  if (i < 128){
    double fp1 = (double)(i + 1);
    double conc = 4.0 * fp1 * fp1;
    double rate = 0.25 * fp1;
    Cf[i] = conc * log(rate) - lgamma(conc);
  }
}

// ---------------- gamma pdf table + global max (f64 arg, f32 exp) ----------
__global__ void gamma_probs_kernel(const double* __restrict__ logx,
                                   const double* __restrict__ Cf,
                                   float* __restrict__ gamtab,
                                   unsigned* __restrict__ gmax){
  int idx = blockIdx.x * 256 + threadIdx.x;   // 2048*128
  int x = idx >> 7, f = idx & 127;
  double fp1 = (double)(f + 1);
  double conc = 4.0 * fp1 * fp1;
  double rate = 0.25 * fp1;
  double xl = (x > 0) ? (conc - 1.0) * logx[x] : 0.0;   // xlogy(a,0)=0
  double logp = xl - rate * (double)x + Cf[f];          // f64: cancellation-safe
  float p = __expf((float)logp);                        // f32: fast exp
  gamtab[idx] = p;
  float m = p;
  #pragma unroll
  for (int off = 1; off < 64; off <<= 1) m = fmaxf(m, __shfl_xor(m, off));
  if ((threadIdx.x & 63) == 0) atomicMax(gmax, __float_as_uint(m));  // p>=0: bits monotone
}

// ---------------- positional encodings -> bf16 peb[4095][768] ----------------
__global__ void pe_kernel(const float* __restrict__ gamtab,
                          const unsigned* __restrict__ gmax,
                          u16* __restrict__ peb){
  int idx = blockIdx.x * 256 + threadIdx.x;
  if (idx >= NR * DM) return;
  int p = idx / DM;
  int c = idx - p * DM;
  int f = c & 127;
  int kind = c >> 7;
  int pos = p - (LQ - 1);
  int apos = pos < 0 ? -pos : pos;
  float sgn = (pos > 0) ? 1.f : ((pos < 0) ? -1.f : 0.f);
  float v;
  int grp = kind >> 1;
  if (grp == 0){
    float hl = exp2f(3.f + 8.f * (float)f / 127.f);
    v = expf(-(LN2F / hl) * (float)apos);
  } else if (grp == 1){
    float cw = exp2f((float)(f + 1)) - 1.f;
    v = (cw > (float)apos) ? 1.f : 0.f;
  } else {
    float gm = __uint_as_float(*gmax);
    v = gamtab[apos * 128 + f] / gm;
  }
  if (kind & 1) v *= sgn;
  peb[idx] = f2bf(v);
}

// ---------------- input cvt: q/k/v f32 -> bf16 flat ----------------
__global__ void cvt_in_kernel(const float* q, const float* k, const float* v,
                              u16* qb, u16* kb, u16* vb){
  const int z = blockIdx.z;
  const float* src = (z == 0) ? q : (z == 1) ? k : v;
  u16* dst = (z == 0) ? qb : (z == 1) ? kb : vb;
  int base = (blockIdx.x * 256 + threadIdx.x) * 8;
  f32x4 a = *(const f32x4*)(src + base);
  f32x4 b = *(const f32x4*)(src + base + 4);
  u16x8 o;
  #pragma unroll
  for (int j = 0; j < 4; j++){ o[j] = f2bf(a[j]); o[4 + j] = f2bf(b[j]); }
  *(u16x8*)(dst + base) = o;
}

// ---------------- weight transpose+cvt: WT[n][k] bf16 = f2bf(W[k][n]) --------
__global__ void cvtw_kernel(const float* W0, const float* W1, const float* W2,
                            const float* W3, const float* W4,
                            u16* T0, u16* T1, u16* T2, u16* T3, u16* T4){
  __shared__ u16 tile[64 * 72];
  const int z = blockIdx.z;
  const float* W = (z == 0) ? W0 : (z == 1) ? W1 : (z == 2) ? W2 : (z == 3) ? W3 : W4;
  u16* T = (z == 0) ? T0 : (z == 1) ? T1 : (z == 2) ? T2 : (z == 3) ? T3 : T4;
  const int k0 = blockIdx.x * 64, n0 = blockIdx.y * 64;
  const int t = threadIdx.x;
  {
    int kr = t >> 2, ng = (t & 3) * 16;
    const float* p = W + (size_t)(k0 + kr) * DM + n0 + ng;
    u16x8 o0, o1;
    #pragma unroll
    for (int j = 0; j < 8; j++){ o0[j] = f2bf(p[j]); o1[j] = f2bf(p[8 + j]); }
    *(u16x8*)&tile[kr * 72 + ng] = o0;
    *(u16x8*)&tile[kr * 72 + ng + 8] = o1;
  }
  __syncthreads();
  {
    int nr = t >> 2, kg = (t & 3) * 16;
    u16x8 o0, o1;
    #pragma unroll
    for (int j = 0; j < 8; j++){
      o0[j] = tile[(kg + j) * 72 + nr];
      o1[j] = tile[(kg + j + 8) * 72 + nr];
    }
    u16* qp = T + (size_t)(n0 + nr) * DM + k0 + kg;
    *(u16x8*)qp = o0;
    *(u16x8*)(qp + 8) = o1;
  }
}

// ---------------- fused proj(q/k/v) + rk GEMM: one flat launch ---------------
// bid < 1152: z = bid/384 in {0,1,2} (q,k,v proj, 32x12 tiles)
// bid >= 1152: rk GEMM (peb x WrkT, 64x12 tiles)
#define GSTRB 72
__launch_bounds__(256)
__global__ void proj4_kernel(const u16* __restrict__ qb, const u16* __restrict__ kb,
                             const u16* __restrict__ vb, const u16* __restrict__ peb,
                             const u16* __restrict__ WqT, const u16* __restrict__ WkT,
                             const u16* __restrict__ WvT, const u16* __restrict__ WrkT,
                             u16* __restrict__ qh, u16* __restrict__ kh,
                             u16* __restrict__ vt, u16* __restrict__ rk){
  __shared__ u16 At[64 * GSTRB];
  __shared__ u16 Wt[64 * GSTRB];
  const int bid = blockIdx.x;
  int z, bx, by;
  if (bid < 1152){ z = bid / 384; int t = bid - z * 384; bx = t & 31; by = t >> 5; }
  else           { z = 3; int t = bid - 1152; bx = t & 63; by = t >> 6; }
  const u16* A  = (z == 0) ? qb : (z == 1) ? kb : (z == 2) ? vb : peb;
  const u16* WT = (z == 0) ? WqT : (z == 1) ? WkT : (z == 2) ? WvT : WrkT;
  const int m0 = bx * 64, n0 = by * 64;
  const int tid = threadIdx.x;
  const int w = tid >> 6, l = tid & 63, lr = l & 15, lg = l >> 4;
  const int moff = (w & 1) * 32, noff = (w >> 1) * 32;
  f32x4 acc[2][2] = {};
  const int arow = tid >> 2, akg = (tid & 3) * 16;
  for (int k0 = 0; k0 < DM; k0 += 64){
    {
      int m = m0 + arow;
      u16x8 a0 = {}, a1 = {};
      if (z < 3 || m < NR){
        const u16* ap = A + (size_t)m * DM + k0 + akg;
        a0 = *(const u16x8*)ap;
        a1 = *(const u16x8*)(ap + 8);
      }
      *(u16x8*)&At[arow * GSTRB + akg] = a0;
      *(u16x8*)&At[arow * GSTRB + akg + 8] = a1;
      const u16* wp = WT + (size_t)(n0 + arow) * DM + k0 + akg;
      *(u16x8*)&Wt[arow * GSTRB + akg] = *(const u16x8*)wp;
      *(u16x8*)&Wt[arow * GSTRB + akg + 8] = *(const u16x8*)(wp + 8);
    }
    __syncthreads();
    #pragma unroll
    for (int kc = 0; kc < 2; kc++){
      u16x8 af0 = *(u16x8*)&At[(moff + lr) * GSTRB + kc * 32 + lg * 8];
      u16x8 af1 = *(u16x8*)&At[(moff + 16 + lr) * GSTRB + kc * 32 + lg * 8];
      u16x8 bf0 = *(u16x8*)&Wt[(noff + lr) * GSTRB + kc * 32 + lg * 8];
      u16x8 bf1 = *(u16x8*)&Wt[(noff + 16 + lr) * GSTRB + kc * 32 + lg * 8];
      acc[0][0] = MFMA(af0, bf0, acc[0][0]);
      acc[0][1] = MFMA(af0, bf1, acc[0][1]);
      acc[1][0] = MFMA(af1, bf0, acc[1][0]);
      acc[1][1] = MFMA(af1, bf1, acc[1][1]);
    }
    __syncthreads();
  }
  if (z == 2){
    // vt transposed: [(n>>6)*64 + (n&63)][2048]
    #pragma unroll
    for (int mi = 0; mi < 2; mi++)
      #pragma unroll
      for (int ni = 0; ni < 2; ni++){
        int m = m0 + moff + mi * 16 + lg * 4;
        int n = n0 + noff + ni * 16 + lr;
        u16x4 ov;
        #pragma unroll
        for (int j = 0; j < 4; j++) ov[j] = f2bf(acc[mi][ni][j]);
        *(u16x4*)(vt + ((size_t)(n >> 6) * DH + (n & 63)) * LQ + m) = ov;
      }
  } else if (z == 3){
    #pragma unroll
    for (int mi = 0; mi < 2; mi++)
      #pragma unroll
      for (int ni = 0; ni < 2; ni++)
        #pragma unroll
        for (int j = 0; j < 4; j++){
          int m = m0 + moff + mi * 16 + lg * 4 + j;
          int n = n0 + noff + ni * 16 + lr;
          if (m < NR)
            rk[((size_t)(n >> 6) * NR + m) * DH + (n & 63)] = f2bf(acc[mi][ni][j]);
        }
  } else {
    u16* outb = (z == 0) ? qh : kh;
    const float scale = (z == 0) ? 0.125f : 1.f;
    #pragma unroll
    for (int mi = 0; mi < 2; mi++)
      #pragma unroll
      for (int ni = 0; ni < 2; ni++)
        #pragma unroll
        for (int j = 0; j < 4; j++){
          int m = m0 + moff + mi * 16 + lg * 4 + j;
          int n = n0 + noff + ni * 16 + lr;
          outb[((size_t)(n >> 6) * LQ + m) * DH + (n & 63)] = f2bf(acc[mi][ni][j] * scale);
        }
  }
}

// ---------------- out-proj GEMM: f32 att x WoT bf16, f32 out + bias ----------
__launch_bounds__(256)
__global__ void gemm_out_kernel(const float* __restrict__ A, const u16* __restrict__ WT,
                                float* __restrict__ outf, const float* __restrict__ bias){
  __shared__ u16 At[64 * GSTRB];
  __shared__ u16 Wt[64 * GSTRB];
  const int m0 = blockIdx.x * 64, n0 = blockIdx.y * 64;
  const int tid = threadIdx.x;
  const int w = tid >> 6, l = tid & 63, lr = l & 15, lg = l >> 4;
  const int moff = (w & 1) * 32, noff = (w >> 1) * 32;
  f32x4 acc[2][2] = {};
  const int arow = tid >> 2, akg = (tid & 3) * 16;
  for (int k0 = 0; k0 < DM; k0 += 64){
    {
      const float* ap = A + (size_t)(m0 + arow) * DM + k0 + akg;
      u16x8 a0, a1;
      #pragma unroll
      for (int j = 0; j < 8; j++){ a0[j] = f2bf(ap[j]); a1[j] = f2bf(ap[8 + j]); }
      *(u16x8*)&At[arow * GSTRB + akg] = a0;
      *(u16x8*)&At[arow * GSTRB + akg + 8] = a1;
      const u16* wp = WT + (size_t)(n0 + arow) * DM + k0 + akg;
      *(u16x8*)&Wt[arow * GSTRB + akg] = *(const u16x8*)wp;
      *(u16x8*)&Wt[arow * GSTRB + akg + 8] = *(const u16x8*)(wp + 8);
    }
    __syncthreads();
    #pragma unroll
    for (int kc = 0; kc < 2; kc++){
      u16x8 af0 = *(u16x8*)&At[(moff + lr) * GSTRB + kc * 32 + lg * 8];
      u16x8 af1 = *(u16x8*)&At[(moff + 16 + lr) * GSTRB + kc * 32 + lg * 8];
      u16x8 bf0 = *(u16x8*)&Wt[(noff + lr) * GSTRB + kc * 32 + lg * 8];
      u16x8 bf1 = *(u16x8*)&Wt[(noff + 16 + lr) * GSTRB + kc * 32 + lg * 8];
      acc[0][0] = MFMA(af0, bf0, acc[0][0]);
      acc[0][1] = MFMA(af0, bf1, acc[0][1]);
      acc[1][0] = MFMA(af1, bf0, acc[1][0]);
      acc[1][1] = MFMA(af1, bf1, acc[1][1]);
    }
    __syncthreads();
  }
  #pragma unroll
  for (int mi = 0; mi < 2; mi++)
    #pragma unroll
    for (int ni = 0; ni < 2; ni++)
      #pragma unroll
      for (int j = 0; j < 4; j++){
        int m = m0 + moff + mi * 16 + lg * 4 + j;
        int n = n0 + noff + ni * 16 + lr;
        __builtin_nontemporal_store(acc[mi][ni][j] + bias[n], &outf[(size_t)m * DM + n]);
      }
}

// ---------------- fused rel-pos attention (r17, unchanged) -------------------
#define QB 16
#define DSTR 16
#define DROWS 288
#define PSTR 264
#define SLABU (DROWS * DSTR)
#define SMEM_ATTN (8 * SLABU * 2 + 1024)
__launch_bounds__(512, 4)
__global__ void attn_kernel(const u16* __restrict__ qh, const u16* __restrict__ kh,
                            const u16* __restrict__ vt, const u16* __restrict__ rk,
                            const int* __restrict__ mask,
                            const float* __restrict__ r_w, const float* __restrict__ r_r,
                            float* __restrict__ map, float* __restrict__ att){
  extern __shared__ char smem[];
  u16* RP = (u16*)smem;
  float* redm = (float*)(smem + 8 * SLABU * 2);
  float* redl = redm + 128;
  const int bid = blockIdx.x;
  const int swz = (bid & 7) * 192 + (bid >> 3);
  const int h = swz >> 7, q0 = (swz & 127) * QB;
  const int tid = threadIdx.x, w = tid >> 6, l = tid & 63, lr = l & 15, lg = l >> 4;
  const int roff = (LQ - 1) - q0 - (QB - 1);
  const int kb = w * 256;
  u16* slab = RP + w * SLABU;

  u16x8 a1[2], a2[2];
  #pragma unroll
  for (int kc = 0; kc < 2; kc++){
    u16x8 qv = *(const u16x8*)(qh + (size_t)(h * LQ + q0 + lr) * DH + kc * 32 + lg * 8);
    #pragma unroll
    for (int j = 0; j < 8; j++){
      int d = kc * 32 + lg * 8 + j;
      float f = bf2f(qv[j]);
      a1[kc][j] = f2bf(f + r_w[h * DH + d]);
      a2[kc][j] = f2bf(f + r_r[h * DH + d]);
    }
  }

  #pragma unroll 4
  for (int t = 0; t < 17; t++){
    int r = roff + kb + t * 16 + lr;
    if (r > NR - 1) r = NR - 1;
    const u16* rp = rk + (size_t)(h * NR + r) * DH + lg * 8;
    u16x8 b0 = *(const u16x8*)(rp);
    u16x8 b1 = *(const u16x8*)(rp + 32);
    f32x4 racc = {};
    racc = MFMA(a2[0], b0, racc);
    racc = MFMA(a2[1], b1, racc);
    int lc = t * 16 + lr;
    #pragma unroll
    for (int j = 0; j < 4; j++){
      int ql = lg * 4 + j;
      slab[(lc + ql) * DSTR + ql] = f2bf(racc[j]);
    }
  }
  __asm__ volatile("s_waitcnt lgkmcnt(0)" ::: "memory");
  __builtin_amdgcn_sched_barrier(0);

  f32x4 s[16];
  #pragma unroll
  for (int nt = 0; nt < 16; nt++){
    const u16* kp = kh + (size_t)(h * LQ + kb + nt * 16 + lr) * DH + lg * 8;
    u16x8 b0 = *(const u16x8*)(kp);
    u16x8 b1 = *(const u16x8*)(kp + 32);
    f32x4 sv = {};
    sv = MFMA(a1[0], b0, sv);
    sv = MFMA(a1[1], b1, sv);
    int mv = mask[kb + nt * 16 + lr];
    u16x4 g = *(u16x4*)&slab[(nt * 16 + lr + (QB - 1)) * DSTR + lg * 4];
    #pragma unroll
    for (int j = 0; j < 4; j++){
      float x = sv[j] + bf2f(g[j]);
      sv[j] = (mv == 1) ? -10000.f : x;
    }
    s[nt] = sv;
  }

  float fm[4];
  #pragma unroll
  for (int j = 0; j < 4; j++){
    float mx = -3.0e38f;
    #pragma unroll
    for (int nt = 0; nt < 16; nt++) mx = fmaxf(mx, s[nt][j]);
    #pragma unroll
    for (int off = 1; off < 16; off <<= 1) mx = fmaxf(mx, __shfl_xor(mx, off));
    if (lr == 0) redm[w * QB + lg * 4 + j] = mx;
  }
  __syncthreads();
  #pragma unroll
  for (int j = 0; j < 4; j++){
    int ql = lg * 4 + j;
    float mx = redm[ql];
    #pragma unroll
    for (int w2 = 1; w2 < 8; w2++) mx = fmaxf(mx, redm[w2 * QB + ql]);
    fm[j] = mx;
  }

  float ls[4] = {0.f, 0.f, 0.f, 0.f};
  #pragma unroll
  for (int nt = 0; nt < 16; nt++)
    #pragma unroll
    for (int j = 0; j < 4; j++){
      float p = __expf(s[nt][j] - fm[j]);
      ls[j] += p;
      slab[(lg * 4 + j) * PSTR + nt * 16 + lr] = f2bf(p);
    }
  #pragma unroll
  for (int j = 0; j < 4; j++){
    float sum = ls[j];
    #pragma unroll
    for (int off = 1; off < 16; off <<= 1) sum += __shfl_xor(sum, off);
    if (lr == 0) redl[w * QB + lg * 4 + j] = sum;
  }
  __syncthreads();
  float inv[4];
  #pragma unroll
  for (int j = 0; j < 4; j++){
    int ql = lg * 4 + j;
    float d = redl[ql];
    #pragma unroll
    for (int w2 = 1; w2 < 8; w2++) d += redl[w2 * QB + ql];
    inv[j] = 1.f / d;
  }

  {
    int qrow = tid >> 5, cb = (tid & 31) * 8;
    float dsum = redl[qrow];
    #pragma unroll
    for (int w2 = 1; w2 < 8; w2++) dsum += redl[w2 * QB + qrow];
    float invr = 1.f / dsum;
    float* mrow = map + (size_t)(h * LQ + q0 + qrow) * LQ;
    #pragma unroll
    for (int it = 0; it < 8; it++){
      u16x8 pv = *(u16x8*)&RP[it * SLABU + qrow * PSTR + cb];
      f32x4 o0, o1;
      #pragma unroll
      for (int j = 0; j < 4; j++){
        o0[j] = bf2f(pv[j]) * invr;
        o1[j] = bf2f(pv[4 + j]) * invr;
      }
      int c = cb + it * 256;
      __builtin_nontemporal_store(o0, (f32x4*)(mrow + c));
      __builtin_nontemporal_store(o1, (f32x4*)(mrow + c + 4));
    }
  }

  f32x4 o[4] = {};
  #pragma unroll
  for (int kc2 = 0; kc2 < 8; kc2++){
    u16x8 pa = *(u16x8*)&slab[lr * PSTR + kc2 * 32 + lg * 8];
    #pragma unroll
    for (int ni = 0; ni < 4; ni++){
      u16x8 vv = *(const u16x8*)(vt + (size_t)(h * DH + ni * 16 + lr) * LQ + kb + kc2 * 32 + lg * 8);
      o[ni] = MFMA(pa, vv, o[ni]);
    }
  }
  __syncthreads();

  float* Op = (float*)smem;
  #pragma unroll
  for (int ni = 0; ni < 4; ni++)
    #pragma unroll
    for (int j = 0; j < 4; j++)
      Op[(w * QB + lg * 4 + j) * 64 + ni * 16 + lr] = o[ni][j] * inv[j];
  __syncthreads();
  {
    int q = tid >> 5, dg = (tid & 31) * 2;
    float acc0 = 0.f, acc1 = 0.f;
    #pragma unroll
    for (int w2 = 0; w2 < 8; w2++){
      acc0 += Op[(w2 * QB + q) * 64 + dg];
      acc1 += Op[(w2 * QB + q) * 64 + dg + 1];
    }
    float* ap = att + (size_t)(q0 + q) * DM + h * DH + dg;
    ap[0] = acc0;
    ap[1] = acc1;
  }
}

extern "C" void kernel_launch(void* const* d_in, const int* in_sizes, int n_in,
                              void* d_out, int out_size, void* d_ws, size_t ws_size,
                              hipStream_t stream){
  const float* v_in = (const float*)d_in[0];
  const float* k_in = (const float*)d_in[1];
  const float* q_in = (const float*)d_in[2];
  const int*   mask = (const int*)d_in[3];
  const float* Wq   = (const float*)d_in[4];
  const float* Wk   = (const float*)d_in[5];
  const float* Wv   = (const float*)d_in[6];
  const float* Wrk  = (const float*)d_in[7];
  const float* r_w  = (const float*)d_in[8];
  const float* r_r  = (const float*)d_in[9];
  const float* Wo   = (const float*)d_in[10];
  const float* bo   = (const float*)d_in[11];

  char* ws = (char*)d_ws;
  u16* qh  = (u16*)(ws + 0);             // [12][2048][64] bf16
  u16* kh  = (u16*)(ws + 3145728);
  u16* vt  = (u16*)(ws + 6291456);       // [12][64][2048] bf16
  u16* rk  = (u16*)(ws + 9437184);       // [12][4095][64] bf16
  u16* qb  = (u16*)(ws + 15728640);      // [2048][768] bf16 inputs
  u16* kb  = (u16*)(ws + 18874368);
  u16* vb  = (u16*)(ws + 22020096);
  u16* WqT = (u16*)(ws + 25165824);      // [768][768] bf16 transposed weights
  u16* WkT = (u16*)(ws + 26345472);
  u16* WvT = (u16*)(ws + 27525120);
  u16* WrkT= (u16*)(ws + 28704768);
  u16* WoT = (u16*)(ws + 29884416);
  u16* peb = (u16*)(ws + 31064064);      // [4095][768] bf16
  float* att = (float*)(ws + 37355520);  // [2048][768] f32
  float* gamtab = (float*)(ws + 43646976);
  unsigned* gmax = (unsigned*)(ws + 44695552);
  double* logx = (double*)(ws + 44695616);
  double* Cf   = (double*)(ws + 44712000);

  float* out0 = (float*)d_out;                     // [2048][768] f32
  float* map  = out0 + (size_t)LQ * DM;            // [12][2048][2048] f32

  hipMemsetAsync(gmax, 0, 4, stream);
  gamma_tables_kernel<<<8, 256, 0, stream>>>(logx, Cf);
  gamma_probs_kernel<<<1024, 256, 0, stream>>>(logx, Cf, gamtab, gmax);
  pe_kernel<<<(NR * DM + 255) / 256, 256, 0, stream>>>(gamtab, gmax, peb);

  cvt_in_kernel<<<dim3(LQ * DM / 2048, 1, 3), 256, 0, stream>>>(q_in, k_in, v_in,
                                                                qb, kb, vb);
  cvtw_kernel<<<dim3(12, 12, 5), 256, 0, stream>>>(Wq, Wk, Wv, Wrk, Wo,
                                                   WqT, WkT, WvT, WrkT, WoT);

  proj4_kernel<<<dim3(1920), 256, 0, stream>>>(qb, kb, vb, peb,
                                               WqT, WkT, WvT, WrkT,
                                               qh, kh, vt, rk);

  hipFuncSetAttribute((const void*)attn_kernel,
                      hipFuncAttributeMaxDynamicSharedMemorySize, SMEM_ATTN);
  attn_kernel<<<dim3((LQ / QB) * NH), 512, SMEM_ATTN, stream>>>(qh, kh, vt, rk, mask,
                                                                r_w, r_r, map, att);
  gemm_out_kernel<<<dim3(32, 12), 256, 0, stream>>>(att, WoT, out0, bo);
}

// Round 20
// 271.385 us; speedup vs baseline: 1.7518x; 1.0494x over previous
//
#include <hip/hip_runtime.h>
#include <hip/hip_bf16.h>
#include <math.h>

typedef unsigned short u16;
typedef __bf16 bf16x8_t __attribute__((ext_vector_type(8)));
typedef u16 u16x8 __attribute__((ext_vector_type(8)));
typedef u16 u16x4 __attribute__((ext_vector_type(4)));
typedef float f32x4 __attribute__((ext_vector_type(4)));

#define NH 12
#define LQ 2048
#define DM 768
#define DH 64
#define NR 4095           // 2L-1
#define LN2F 0.6931471805599453f

__device__ __forceinline__ u16 f2bf(float f){
  unsigned x = __float_as_uint(f);
  return (u16)((x + 0x7fffu + ((x >> 16) & 1u)) >> 16);   // RTNE
}
__device__ __forceinline__ float bf2f(u16 u){ return __uint_as_float(((unsigned)u) << 16); }

__device__ __forceinline__ f32x4 MFMA(u16x8 a, u16x8 b, f32x4 c){
  return __builtin_amdgcn_mfma_f32_16x16x32_bf16(
      __builtin_bit_cast(bf16x8_t, a), __builtin_bit_cast(bf16x8_t, b), c, 0, 0, 0);
}

// ---------------- merged prep: cvt q/k/v + transpose-cvt 5 weights + gamma tables
// bid < 2304: input cvt (z = bid/768)
// 2304 <= bid < 3024: weight transpose+cvt (z = (bid-2304)/144)
// bid >= 3024: gamma tables (8 blocks)
__launch_bounds__(256)
__global__ void prep_kernel(const float* q, const float* k, const float* v,
                            const float* W0, const float* W1, const float* W2,
                            const float* W3, const float* W4,
                            u16* qb, u16* kb, u16* vb,
                            u16* T0, u16* T1, u16* T2, u16* T3, u16* T4,
                            double* __restrict__ logx, double* __restrict__ Cf){
  __shared__ u16 tile[64 * 72];
  const int bid = blockIdx.x;
  const int t = threadIdx.x;
  if (bid < 2304){
    int z = bid / 768, b = bid - z * 768;
    const float* src = (z == 0) ? q : (z == 1) ? k : v;
    u16* dst = (z == 0) ? qb : (z == 1) ? kb : vb;
    int base = (b * 256 + t) * 8;
    f32x4 a0 = *(const f32x4*)(src + base);
    f32x4 a1 = *(const f32x4*)(src + base + 4);
    u16x8 o;
    #pragma unroll
    for (int j = 0; j < 4; j++){ o[j] = f2bf(a0[j]); o[4 + j] = f2bf(a1[j]); }
    *(u16x8*)(dst + base) = o;
  } else if (bid < 3024){
    int r = bid - 2304;
    int z = r / 144, rem = r - z * 144;
    int k0 = (rem % 12) * 64, n0 = (rem / 12) * 64;
    const float* W = (z == 0) ? W0 : (z == 1) ? W1 : (z == 2) ? W2 : (z == 3) ? W3 : W4;
    u16* T = (z == 0) ? T0 : (z == 1) ? T1 : (z == 2) ? T2 : (z == 3) ? T3 : T4;
    {
      int kr = t >> 2, ng = (t & 3) * 16;
      const float* p = W + (size_t)(k0 + kr) * DM + n0 + ng;
      u16x8 o0, o1;
      #pragma unroll
      for (int j = 0; j < 8; j++){ o0[j] = f2bf(p[j]); o1[j] = f2bf(p[8 + j]); }
      *(u16x8*)&tile[kr * 72 + ng] = o0;
      *(u16x8*)&tile[kr * 72 + ng + 8] = o1;
    }
    __syncthreads();
    {
      int nr = t >> 2, kg = (t & 3) * 16;
      u16x8 o0, o1;
      #pragma unroll
      for (int j = 0; j < 8; j++){
        o0[j] = tile[(kg + j) * 72 + nr];
        o1[j] = tile[(kg + j + 8) * 72 + nr];
      }
      u16* qp = T + (size_t)(n0 + nr) * DM + k0 + kg;
      *(u16x8*)qp = o0;
      *(u16x8*)(qp + 8) = o1;
    }
  } else {
    int i = (bid - 3024) * 256 + t;
    if (i < 2048) logx[i] = (i > 0) ? log((double)i) : 0.0;
    if (i < 128){
      double fp1 = (double)(i + 1);
      double conc = 4.0 * fp1 * fp1;
      double rate = 0.25 * fp1;
      Cf[i] = conc * log(rate) - lgamma(conc);
    }
  }
}

// ---------------- gamma pdf table + global max (f64 arg, f32 exp) ----------
__global__ void gamma_probs_kernel(const double* __restrict__ logx,
                                   const double* __restrict__ Cf,
                                   float* __restrict__ gamtab,
                                   unsigned* __restrict__ gmax){
  int idx = blockIdx.x * 256 + threadIdx.x;   // 2048*128
  int x = idx >> 7, f = idx & 127;
  double fp1 = (double)(f + 1);
  double conc = 4.0 * fp1 * fp1;
  double rate = 0.25 * fp1;
  double xl = (x > 0) ? (conc - 1.0) * logx[x] : 0.0;   // xlogy(a,0)=0
  double logp = xl - rate * (double)x + Cf[f];          // f64: cancellation-safe
  float p = __expf((float)logp);                        // f32: fast exp
  gamtab[idx] = p;
  float m = p;
  #pragma unroll
  for (int off = 1; off < 64; off <<= 1) m = fmaxf(m, __shfl_xor(m, off));
  if ((threadIdx.x & 63) == 0) atomicMax(gmax, __float_as_uint(m));
}

// ---------------- positional encodings -> bf16 peb[4095][768] ----------------
__global__ void pe_kernel(const float* __restrict__ gamtab,
                          const unsigned* __restrict__ gmax,
                          u16* __restrict__ peb){
  int idx = blockIdx.x * 256 + threadIdx.x;
  if (idx >= NR * DM) return;
  int p = idx / DM;
  int c = idx - p * DM;
  int f = c & 127;
  int kind = c >> 7;
  int pos = p - (LQ - 1);
  int apos = pos < 0 ? -pos : pos;
  float sgn = (pos > 0) ? 1.f : ((pos < 0) ? -1.f : 0.f);
  float v;
  int grp = kind >> 1;
  if (grp == 0){
    float hl = exp2f(3.f + 8.f * (float)f / 127.f);
    v = expf(-(LN2F / hl) * (float)apos);
  } else if (grp == 1){
    float cw = exp2f((float)(f + 1)) - 1.f;
    v = (cw > (float)apos) ? 1.f : 0.f;
  } else {
    float gm = __uint_as_float(*gmax);
    v = gamtab[apos * 128 + f] / gm;
  }
  if (kind & 1) v *= sgn;
  peb[idx] = f2bf(v);
}

// ---------------- fused proj(q/k/v) + rk GEMM: one flat launch ---------------
#define GSTRB 72
__launch_bounds__(256)
__global__ void proj4_kernel(const u16* __restrict__ qb, const u16* __restrict__ kb,
                             const u16* __restrict__ vb, const u16* __restrict__ peb,
                             const u16* __restrict__ WqT, const u16* __restrict__ WkT,
                             const u16* __restrict__ WvT, const u16* __restrict__ WrkT,
                             u16* __restrict__ qh, u16* __restrict__ kh,
                             u16* __restrict__ vt, u16* __restrict__ rk){
  __shared__ u16 At[64 * GSTRB];
  __shared__ u16 Wt[64 * GSTRB];
  const int bid = blockIdx.x;
  int z, bx, by;
  if (bid < 1152){ z = bid / 384; int t = bid - z * 384; bx = t & 31; by = t >> 5; }
  else           { z = 3; int t = bid - 1152; bx = t & 63; by = t >> 6; }
  const u16* A  = (z == 0) ? qb : (z == 1) ? kb : (z == 2) ? vb : peb;
  const u16* WT = (z == 0) ? WqT : (z == 1) ? WkT : (z == 2) ? WvT : WrkT;
  const int m0 = bx * 64, n0 = by * 64;
  const int tid = threadIdx.x;
  const int w = tid >> 6, l = tid & 63, lr = l & 15, lg = l >> 4;
  const int moff = (w & 1) * 32, noff = (w >> 1) * 32;
  f32x4 acc[2][2] = {};
  const int arow = tid >> 2, akg = (tid & 3) * 16;
  for (int k0 = 0; k0 < DM; k0 += 64){
    {
      int m = m0 + arow;
      u16x8 a0 = {}, a1 = {};
      if (z < 3 || m < NR){
        const u16* ap = A + (size_t)m * DM + k0 + akg;
        a0 = *(const u16x8*)ap;
        a1 = *(const u16x8*)(ap + 8);
      }
      *(u16x8*)&At[arow * GSTRB + akg] = a0;
      *(u16x8*)&At[arow * GSTRB + akg + 8] = a1;
      const u16* wp = WT + (size_t)(n0 + arow) * DM + k0 + akg;
      *(u16x8*)&Wt[arow * GSTRB + akg] = *(const u16x8*)wp;
      *(u16x8*)&Wt[arow * GSTRB + akg + 8] = *(const u16x8*)(wp + 8);
    }
    __syncthreads();
    #pragma unroll
    for (int kc = 0; kc < 2; kc++){
      u16x8 af0 = *(u16x8*)&At[(moff + lr) * GSTRB + kc * 32 + lg * 8];
      u16x8 af1 = *(u16x8*)&At[(moff + 16 + lr) * GSTRB + kc * 32 + lg * 8];
      u16x8 bf0 = *(u16x8*)&Wt[(noff + lr) * GSTRB + kc * 32 + lg * 8];
      u16x8 bf1 = *(u16x8*)&Wt[(noff + 16 + lr) * GSTRB + kc * 32 + lg * 8];
      acc[0][0] = MFMA(af0, bf0, acc[0][0]);
      acc[0][1] = MFMA(af0, bf1, acc[0][1]);
      acc[1][0] = MFMA(af1, bf0, acc[1][0]);
      acc[1][1] = MFMA(af1, bf1, acc[1][1]);
    }
    __syncthreads();
  }
  if (z == 2){
    #pragma unroll
    for (int mi = 0; mi < 2; mi++)
      #pragma unroll
      for (int ni = 0; ni < 2; ni++){
        int m = m0 + moff + mi * 16 + lg * 4;
        int n = n0 + noff + ni * 16 + lr;
        u16x4 ov;
        #pragma unroll
        for (int j = 0; j < 4; j++) ov[j] = f2bf(acc[mi][ni][j]);
        *(u16x4*)(vt + ((size_t)(n >> 6) * DH + (n & 63)) * LQ + m) = ov;
      }
  } else if (z == 3){
    #pragma unroll
    for (int mi = 0; mi < 2; mi++)
      #pragma unroll
      for (int ni = 0; ni < 2; ni++)
        #pragma unroll
        for (int j = 0; j < 4; j++){
          int m = m0 + moff + mi * 16 + lg * 4 + j;
          int n = n0 + noff + ni * 16 + lr;
          if (m < NR)
            rk[((size_t)(n >> 6) * NR + m) * DH + (n & 63)] = f2bf(acc[mi][ni][j]);
        }
  } else {
    u16* outb = (z == 0) ? qh : kh;
    const float scale = (z == 0) ? 0.125f : 1.f;
    #pragma unroll
    for (int mi = 0; mi < 2; mi++)
      #pragma unroll
      for (int ni = 0; ni < 2; ni++)
        #pragma unroll
        for (int j = 0; j < 4; j++){
          int m = m0 + moff + mi * 16 + lg * 4 + j;
          int n = n0 + noff + ni * 16 + lr;
          outb[((size_t)(n >> 6) * LQ + m) * DH + (n & 63)] = f2bf(acc[mi][ni][j] * scale);
        }
  }
}

// ---------------- out-proj GEMM: bf16 att x WoT bf16, f32 out + bias ---------
__launch_bounds__(256)
__global__ void gemm_out_kernel(const u16* __restrict__ A, const u16* __restrict__ WT,
                                float* __restrict__ outf, const float* __restrict__ bias){
  __shared__ u16 At[64 * GSTRB];
  __shared__ u16 Wt[64 * GSTRB];
  const int m0 = blockIdx.x * 64, n0 = blockIdx.y * 64;
  const int tid = threadIdx.x;
  const int w = tid >> 6, l = tid & 63, lr = l & 15, lg = l >> 4;
  const int moff = (w & 1) * 32, noff = (w >> 1) * 32;
  f32x4 acc[2][2] = {};
  const int arow = tid >> 2, akg = (tid & 3) * 16;
  for (int k0 = 0; k0 < DM; k0 += 64){
    {
      const u16* ap = A + (size_t)(m0 + arow) * DM + k0 + akg;
      *(u16x8*)&At[arow * GSTRB + akg] = *(const u16x8*)ap;
      *(u16x8*)&At[arow * GSTRB + akg + 8] = *(const u16x8*)(ap + 8);
      const u16* wp = WT + (size_t)(n0 + arow) * DM + k0 + akg;
      *(u16x8*)&Wt[arow * GSTRB + akg] = *(const u16x8*)wp;
      *(u16x8*)&Wt[arow * GSTRB + akg + 8] = *(const u16x8*)(wp + 8);
    }
    __syncthreads();
    #pragma unroll
    for (int kc = 0; kc < 2; kc++){
      u16x8 af0 = *(u16x8*)&At[(moff + lr) * GSTRB + kc * 32 + lg * 8];
      u16x8 af1 = *(u16x8*)&At[(moff + 16 + lr) * GSTRB + kc * 32 + lg * 8];
      u16x8 bf0 = *(u16x8*)&Wt[(noff + lr) * GSTRB + kc * 32 + lg * 8];
      u16x8 bf1 = *(u16x8*)&Wt[(noff + 16 + lr) * GSTRB + kc * 32 + lg * 8];
      acc[0][0] = MFMA(af0, bf0, acc[0][0]);
      acc[0][1] = MFMA(af0, bf1, acc[0][1]);
      acc[1][0] = MFMA(af1, bf0, acc[1][0]);
      acc[1][1] = MFMA(af1, bf1, acc[1][1]);
    }
    __syncthreads();
  }
  #pragma unroll
  for (int mi = 0; mi < 2; mi++)
    #pragma unroll
    for (int ni = 0; ni < 2; ni++)
      #pragma unroll
      for (int j = 0; j < 4; j++){
        int m = m0 + moff + mi * 16 + lg * 4 + j;
        int n = n0 + noff + ni * 16 + lr;
        __builtin_nontemporal_store(acc[mi][ni][j] + bias[n], &outf[(size_t)m * DM + n]);
      }
}

// ---------------- fused rel-pos attention (r17; att emitted bf16) ------------
#define QB 16
#define DSTR 16
#define DROWS 288
#define PSTR 264
#define SLABU (DROWS * DSTR)
#define SMEM_ATTN (8 * SLABU * 2 + 1024)
__launch_bounds__(512, 4)
__global__ void attn_kernel(const u16* __restrict__ qh, const u16* __restrict__ kh,
                            const u16* __restrict__ vt, const u16* __restrict__ rk,
                            const int* __restrict__ mask,
                            const float* __restrict__ r_w, const float* __restrict__ r_r,
                            float* __restrict__ map, u16* __restrict__ att){
  extern __shared__ char smem[];
  u16* RP = (u16*)smem;
  float* redm = (float*)(smem + 8 * SLABU * 2);
  float* redl = redm + 128;
  const int bid = blockIdx.x;
  const int swz = (bid & 7) * 192 + (bid >> 3);
  const int h = swz >> 7, q0 = (swz & 127) * QB;
  const int tid = threadIdx.x, w = tid >> 6, l = tid & 63, lr = l & 15, lg = l >> 4;
  const int roff = (LQ - 1) - q0 - (QB - 1);
  const int kb = w * 256;
  u16* slab = RP + w * SLABU;

  u16x8 a1[2], a2[2];
  #pragma unroll
  for (int kc = 0; kc < 2; kc++){
    u16x8 qv = *(const u16x8*)(qh + (size_t)(h * LQ + q0 + lr) * DH + kc * 32 + lg * 8);
    #pragma unroll
    for (int j = 0; j < 8; j++){
      int d = kc * 32 + lg * 8 + j;
      float f = bf2f(qv[j]);
      a1[kc][j] = f2bf(f + r_w[h * DH + d]);
      a2[kc][j] = f2bf(f + r_r[h * DH + d]);
    }
  }

  #pragma unroll 4
  for (int t = 0; t < 17; t++){
    int r = roff + kb + t * 16 + lr;
    if (r > NR - 1) r = NR - 1;
    const u16* rp = rk + (size_t)(h * NR + r) * DH + lg * 8;
    u16x8 b0 = *(const u16x8*)(rp);
    u16x8 b1 = *(const u16x8*)(rp + 32);
    f32x4 racc = {};
    racc = MFMA(a2[0], b0, racc);
    racc = MFMA(a2[1], b1, racc);
    int lc = t * 16 + lr;
    #pragma unroll
    for (int j = 0; j < 4; j++){
      int ql = lg * 4 + j;
      slab[(lc + ql) * DSTR + ql] = f2bf(racc[j]);
    }
  }
  __asm__ volatile("s_waitcnt lgkmcnt(0)" ::: "memory");
  __builtin_amdgcn_sched_barrier(0);

  f32x4 s[16];
  #pragma unroll
  for (int nt = 0; nt < 16; nt++){
    const u16* kp = kh + (size_t)(h * LQ + kb + nt * 16 + lr) * DH + lg * 8;
    u16x8 b0 = *(const u16x8*)(kp);
    u16x8 b1 = *(const u16x8*)(kp + 32);
    f32x4 sv = {};
    sv = MFMA(a1[0], b0, sv);
    sv = MFMA(a1[1], b1, sv);
    int mv = mask[kb + nt * 16 + lr];
    u16x4 g = *(u16x4*)&slab[(nt * 16 + lr + (QB - 1)) * DSTR + lg * 4];
    #pragma unroll
    for (int j = 0; j < 4; j++){
      float x = sv[j] + bf2f(g[j]);
      sv[j] = (mv == 1) ? -10000.f : x;
    }
    s[nt] = sv;
  }

  float fm[4];
  #pragma unroll
  for (int j = 0; j < 4; j++){
    float mx = -3.0e38f;
    #pragma unroll
    for (int nt = 0; nt < 16; nt++) mx = fmaxf(mx, s[nt][j]);
    #pragma unroll
    for (int off = 1; off < 16; off <<= 1) mx = fmaxf(mx, __shfl_xor(mx, off));
    if (lr == 0) redm[w * QB + lg * 4 + j] = mx;
  }
  __syncthreads();
  #pragma unroll
  for (int j = 0; j < 4; j++){
    int ql = lg * 4 + j;
    float mx = redm[ql];
    #pragma unroll
    for (int w2 = 1; w2 < 8; w2++) mx = fmaxf(mx, redm[w2 * QB + ql]);
    fm[j] = mx;
  }

  float ls[4] = {0.f, 0.f, 0.f, 0.f};
  #pragma unroll
  for (int nt = 0; nt < 16; nt++)
    #pragma unroll
    for (int j = 0; j < 4; j++){
      float p = __expf(s[nt][j] - fm[j]);
      ls[j] += p;
      slab[(lg * 4 + j) * PSTR + nt * 16 + lr] = f2bf(p);
    }
  #pragma unroll
  for (int j = 0; j < 4; j++){
    float sum = ls[j];
    #pragma unroll
    for (int off = 1; off < 16; off <<= 1) sum += __shfl_xor(sum, off);
    if (lr == 0) redl[w * QB + lg * 4 + j] = sum;
  }
  __syncthreads();
  float inv[4];
  #pragma unroll
  for (int j = 0; j < 4; j++){
    int ql = lg * 4 + j;
    float d = redl[ql];
    #pragma unroll
    for (int w2 = 1; w2 < 8; w2++) d += redl[w2 * QB + ql];
    inv[j] = 1.f / d;
  }

  {
    int qrow = tid >> 5, cb = (tid & 31) * 8;
    float dsum = redl[qrow];
    #pragma unroll
    for (int w2 = 1; w2 < 8; w2++) dsum += redl[w2 * QB + qrow];
    float invr = 1.f / dsum;
    float* mrow = map + (size_t)(h * LQ + q0 + qrow) * LQ;
    #pragma unroll
    for (int it = 0; it < 8; it++){
      u16x8 pv = *(u16x8*)&RP[it * SLABU + qrow * PSTR + cb];
      f32x4 o0, o1;
      #pragma unroll
      for (int j = 0; j < 4; j++){
        o0[j] = bf2f(pv[j]) * invr;
        o1[j] = bf2f(pv[4 + j]) * invr;
      }
      int c = cb + it * 256;
      __builtin_nontemporal_store(o0, (f32x4*)(mrow + c));
      __builtin_nontemporal_store(o1, (f32x4*)(mrow + c + 4));
    }
  }

  f32x4 o[4] = {};
  #pragma unroll
  for (int kc2 = 0; kc2 < 8; kc2++){
    u16x8 pa = *(u16x8*)&slab[lr * PSTR + kc2 * 32 + lg * 8];
    #pragma unroll
    for (int ni = 0; ni < 4; ni++){
      u16x8 vv = *(const u16x8*)(vt + (size_t)(h * DH + ni * 16 + lr) * LQ + kb + kc2 * 32 + lg * 8);
      o[ni] = MFMA(pa, vv, o[ni]);
    }
  }
  __syncthreads();

  float* Op = (float*)smem;
  #pragma unroll
  for (int ni = 0; ni < 4; ni++)
    #pragma unroll
    for (int j = 0; j < 4; j++)
      Op[(w * QB + lg * 4 + j) * 64 + ni * 16 + lr] = o[ni][j] * inv[j];
  __syncthreads();
  {
    int q = tid >> 5, dg = (tid & 31) * 2;
    float acc0 = 0.f, acc1 = 0.f;
    #pragma unroll
    for (int w2 = 0; w2 < 8; w2++){
      acc0 += Op[(w2 * QB + q) * 64 + dg];
      acc1 += Op[(w2 * QB + q) * 64 + dg + 1];
    }
    unsigned pk = (unsigned)f2bf(acc0) | ((unsigned)f2bf(acc1) << 16);
    *(unsigned*)(att + (size_t)(q0 + q) * DM + h * DH + dg) = pk;
  }
}

extern "C" void kernel_launch(void* const* d_in, const int* in_sizes, int n_in,
                              void* d_out, int out_size, void* d_ws, size_t ws_size,
                              hipStream_t stream){
  const float* v_in = (const float*)d_in[0];
  const float* k_in = (const float*)d_in[1];
  const float* q_in = (const float*)d_in[2];
  const int*   mask = (const int*)d_in[3];
  const float* Wq   = (const float*)d_in[4];
  const float* Wk   = (const float*)d_in[5];
  const float* Wv   = (const float*)d_in[6];
  const float* Wrk  = (const float*)d_in[7];
  const float* r_w  = (const float*)d_in[8];
  const float* r_r  = (const float*)d_in[9];
  const float* Wo   = (const float*)d_in[10];
  const float* bo   = (const float*)d_in[11];

  char* ws = (char*)d_ws;
  u16* qh  = (u16*)(ws + 0);             // [12][2048][64] bf16
  u16* kh  = (u16*)(ws + 3145728);
  u16* vt  = (u16*)(ws + 6291456);       // [12][64][2048] bf16
  u16* rk  = (u16*)(ws + 9437184);       // [12][4095][64] bf16
  u16* qb  = (u16*)(ws + 15728640);      // [2048][768] bf16 inputs
  u16* kb  = (u16*)(ws + 18874368);
  u16* vb  = (u16*)(ws + 22020096);
  u16* WqT = (u16*)(ws + 25165824);      // [768][768] bf16 transposed weights
  u16* WkT = (u16*)(ws + 26345472);
  u16* WvT = (u16*)(ws + 27525120);
  u16* WrkT= (u16*)(ws + 28704768);
  u16* WoT = (u16*)(ws + 29884416);
  u16* peb = (u16*)(ws + 31064064);      // [4095][768] bf16
  u16* att = (u16*)(ws + 37355520);      // [2048][768] bf16
  float* gamtab = (float*)(ws + 43646976);
  unsigned* gmax = (unsigned*)(ws + 44695552);
  double* logx = (double*)(ws + 44695616);
  double* Cf   = (double*)(ws + 44712000);

  float* out0 = (float*)d_out;                     // [2048][768] f32
  float* map  = out0 + (size_t)LQ * DM;            // [12][2048][2048] f32

  hipMemsetAsync(gmax, 0, 4, stream);
  prep_kernel<<<dim3(3032), 256, 0, stream>>>(q_in, k_in, v_in,
                                              Wq, Wk, Wv, Wrk, Wo,
                                              qb, kb, vb,
                                              WqT, WkT, WvT, WrkT, WoT,
                                              logx, Cf);
  gamma_probs_kernel<<<1024, 256, 0, stream>>>(logx, Cf, gamtab, gmax);
  pe_kernel<<<(NR * DM + 255) / 256, 256, 0, stream>>>(gamtab, gmax, peb);

  proj4_kernel<<<dim3(1920), 256, 0, stream>>>(qb, kb, vb, peb,
                                               WqT, WkT, WvT, WrkT,
                                               qh, kh, vt, rk);

  hipFuncSetAttribute((const void*)attn_kernel,
                      hipFuncAttributeMaxDynamicSharedMemorySize, SMEM_ATTN);
  attn_kernel<<<dim3((LQ / QB) * NH), 512, SMEM_ATTN, stream>>>(qh, kh, vt, rk, mask,
                                                                r_w, r_r, map, att);
  gemm_out_kernel<<<dim3(32, 12), 256, 0, stream>>>(att, WoT, out0, bo);
}

// Round 21
// 268.989 us; speedup vs baseline: 1.7674x; 1.0089x over previous
//
#include <hip/hip_runtime.h>
#include <hip/hip_bf16.h>
#include <math.h>

typedef unsigned short u16;
typedef __bf16 bf16x8_t __attribute__((ext_vector_type(8)));
typedef u16 u16x8 __attribute__((ext_vector_type(8)));
typedef u16 u16x4 __attribute__((ext_vector_type(4)));
typedef float f32x4 __attribute__((ext_vector_type(4)));

#define NH 12
#define LQ 2048
#define DM 768
#define DH 64
#define NR 4095           // 2L-1
#define LN2F 0.6931471805599453f

__device__ __forceinline__ u16 f2bf(float f){
  unsigned x = __float_as_uint(f);
  return (u16)((x + 0x7fffu + ((x >> 16) & 1u)) >> 16);   // RTNE
}
__device__ __forceinline__ float bf2f(u16 u){ return __uint_as_float(((unsigned)u) << 16); }

__device__ __forceinline__ f32x4 MFMA(u16x8 a, u16x8 b, f32x4 c){
  return __builtin_amdgcn_mfma_f32_16x16x32_bf16(
      __builtin_bit_cast(bf16x8_t, a), __builtin_bit_cast(bf16x8_t, b), c, 0, 0, 0);
}

// ---------------- merged prep: cvt q/k/v + transpose-cvt 5 weights + gamma tables
__launch_bounds__(256)
__global__ void prep_kernel(const float* q, const float* k, const float* v,
                            const float* W0, const float* W1, const float* W2,
                            const float* W3, const float* W4,
                            u16* qb, u16* kb, u16* vb,
                            u16* T0, u16* T1, u16* T2, u16* T3, u16* T4,
                            double* __restrict__ logx, double* __restrict__ Cf){
  __shared__ u16 tile[64 * 72];
  const int bid = blockIdx.x;
  const int t = threadIdx.x;
  if (bid < 2304){
    int z = bid / 768, b = bid - z * 768;
    const float* src = (z == 0) ? q : (z == 1) ? k : v;
    u16* dst = (z == 0) ? qb : (z == 1) ? kb : vb;
    int base = (b * 256 + t) * 8;
    f32x4 a0 = *(const f32x4*)(src + base);
    f32x4 a1 = *(const f32x4*)(src + base + 4);
    u16x8 o;
    #pragma unroll
    for (int j = 0; j < 4; j++){ o[j] = f2bf(a0[j]); o[4 + j] = f2bf(a1[j]); }
    *(u16x8*)(dst + base) = o;
  } else if (bid < 3024){
    int r = bid - 2304;
    int z = r / 144, rem = r - z * 144;
    int k0 = (rem % 12) * 64, n0 = (rem / 12) * 64;
    const float* W = (z == 0) ? W0 : (z == 1) ? W1 : (z == 2) ? W2 : (z == 3) ? W3 : W4;
    u16* T = (z == 0) ? T0 : (z == 1) ? T1 : (z == 2) ? T2 : (z == 3) ? T3 : T4;
    {
      int kr = t >> 2, ng = (t & 3) * 16;
      const float* p = W + (size_t)(k0 + kr) * DM + n0 + ng;
      u16x8 o0, o1;
      #pragma unroll
      for (int j = 0; j < 8; j++){ o0[j] = f2bf(p[j]); o1[j] = f2bf(p[8 + j]); }
      *(u16x8*)&tile[kr * 72 + ng] = o0;
      *(u16x8*)&tile[kr * 72 + ng + 8] = o1;
    }
    __syncthreads();
    {
      int nr = t >> 2, kg = (t & 3) * 16;
      u16x8 o0, o1;
      #pragma unroll
      for (int j = 0; j < 8; j++){
        o0[j] = tile[(kg + j) * 72 + nr];
        o1[j] = tile[(kg + j + 8) * 72 + nr];
      }
      u16* qp = T + (size_t)(n0 + nr) * DM + k0 + kg;
      *(u16x8*)qp = o0;
      *(u16x8*)(qp + 8) = o1;
    }
  } else {
    int i = (bid - 3024) * 256 + t;
    if (i < 2048) logx[i] = (i > 0) ? log((double)i) : 0.0;
    if (i < 128){
      double fp1 = (double)(i + 1);
      double conc = 4.0 * fp1 * fp1;
      double rate = 0.25 * fp1;
      Cf[i] = conc * log(rate) - lgamma(conc);
    }
  }
}

// ---------------- gamma pdf table + global max (f64 arg, f32 exp) ----------
__global__ void gamma_probs_kernel(const double* __restrict__ logx,
                                   const double* __restrict__ Cf,
                                   float* __restrict__ gamtab,
                                   unsigned* __restrict__ gmax){
  int idx = blockIdx.x * 256 + threadIdx.x;   // 2048*128
  int x = idx >> 7, f = idx & 127;
  double fp1 = (double)(f + 1);
  double conc = 4.0 * fp1 * fp1;
  double rate = 0.25 * fp1;
  double xl = (x > 0) ? (conc - 1.0) * logx[x] : 0.0;   // xlogy(a,0)=0
  double logp = xl - rate * (double)x + Cf[f];
  float p = __expf((float)logp);
  gamtab[idx] = p;
  float m = p;
  #pragma unroll
  for (int off = 1; off < 64; off <<= 1) m = fmaxf(m, __shfl_xor(m, off));
  if ((threadIdx.x & 63) == 0) atomicMax(gmax, __float_as_uint(m));
}

// ---------------- positional encodings -> bf16 peb[4095][768] ----------------
__global__ void pe_kernel(const float* __restrict__ gamtab,
                          const unsigned* __restrict__ gmax,
                          u16* __restrict__ peb){
  int idx = blockIdx.x * 256 + threadIdx.x;
  if (idx >= NR * DM) return;
  int p = idx / DM;
  int c = idx - p * DM;
  int f = c & 127;
  int kind = c >> 7;
  int pos = p - (LQ - 1);
  int apos = pos < 0 ? -pos : pos;
  float sgn = (pos > 0) ? 1.f : ((pos < 0) ? -1.f : 0.f);
  float v;
  int grp = kind >> 1;
  if (grp == 0){
    float hl = exp2f(3.f + 8.f * (float)f / 127.f);
    v = expf(-(LN2F / hl) * (float)apos);
  } else if (grp == 1){
    float cw = exp2f((float)(f + 1)) - 1.f;
    v = (cw > (float)apos) ? 1.f : 0.f;
  } else {
    float gm = __uint_as_float(*gmax);
    v = gamtab[apos * 128 + f] / gm;
  }
  if (kind & 1) v *= sgn;
  peb[idx] = f2bf(v);
}

// ---------------- merged 128x128-tile projections + rk GEMM (480 WGs) --------
// bid<288: z=bid/96 (q,k,v; 16x6 tiles). bid>=288: z=3 rk (32x6 tiles).
#define ASTR 40   // 32 k + 8 pad u16; 80B rows (16B-aligned)
__launch_bounds__(256)
__global__ void proj128_kernel(const u16* __restrict__ qb, const u16* __restrict__ kb,
                               const u16* __restrict__ vb, const u16* __restrict__ peb,
                               const u16* __restrict__ WqT, const u16* __restrict__ WkT,
                               const u16* __restrict__ WvT, const u16* __restrict__ WrkT,
                               u16* __restrict__ qh, u16* __restrict__ kh,
                               u16* __restrict__ vt, u16* __restrict__ rk){
  __shared__ u16 At[128 * ASTR];
  __shared__ u16 Wt[128 * ASTR];
  const int bid = blockIdx.x;
  int z, bx, by;
  if (bid < 288){ z = bid / 96; int t = bid - z * 96; bx = t & 15; by = t >> 4; }
  else          { z = 3; int t = bid - 288; bx = t & 31; by = t >> 5; }
  const u16* A  = (z == 0) ? qb : (z == 1) ? kb : (z == 2) ? vb : peb;
  const u16* WT = (z == 0) ? WqT : (z == 1) ? WkT : (z == 2) ? WvT : WrkT;
  const int m0 = bx * 128, n0 = by * 128;
  const int tid = threadIdx.x;
  const int w = tid >> 6, l = tid & 63, lr = l & 15, lg = l >> 4;
  const int moff = (w & 1) * 64, noff = (w >> 1) * 64;
  f32x4 acc[4][4] = {};
  const int srow = tid >> 1, sg = (tid & 1) * 16;
  for (int k0 = 0; k0 < DM; k0 += 32){
    {
      int m = m0 + srow;
      u16x8 a0 = {}, a1 = {};
      if (z < 3 || m < NR){
        const u16* ap = A + (size_t)m * DM + k0 + sg;
        a0 = *(const u16x8*)ap;
        a1 = *(const u16x8*)(ap + 8);
      }
      *(u16x8*)&At[srow * ASTR + sg] = a0;
      *(u16x8*)&At[srow * ASTR + sg + 8] = a1;
      const u16* wp = WT + (size_t)(n0 + srow) * DM + k0 + sg;
      *(u16x8*)&Wt[srow * ASTR + sg] = *(const u16x8*)wp;
      *(u16x8*)&Wt[srow * ASTR + sg + 8] = *(const u16x8*)(wp + 8);
    }
    __syncthreads();
    u16x8 af[4], bf[4];
    #pragma unroll
    for (int mi = 0; mi < 4; mi++)
      af[mi] = *(u16x8*)&At[(moff + mi * 16 + lr) * ASTR + lg * 8];
    #pragma unroll
    for (int ni = 0; ni < 4; ni++)
      bf[ni] = *(u16x8*)&Wt[(noff + ni * 16 + lr) * ASTR + lg * 8];
    #pragma unroll
    for (int mi = 0; mi < 4; mi++)
      #pragma unroll
      for (int ni = 0; ni < 4; ni++)
        acc[mi][ni] = MFMA(af[mi], bf[ni], acc[mi][ni]);
    __syncthreads();
  }
  if (z == 2){
    #pragma unroll
    for (int mi = 0; mi < 4; mi++)
      #pragma unroll
      for (int ni = 0; ni < 4; ni++){
        int m = m0 + moff + mi * 16 + lg * 4;
        int n = n0 + noff + ni * 16 + lr;
        u16x4 ov;
        #pragma unroll
        for (int j = 0; j < 4; j++) ov[j] = f2bf(acc[mi][ni][j]);
        *(u16x4*)(vt + ((size_t)(n >> 6) * DH + (n & 63)) * LQ + m) = ov;
      }
  } else if (z == 3){
    #pragma unroll
    for (int mi = 0; mi < 4; mi++)
      #pragma unroll
      for (int ni = 0; ni < 4; ni++)
        #pragma unroll
        for (int j = 0; j < 4; j++){
          int m = m0 + moff + mi * 16 + lg * 4 + j;
          int n = n0 + noff + ni * 16 + lr;
          if (m < NR)
            rk[((size_t)(n >> 6) * NR + m) * DH + (n & 63)] = f2bf(acc[mi][ni][j]);
        }
  } else {
    u16* outb = (z == 0) ? qh : kh;
    const float scale = (z == 0) ? 0.125f : 1.f;
    #pragma unroll
    for (int mi = 0; mi < 4; mi++)
      #pragma unroll
      for (int ni = 0; ni < 4; ni++)
        #pragma unroll
        for (int j = 0; j < 4; j++){
          int m = m0 + moff + mi * 16 + lg * 4 + j;
          int n = n0 + noff + ni * 16 + lr;
          outb[((size_t)(n >> 6) * LQ + m) * DH + (n & 63)] = f2bf(acc[mi][ni][j] * scale);
        }
  }
}

// ---------------- out-proj GEMM: bf16 att x WoT bf16, f32 out + bias ---------
#define GSTRB 72
__launch_bounds__(256)
__global__ void gemm_out_kernel(const u16* __restrict__ A, const u16* __restrict__ WT,
                                float* __restrict__ outf, const float* __restrict__ bias){
  __shared__ u16 At[64 * GSTRB];
  __shared__ u16 Wt[64 * GSTRB];
  const int m0 = blockIdx.x * 64, n0 = blockIdx.y * 64;
  const int tid = threadIdx.x;
  const int w = tid >> 6, l = tid & 63, lr = l & 15, lg = l >> 4;
  const int moff = (w & 1) * 32, noff = (w >> 1) * 32;
  f32x4 acc[2][2] = {};
  const int arow = tid >> 2, akg = (tid & 3) * 16;
  for (int k0 = 0; k0 < DM; k0 += 64){
    {
      const u16* ap = A + (size_t)(m0 + arow) * DM + k0 + akg;
      *(u16x8*)&At[arow * GSTRB + akg] = *(const u16x8*)ap;
      *(u16x8*)&At[arow * GSTRB + akg + 8] = *(const u16x8*)(ap + 8);
      const u16* wp = WT + (size_t)(n0 + arow) * DM + k0 + akg;
      *(u16x8*)&Wt[arow * GSTRB + akg] = *(const u16x8*)wp;
      *(u16x8*)&Wt[arow * GSTRB + akg + 8] = *(const u16x8*)(wp + 8);
    }
    __syncthreads();
    #pragma unroll
    for (int kc = 0; kc < 2; kc++){
      u16x8 af0 = *(u16x8*)&At[(moff + lr) * GSTRB + kc * 32 + lg * 8];
      u16x8 af1 = *(u16x8*)&At[(moff + 16 + lr) * GSTRB + kc * 32 + lg * 8];
      u16x8 bf0 = *(u16x8*)&Wt[(noff + lr) * GSTRB + kc * 32 + lg * 8];
      u16x8 bf1 = *(u16x8*)&Wt[(noff + 16 + lr) * GSTRB + kc * 32 + lg * 8];
      acc[0][0] = MFMA(af0, bf0, acc[0][0]);
      acc[0][1] = MFMA(af0, bf1, acc[0][1]);
      acc[1][0] = MFMA(af1, bf0, acc[1][0]);
      acc[1][1] = MFMA(af1, bf1, acc[1][1]);
    }
    __syncthreads();
  }
  #pragma unroll
  for (int mi = 0; mi < 2; mi++)
    #pragma unroll
    for (int ni = 0; ni < 2; ni++)
      #pragma unroll
      for (int j = 0; j < 4; j++){
        int m = m0 + moff + mi * 16 + lg * 4 + j;
        int n = n0 + noff + ni * 16 + lr;
        __builtin_nontemporal_store(acc[mi][ni][j] + bias[n], &outf[(size_t)m * DM + n]);
      }
}

// ---------------- fused rel-pos attention (r17/r20 + hoisted mask bits) ------
#define QB 16
#define DSTR 16
#define DROWS 288
#define PSTR 264
#define SLABU (DROWS * DSTR)
#define SMEM_ATTN (8 * SLABU * 2 + 1024)
__launch_bounds__(512, 4)
__global__ void attn_kernel(const u16* __restrict__ qh, const u16* __restrict__ kh,
                            const u16* __restrict__ vt, const u16* __restrict__ rk,
                            const int* __restrict__ mask,
                            const float* __restrict__ r_w, const float* __restrict__ r_r,
                            float* __restrict__ map, u16* __restrict__ att){
  extern __shared__ char smem[];
  u16* RP = (u16*)smem;
  float* redm = (float*)(smem + 8 * SLABU * 2);
  float* redl = redm + 128;
  const int bid = blockIdx.x;
  const int swz = (bid & 7) * 192 + (bid >> 3);
  const int h = swz >> 7, q0 = (swz & 127) * QB;
  const int tid = threadIdx.x, w = tid >> 6, l = tid & 63, lr = l & 15, lg = l >> 4;
  const int roff = (LQ - 1) - q0 - (QB - 1);
  const int kb = w * 256;
  u16* slab = RP + w * SLABU;

  u16x8 a1[2], a2[2];
  #pragma unroll
  for (int kc = 0; kc < 2; kc++){
    u16x8 qv = *(const u16x8*)(qh + (size_t)(h * LQ + q0 + lr) * DH + kc * 32 + lg * 8);
    #pragma unroll
    for (int j = 0; j < 8; j++){
      int d = kc * 32 + lg * 8 + j;
      float f = bf2f(qv[j]);
      a1[kc][j] = f2bf(f + r_w[h * DH + d]);
      a2[kc][j] = f2bf(f + r_r[h * DH + d]);
    }
  }

  // hoisted mask bits: bit nt = mask[kb + nt*16 + lr] (4 loads + 3 shuffles)
  unsigned mbits = 0;
  {
    #pragma unroll
    for (int i = 0; i < 4; i++){
      int nt = lg + 4 * i;
      int mv = mask[kb + nt * 16 + lr];
      mbits |= ((unsigned)(mv & 1)) << nt;
    }
    mbits |= __shfl_xor(mbits, 16);
    mbits |= __shfl_xor(mbits, 32);
  }

  #pragma unroll 4
  for (int t = 0; t < 17; t++){
    int r = roff + kb + t * 16 + lr;
    if (r > NR - 1) r = NR - 1;
    const u16* rp = rk + (size_t)(h * NR + r) * DH + lg * 8;
    u16x8 b0 = *(const u16x8*)(rp);
    u16x8 b1 = *(const u16x8*)(rp + 32);
    f32x4 racc = {};
    racc = MFMA(a2[0], b0, racc);
    racc = MFMA(a2[1], b1, racc);
    int lc = t * 16 + lr;
    #pragma unroll
    for (int j = 0; j < 4; j++){
      int ql = lg * 4 + j;
      slab[(lc + ql) * DSTR + ql] = f2bf(racc[j]);
    }
  }
  __asm__ volatile("s_waitcnt lgkmcnt(0)" ::: "memory");
  __builtin_amdgcn_sched_barrier(0);

  f32x4 s[16];
  #pragma unroll
  for (int nt = 0; nt < 16; nt++){
    const u16* kp = kh + (size_t)(h * LQ + kb + nt * 16 + lr) * DH + lg * 8;
    u16x8 b0 = *(const u16x8*)(kp);
    u16x8 b1 = *(const u16x8*)(kp + 32);
    f32x4 sv = {};
    sv = MFMA(a1[0], b0, sv);
    sv = MFMA(a1[1], b1, sv);
    int mv = (mbits >> nt) & 1;
    u16x4 g = *(u16x4*)&slab[(nt * 16 + lr + (QB - 1)) * DSTR + lg * 4];
    #pragma unroll
    for (int j = 0; j < 4; j++){
      float x = sv[j] + bf2f(g[j]);
      sv[j] = mv ? -10000.f : x;
    }
    s[nt] = sv;
  }

  float fm[4];
  #pragma unroll
  for (int j = 0; j < 4; j++){
    float mx = -3.0e38f;
    #pragma unroll
    for (int nt = 0; nt < 16; nt++) mx = fmaxf(mx, s[nt][j]);
    #pragma unroll
    for (int off = 1; off < 16; off <<= 1) mx = fmaxf(mx, __shfl_xor(mx, off));
    if (lr == 0) redm[w * QB + lg * 4 + j] = mx;
  }
  __syncthreads();
  #pragma unroll
  for (int j = 0; j < 4; j++){
    int ql = lg * 4 + j;
    float mx = redm[ql];
    #pragma unroll
    for (int w2 = 1; w2 < 8; w2++) mx = fmaxf(mx, redm[w2 * QB + ql]);
    fm[j] = mx;
  }

  float ls[4] = {0.f, 0.f, 0.f, 0.f};
  #pragma unroll
  for (int nt = 0; nt < 16; nt++)
    #pragma unroll
    for (int j = 0; j < 4; j++){
      float p = __expf(s[nt][j] - fm[j]);
      ls[j] += p;
      slab[(lg * 4 + j) * PSTR + nt * 16 + lr] = f2bf(p);
    }
  #pragma unroll
  for (int j = 0; j < 4; j++){
    float sum = ls[j];
    #pragma unroll
    for (int off = 1; off < 16; off <<= 1) sum += __shfl_xor(sum, off);
    if (lr == 0) redl[w * QB + lg * 4 + j] = sum;
  }
  __syncthreads();
  float inv[4];
  #pragma unroll
  for (int j = 0; j < 4; j++){
    int ql = lg * 4 + j;
    float d = redl[ql];
    #pragma unroll
    for (int w2 = 1; w2 < 8; w2++) d += redl[w2 * QB + ql];
    inv[j] = 1.f / d;
  }

  {
    int qrow = tid >> 5, cb = (tid & 31) * 8;
    float dsum = redl[qrow];
    #pragma unroll
    for (int w2 = 1; w2 < 8; w2++) dsum += redl[w2 * QB + qrow];
    float invr = 1.f / dsum;
    float* mrow = map + (size_t)(h * LQ + q0 + qrow) * LQ;
    #pragma unroll
    for (int it = 0; it < 8; it++){
      u16x8 pv = *(u16x8*)&RP[it * SLABU + qrow * PSTR + cb];
      f32x4 o0, o1;
      #pragma unroll
      for (int j = 0; j < 4; j++){
        o0[j] = bf2f(pv[j]) * invr;
        o1[j] = bf2f(pv[4 + j]) * invr;
      }
      int c = cb + it * 256;
      __builtin_nontemporal_store(o0, (f32x4*)(mrow + c));
      __builtin_nontemporal_store(o1, (f32x4*)(mrow + c + 4));
    }
  }

  f32x4 o[4] = {};
  #pragma unroll
  for (int kc2 = 0; kc2 < 8; kc2++){
    u16x8 pa = *(u16x8*)&slab[lr * PSTR + kc2 * 32 + lg * 8];
    #pragma unroll
    for (int ni = 0; ni < 4; ni++){
      u16x8 vv = *(const u16x8*)(vt + (size_t)(h * DH + ni * 16 + lr) * LQ + kb + kc2 * 32 + lg * 8);
      o[ni] = MFMA(pa, vv, o[ni]);
    }
  }
  __syncthreads();

  float* Op = (float*)smem;
  #pragma unroll
  for (int ni = 0; ni < 4; ni++)
    #pragma unroll
    for (int j = 0; j < 4; j++)
      Op[(w * QB + lg * 4 + j) * 64 + ni * 16 + lr] = o[ni][j] * inv[j];
  __syncthreads();
  {
    int q = tid >> 5, dg = (tid & 31) * 2;
    float acc0 = 0.f, acc1 = 0.f;
    #pragma unroll
    for (int w2 = 0; w2 < 8; w2++){
      acc0 += Op[(w2 * QB + q) * 64 + dg];
      acc1 += Op[(w2 * QB + q) * 64 + dg + 1];
    }
    unsigned pk = (unsigned)f2bf(acc0) | ((unsigned)f2bf(acc1) << 16);
    *(unsigned*)(att + (size_t)(q0 + q) * DM + h * DH + dg) = pk;
  }
}

extern "C" void kernel_launch(void* const* d_in, const int* in_sizes, int n_in,
                              void* d_out, int out_size, void* d_ws, size_t ws_size,
                              hipStream_t stream){
  const float* v_in = (const float*)d_in[0];
  const float* k_in = (const float*)d_in[1];
  const float* q_in = (const float*)d_in[2];
  const int*   mask = (const int*)d_in[3];
  const float* Wq   = (const float*)d_in[4];
  const float* Wk   = (const float*)d_in[5];
  const float* Wv   = (const float*)d_in[6];
  const float* Wrk  = (const float*)d_in[7];
  const float* r_w  = (const float*)d_in[8];
  const float* r_r  = (const float*)d_in[9];
  const float* Wo   = (const float*)d_in[10];
  const float* bo   = (const float*)d_in[11];

  char* ws = (char*)d_ws;
  u16* qh  = (u16*)(ws + 0);             // [12][2048][64] bf16
  u16* kh  = (u16*)(ws + 3145728);
  u16* vt  = (u16*)(ws + 6291456);       // [12][64][2048] bf16
  u16* rk  = (u16*)(ws + 9437184);       // [12][4095][64] bf16
  u16* qb  = (u16*)(ws + 15728640);      // [2048][768] bf16 inputs
  u16* kb  = (u16*)(ws + 18874368);
  u16* vb  = (u16*)(ws + 22020096);
  u16* WqT = (u16*)(ws + 25165824);      // [768][768] bf16 transposed weights
  u16* WkT = (u16*)(ws + 26345472);
  u16* WvT = (u16*)(ws + 27525120);
  u16* WrkT= (u16*)(ws + 28704768);
  u16* WoT = (u16*)(ws + 29884416);
  u16* peb = (u16*)(ws + 31064064);      // [4095][768] bf16
  u16* att = (u16*)(ws + 37355520);      // [2048][768] bf16
  float* gamtab = (float*)(ws + 43646976);
  unsigned* gmax = (unsigned*)(ws + 44695552);
  double* logx = (double*)(ws + 44695616);
  double* Cf   = (double*)(ws + 44712000);

  float* out0 = (float*)d_out;                     // [2048][768] f32
  float* map  = out0 + (size_t)LQ * DM;            // [12][2048][2048] f32

  hipMemsetAsync(gmax, 0, 4, stream);
  prep_kernel<<<dim3(3032), 256, 0, stream>>>(q_in, k_in, v_in,
                                              Wq, Wk, Wv, Wrk, Wo,
                                              qb, kb, vb,
                                              WqT, WkT, WvT, WrkT, WoT,
                                              logx, Cf);
  gamma_probs_kernel<<<1024, 256, 0, stream>>>(logx, Cf, gamtab, gmax);
  pe_kernel<<<(NR * DM + 255) / 256, 256, 0, stream>>>(gamtab, gmax, peb);

  proj128_kernel<<<dim3(480), 256, 0, stream>>>(qb, kb, vb, peb,
                                                WqT, WkT, WvT, WrkT,
                                                qh, kh, vt, rk);

  hipFuncSetAttribute((const void*)attn_kernel,
                      hipFuncAttributeMaxDynamicSharedMemorySize, SMEM_ATTN);
  attn_kernel<<<dim3((LQ / QB) * NH), 512, SMEM_ATTN, stream>>>(qh, kh, vt, rk, mask,
                                                                r_w, r_r, map, att);
  gemm_out_kernel<<<dim3(32, 12), 256, 0, stream>>>(att, WoT, out0, bo);
}

// Round 22
// 267.209 us; speedup vs baseline: 1.7791x; 1.0067x over previous
//
#include <hip/hip_runtime.h>
#include <hip/hip_bf16.h>
#include <math.h>

typedef unsigned short u16;
typedef __bf16 bf16x8_t __attribute__((ext_vector_type(8)));
typedef u16 u16x8 __attribute__((ext_vector_type(8)));
typedef u16 u16x4 __attribute__((ext_vector_type(4)));
typedef float f32x4 __attribute__((ext_vector_type(4)));

#define NH 12
#define LQ 2048
#define DM 768
#define DH 64
#define NR 4095           // 2L-1
#define LN2F 0.6931471805599453f

__device__ __forceinline__ u16 f2bf(float f){
  unsigned x = __float_as_uint(f);
  return (u16)((x + 0x7fffu + ((x >> 16) & 1u)) >> 16);   // RTNE
}
__device__ __forceinline__ float bf2f(u16 u){ return __uint_as_float(((unsigned)u) << 16); }

__device__ __forceinline__ f32x4 MFMA(u16x8 a, u16x8 b, f32x4 c){
  return __builtin_amdgcn_mfma_f32_16x16x32_bf16(
      __builtin_bit_cast(bf16x8_t, a), __builtin_bit_cast(bf16x8_t, b), c, 0, 0, 0);
}

// ---------------- merged prep: cvt q/k/v + transpose-cvt 5 weights + gamma tables
__launch_bounds__(256)
__global__ void prep_kernel(const float* q, const float* k, const float* v,
                            const float* W0, const float* W1, const float* W2,
                            const float* W3, const float* W4,
                            u16* qb, u16* kb, u16* vb,
                            u16* T0, u16* T1, u16* T2, u16* T3, u16* T4,
                            double* __restrict__ logx, double* __restrict__ Cf){
  __shared__ u16 tile[64 * 72];
  const int bid = blockIdx.x;
  const int t = threadIdx.x;
  if (bid < 2304){
    int z = bid / 768, b = bid - z * 768;
    const float* src = (z == 0) ? q : (z == 1) ? k : v;
    u16* dst = (z == 0) ? qb : (z == 1) ? kb : vb;
    int base = (b * 256 + t) * 8;
    f32x4 a0 = *(const f32x4*)(src + base);
    f32x4 a1 = *(const f32x4*)(src + base + 4);
    u16x8 o;
    #pragma unroll
    for (int j = 0; j < 4; j++){ o[j] = f2bf(a0[j]); o[4 + j] = f2bf(a1[j]); }
    *(u16x8*)(dst + base) = o;
  } else if (bid < 3024){
    int r = bid - 2304;
    int z = r / 144, rem = r - z * 144;
    int k0 = (rem % 12) * 64, n0 = (rem / 12) * 64;
    const float* W = (z == 0) ? W0 : (z == 1) ? W1 : (z == 2) ? W2 : (z == 3) ? W3 : W4;
    u16* T = (z == 0) ? T0 : (z == 1) ? T1 : (z == 2) ? T2 : (z == 3) ? T3 : T4;
    {
      int kr = t >> 2, ng = (t & 3) * 16;
      const float* p = W + (size_t)(k0 + kr) * DM + n0 + ng;
      u16x8 o0, o1;
      #pragma unroll
      for (int j = 0; j < 8; j++){ o0[j] = f2bf(p[j]); o1[j] = f2bf(p[8 + j]); }
      *(u16x8*)&tile[kr * 72 + ng] = o0;
      *(u16x8*)&tile[kr * 72 + ng + 8] = o1;
    }
    __syncthreads();
    {
      int nr = t >> 2, kg = (t & 3) * 16;
      u16x8 o0, o1;
      #pragma unroll
      for (int j = 0; j < 8; j++){
        o0[j] = tile[(kg + j) * 72 + nr];
        o1[j] = tile[(kg + j + 8) * 72 + nr];
      }
      u16* qp = T + (size_t)(n0 + nr) * DM + k0 + kg;
      *(u16x8*)qp = o0;
      *(u16x8*)(qp + 8) = o1;
    }
  } else {
    int i = (bid - 3024) * 256 + t;
    if (i < 2048) logx[i] = (i > 0) ? log((double)i) : 0.0;
    if (i < 128){
      double fp1 = (double)(i + 1);
      double conc = 4.0 * fp1 * fp1;
      double rate = 0.25 * fp1;
      Cf[i] = conc * log(rate) - lgamma(conc);
    }
  }
}

// ---------------- gamma pdf table + global max (f64 arg, f32 exp) ----------
__global__ void gamma_probs_kernel(const double* __restrict__ logx,
                                   const double* __restrict__ Cf,
                                   float* __restrict__ gamtab,
                                   unsigned* __restrict__ gmax){
  int idx = blockIdx.x * 256 + threadIdx.x;   // 2048*128
  int x = idx >> 7, f = idx & 127;
  double fp1 = (double)(f + 1);
  double conc = 4.0 * fp1 * fp1;
  double rate = 0.25 * fp1;
  double xl = (x > 0) ? (conc - 1.0) * logx[x] : 0.0;   // xlogy(a,0)=0
  double logp = xl - rate * (double)x + Cf[f];
  float p = __expf((float)logp);
  gamtab[idx] = p;
  float m = p;
  #pragma unroll
  for (int off = 1; off < 64; off <<= 1) m = fmaxf(m, __shfl_xor(m, off));
  if ((threadIdx.x & 63) == 0) atomicMax(gmax, __float_as_uint(m));
}

// ---------------- positional encodings -> bf16 peb[4095][768] ----------------
__global__ void pe_kernel(const float* __restrict__ gamtab,
                          const unsigned* __restrict__ gmax,
                          u16* __restrict__ peb){
  int idx = blockIdx.x * 256 + threadIdx.x;
  if (idx >= NR * DM) return;
  int p = idx / DM;
  int c = idx - p * DM;
  int f = c & 127;
  int kind = c >> 7;
  int pos = p - (LQ - 1);
  int apos = pos < 0 ? -pos : pos;
  float sgn = (pos > 0) ? 1.f : ((pos < 0) ? -1.f : 0.f);
  float v;
  int grp = kind >> 1;
  if (grp == 0){
    float hl = exp2f(3.f + 8.f * (float)f / 127.f);
    v = expf(-(LN2F / hl) * (float)apos);
  } else if (grp == 1){
    float cw = exp2f((float)(f + 1)) - 1.f;
    v = (cw > (float)apos) ? 1.f : 0.f;
  } else {
    float gm = __uint_as_float(*gmax);
    v = gamtab[apos * 128 + f] / gm;
  }
  if (kind & 1) v *= sgn;
  peb[idx] = f2bf(v);
}

// ---------------- merged 128x128-tile projections + rk GEMM, BK=64 (480 WGs) --
// bid<288: z=bid/96 (q,k,v; 16x6 tiles). bid>=288: z=3 rk (32x6 tiles).
#define ASTR 72   // 64 k + 8 pad u16; 144B rows (16B-aligned, 2-way-bank-safe)
__launch_bounds__(256)
__global__ void proj128_kernel(const u16* __restrict__ qb, const u16* __restrict__ kb,
                               const u16* __restrict__ vb, const u16* __restrict__ peb,
                               const u16* __restrict__ WqT, const u16* __restrict__ WkT,
                               const u16* __restrict__ WvT, const u16* __restrict__ WrkT,
                               u16* __restrict__ qh, u16* __restrict__ kh,
                               u16* __restrict__ vt, u16* __restrict__ rk){
  __shared__ u16 At[128 * ASTR];
  __shared__ u16 Wt[128 * ASTR];
  const int bid = blockIdx.x;
  int z, bx, by;
  if (bid < 288){ z = bid / 96; int t = bid - z * 96; bx = t & 15; by = t >> 4; }
  else          { z = 3; int t = bid - 288; bx = t & 31; by = t >> 5; }
  const u16* A  = (z == 0) ? qb : (z == 1) ? kb : (z == 2) ? vb : peb;
  const u16* WT = (z == 0) ? WqT : (z == 1) ? WkT : (z == 2) ? WvT : WrkT;
  const int m0 = bx * 128, n0 = by * 128;
  const int tid = threadIdx.x;
  const int w = tid >> 6, l = tid & 63, lr = l & 15, lg = l >> 4;
  const int moff = (w & 1) * 64, noff = (w >> 1) * 64;
  f32x4 acc[4][4] = {};
  const int srow = tid >> 1, sg = (tid & 1) * 32;   // 2 threads/row, 32 elems each
  for (int k0 = 0; k0 < DM; k0 += 64){
    {
      int m = m0 + srow;
      u16x8 a0 = {}, a1 = {}, a2 = {}, a3 = {};
      if (z < 3 || m < NR){
        const u16* ap = A + (size_t)m * DM + k0 + sg;
        a0 = *(const u16x8*)ap;
        a1 = *(const u16x8*)(ap + 8);
        a2 = *(const u16x8*)(ap + 16);
        a3 = *(const u16x8*)(ap + 24);
      }
      u16* sp = &At[srow * ASTR + sg];
      *(u16x8*)sp = a0;
      *(u16x8*)(sp + 8) = a1;
      *(u16x8*)(sp + 16) = a2;
      *(u16x8*)(sp + 24) = a3;
      const u16* wp = WT + (size_t)(n0 + srow) * DM + k0 + sg;
      u16* wq = &Wt[srow * ASTR + sg];
      *(u16x8*)wq = *(const u16x8*)wp;
      *(u16x8*)(wq + 8) = *(const u16x8*)(wp + 8);
      *(u16x8*)(wq + 16) = *(const u16x8*)(wp + 16);
      *(u16x8*)(wq + 24) = *(const u16x8*)(wp + 24);
    }
    __syncthreads();
    #pragma unroll
    for (int kc = 0; kc < 2; kc++){
      u16x8 af[4], bf[4];
      #pragma unroll
      for (int mi = 0; mi < 4; mi++)
        af[mi] = *(u16x8*)&At[(moff + mi * 16 + lr) * ASTR + kc * 32 + lg * 8];
      #pragma unroll
      for (int ni = 0; ni < 4; ni++)
        bf[ni] = *(u16x8*)&Wt[(noff + ni * 16 + lr) * ASTR + kc * 32 + lg * 8];
      #pragma unroll
      for (int mi = 0; mi < 4; mi++)
        #pragma unroll
        for (int ni = 0; ni < 4; ni++)
          acc[mi][ni] = MFMA(af[mi], bf[ni], acc[mi][ni]);
    }
    __syncthreads();
  }
  if (z == 2){
    #pragma unroll
    for (int mi = 0; mi < 4; mi++)
      #pragma unroll
      for (int ni = 0; ni < 4; ni++){
        int m = m0 + moff + mi * 16 + lg * 4;
        int n = n0 + noff + ni * 16 + lr;
        u16x4 ov;
        #pragma unroll
        for (int j = 0; j < 4; j++) ov[j] = f2bf(acc[mi][ni][j]);
        *(u16x4*)(vt + ((size_t)(n >> 6) * DH + (n & 63)) * LQ + m) = ov;
      }
  } else if (z == 3){
    #pragma unroll
    for (int mi = 0; mi < 4; mi++)
      #pragma unroll
      for (int ni = 0; ni < 4; ni++)
        #pragma unroll
        for (int j = 0; j < 4; j++){
          int m = m0 + moff + mi * 16 + lg * 4 + j;
          int n = n0 + noff + ni * 16 + lr;
          if (m < NR)
            rk[((size_t)(n >> 6) * NR + m) * DH + (n & 63)] = f2bf(acc[mi][ni][j]);
        }
  } else {
    u16* outb = (z == 0) ? qh : kh;
    const float scale = (z == 0) ? 0.125f : 1.f;
    #pragma unroll
    for (int mi = 0; mi < 4; mi++)
      #pragma unroll
      for (int ni = 0; ni < 4; ni++)
        #pragma unroll
        for (int j = 0; j < 4; j++){
          int m = m0 + moff + mi * 16 + lg * 4 + j;
          int n = n0 + noff + ni * 16 + lr;
          outb[((size_t)(n >> 6) * LQ + m) * DH + (n & 63)] = f2bf(acc[mi][ni][j] * scale);
        }
  }
}

// ---------------- out-proj GEMM: bf16 att x WoT bf16, f32 out + bias ---------
#define GSTRB 72
__launch_bounds__(256)
__global__ void gemm_out_kernel(const u16* __restrict__ A, const u16* __restrict__ WT,
                                float* __restrict__ outf, const float* __restrict__ bias){
  __shared__ u16 At[64 * GSTRB];
  __shared__ u16 Wt[64 * GSTRB];
  const int m0 = blockIdx.x * 64, n0 = blockIdx.y * 64;
  const int tid = threadIdx.x;
  const int w = tid >> 6, l = tid & 63, lr = l & 15, lg = l >> 4;
  const int moff = (w & 1) * 32, noff = (w >> 1) * 32;
  f32x4 acc[2][2] = {};
  const int arow = tid >> 2, akg = (tid & 3) * 16;
  for (int k0 = 0; k0 < DM; k0 += 64){
    {
      const u16* ap = A + (size_t)(m0 + arow) * DM + k0 + akg;
      *(u16x8*)&At[arow * GSTRB + akg] = *(const u16x8*)ap;
      *(u16x8*)&At[arow * GSTRB + akg + 8] = *(const u16x8*)(ap + 8);
      const u16* wp = WT + (size_t)(n0 + arow) * DM + k0 + akg;
      *(u16x8*)&Wt[arow * GSTRB + akg] = *(const u16x8*)wp;
      *(u16x8*)&Wt[arow * GSTRB + akg + 8] = *(const u16x8*)(wp + 8);
    }
    __syncthreads();
    #pragma unroll
    for (int kc = 0; kc < 2; kc++){
      u16x8 af0 = *(u16x8*)&At[(moff + lr) * GSTRB + kc * 32 + lg * 8];
      u16x8 af1 = *(u16x8*)&At[(moff + 16 + lr) * GSTRB + kc * 32 + lg * 8];
      u16x8 bf0 = *(u16x8*)&Wt[(noff + lr) * GSTRB + kc * 32 + lg * 8];
      u16x8 bf1 = *(u16x8*)&Wt[(noff + 16 + lr) * GSTRB + kc * 32 + lg * 8];
      acc[0][0] = MFMA(af0, bf0, acc[0][0]);
      acc[0][1] = MFMA(af0, bf1, acc[0][1]);
      acc[1][0] = MFMA(af1, bf0, acc[1][0]);
      acc[1][1] = MFMA(af1, bf1, acc[1][1]);
    }
    __syncthreads();
  }
  #pragma unroll
  for (int mi = 0; mi < 2; mi++)
    #pragma unroll
    for (int ni = 0; ni < 2; ni++)
      #pragma unroll
      for (int j = 0; j < 4; j++){
        int m = m0 + moff + mi * 16 + lg * 4 + j;
        int n = n0 + noff + ni * 16 + lr;
        __builtin_nontemporal_store(acc[mi][ni][j] + bias[n], &outf[(size_t)m * DM + n]);
      }
}

// ---------------- fused rel-pos attention (r21 + s_setprio around MFMA) ------
#define QB 16
#define DSTR 16
#define DROWS 288
#define PSTR 264
#define SLABU (DROWS * DSTR)
#define SMEM_ATTN (8 * SLABU * 2 + 1024)
__launch_bounds__(512, 4)
__global__ void attn_kernel(const u16* __restrict__ qh, const u16* __restrict__ kh,
                            const u16* __restrict__ vt, const u16* __restrict__ rk,
                            const int* __restrict__ mask,
                            const float* __restrict__ r_w, const float* __restrict__ r_r,
                            float* __restrict__ map, u16* __restrict__ att){
  extern __shared__ char smem[];
  u16* RP = (u16*)smem;
  float* redm = (float*)(smem + 8 * SLABU * 2);
  float* redl = redm + 128;
  const int bid = blockIdx.x;
  const int swz = (bid & 7) * 192 + (bid >> 3);
  const int h = swz >> 7, q0 = (swz & 127) * QB;
  const int tid = threadIdx.x, w = tid >> 6, l = tid & 63, lr = l & 15, lg = l >> 4;
  const int roff = (LQ - 1) - q0 - (QB - 1);
  const int kb = w * 256;
  u16* slab = RP + w * SLABU;

  u16x8 a1[2], a2[2];
  #pragma unroll
  for (int kc = 0; kc < 2; kc++){
    u16x8 qv = *(const u16x8*)(qh + (size_t)(h * LQ + q0 + lr) * DH + kc * 32 + lg * 8);
    #pragma unroll
    for (int j = 0; j < 8; j++){
      int d = kc * 32 + lg * 8 + j;
      float f = bf2f(qv[j]);
      a1[kc][j] = f2bf(f + r_w[h * DH + d]);
      a2[kc][j] = f2bf(f + r_r[h * DH + d]);
    }
  }

  unsigned mbits = 0;
  {
    #pragma unroll
    for (int i = 0; i < 4; i++){
      int nt = lg + 4 * i;
      int mv = mask[kb + nt * 16 + lr];
      mbits |= ((unsigned)(mv & 1)) << nt;
    }
    mbits |= __shfl_xor(mbits, 16);
    mbits |= __shfl_xor(mbits, 32);
  }

  __builtin_amdgcn_s_setprio(1);          // favor MFMA-issuing waves (T5)
  #pragma unroll 4
  for (int t = 0; t < 17; t++){
    int r = roff + kb + t * 16 + lr;
    if (r > NR - 1) r = NR - 1;
    const u16* rp = rk + (size_t)(h * NR + r) * DH + lg * 8;
    u16x8 b0 = *(const u16x8*)(rp);
    u16x8 b1 = *(const u16x8*)(rp + 32);
    f32x4 racc = {};
    racc = MFMA(a2[0], b0, racc);
    racc = MFMA(a2[1], b1, racc);
    int lc = t * 16 + lr;
    #pragma unroll
    for (int j = 0; j < 4; j++){
      int ql = lg * 4 + j;
      slab[(lc + ql) * DSTR + ql] = f2bf(racc[j]);
    }
  }
  __asm__ volatile("s_waitcnt lgkmcnt(0)" ::: "memory");
  __builtin_amdgcn_sched_barrier(0);

  f32x4 s[16];
  #pragma unroll
  for (int nt = 0; nt < 16; nt++){
    const u16* kp = kh + (size_t)(h * LQ + kb + nt * 16 + lr) * DH + lg * 8;
    u16x8 b0 = *(const u16x8*)(kp);
    u16x8 b1 = *(const u16x8*)(kp + 32);
    f32x4 sv = {};
    sv = MFMA(a1[0], b0, sv);
    sv = MFMA(a1[1], b1, sv);
    int mv = (mbits >> nt) & 1;
    u16x4 g = *(u16x4*)&slab[(nt * 16 + lr + (QB - 1)) * DSTR + lg * 4];
    #pragma unroll
    for (int j = 0; j < 4; j++){
      float x = sv[j] + bf2f(g[j]);
      sv[j] = mv ? -10000.f : x;
    }
    s[nt] = sv;
  }
  __builtin_amdgcn_s_setprio(0);

  float fm[4];
  #pragma unroll
  for (int j = 0; j < 4; j++){
    float mx = -3.0e38f;
    #pragma unroll
    for (int nt = 0; nt < 16; nt++) mx = fmaxf(mx, s[nt][j]);
    #pragma unroll
    for (int off = 1; off < 16; off <<= 1) mx = fmaxf(mx, __shfl_xor(mx, off));
    if (lr == 0) redm[w * QB + lg * 4 + j] = mx;
  }
  __syncthreads();
  #pragma unroll
  for (int j = 0; j < 4; j++){
    int ql = lg * 4 + j;
    float mx = redm[ql];
    #pragma unroll
    for (int w2 = 1; w2 < 8; w2++) mx = fmaxf(mx, redm[w2 * QB + ql]);
    fm[j] = mx;
  }

  float ls[4] = {0.f, 0.f, 0.f, 0.f};
  #pragma unroll
  for (int nt = 0; nt < 16; nt++)
    #pragma unroll
    for (int j = 0; j < 4; j++){
      float p = __expf(s[nt][j] - fm[j]);
      ls[j] += p;
      slab[(lg * 4 + j) * PSTR + nt * 16 + lr] = f2bf(p);
    }
  #pragma unroll
  for (int j = 0; j < 4; j++){
    float sum = ls[j];
    #pragma unroll
    for (int off = 1; off < 16; off <<= 1) sum += __shfl_xor(sum, off);
    if (lr == 0) redl[w * QB + lg * 4 + j] = sum;
  }
  __syncthreads();
  float inv[4];
  #pragma unroll
  for (int j = 0; j < 4; j++){
    int ql = lg * 4 + j;
    float d = redl[ql];
    #pragma unroll
    for (int w2 = 1; w2 < 8; w2++) d += redl[w2 * QB + ql];
    inv[j] = 1.f / d;
  }

  {
    int qrow = tid >> 5, cb = (tid & 31) * 8;
    float dsum = redl[qrow];
    #pragma unroll
    for (int w2 = 1; w2 < 8; w2++) dsum += redl[w2 * QB + qrow];
    float invr = 1.f / dsum;
    float* mrow = map + (size_t)(h * LQ + q0 + qrow) * LQ;
    #pragma unroll
    for (int it = 0; it < 8; it++){
      u16x8 pv = *(u16x8*)&RP[it * SLABU + qrow * PSTR + cb];
      f32x4 o0, o1;
      #pragma unroll
      for (int j = 0; j < 4; j++){
        o0[j] = bf2f(pv[j]) * invr;
        o1[j] = bf2f(pv[4 + j]) * invr;
      }
      int c = cb + it * 256;
      __builtin_nontemporal_store(o0, (f32x4*)(mrow + c));
      __builtin_nontemporal_store(o1, (f32x4*)(mrow + c + 4));
    }
  }

  __builtin_amdgcn_s_setprio(1);
  f32x4 o[4] = {};
  #pragma unroll
  for (int kc2 = 0; kc2 < 8; kc2++){
    u16x8 pa = *(u16x8*)&slab[lr * PSTR + kc2 * 32 + lg * 8];
    #pragma unroll
    for (int ni = 0; ni < 4; ni++){
      u16x8 vv = *(const u16x8*)(vt + (size_t)(h * DH + ni * 16 + lr) * LQ + kb + kc2 * 32 + lg * 8);
      o[ni] = MFMA(pa, vv, o[ni]);
    }
  }
  __builtin_amdgcn_s_setprio(0);
  __syncthreads();

  float* Op = (float*)smem;
  #pragma unroll
  for (int ni = 0; ni < 4; ni++)
    #pragma unroll
    for (int j = 0; j < 4; j++)
      Op[(w * QB + lg * 4 + j) * 64 + ni * 16 + lr] = o[ni][j] * inv[j];
  __syncthreads();
  {
    int q = tid >> 5, dg = (tid & 31) * 2;
    float acc0 = 0.f, acc1 = 0.f;
    #pragma unroll
    for (int w2 = 0; w2 < 8; w2++){
      acc0 += Op[(w2 * QB + q) * 64 + dg];
      acc1 += Op[(w2 * QB + q) * 64 + dg + 1];
    }
    unsigned pk = (unsigned)f2bf(acc0) | ((unsigned)f2bf(acc1) << 16);
    *(unsigned*)(att + (size_t)(q0 + q) * DM + h * DH + dg) = pk;
  }
}

extern "C" void kernel_launch(void* const* d_in, const int* in_sizes, int n_in,
                              void* d_out, int out_size, void* d_ws, size_t ws_size,
                              hipStream_t stream){
  const float* v_in = (const float*)d_in[0];
  const float* k_in = (const float*)d_in[1];
  const float* q_in = (const float*)d_in[2];
  const int*   mask = (const int*)d_in[3];
  const float* Wq   = (const float*)d_in[4];
  const float* Wk   = (const float*)d_in[5];
  const float* Wv   = (const float*)d_in[6];
  const float* Wrk  = (const float*)d_in[7];
  const float* r_w  = (const float*)d_in[8];
  const float* r_r  = (const float*)d_in[9];
  const float* Wo   = (const float*)d_in[10];
  const float* bo   = (const float*)d_in[11];

  char* ws = (char*)d_ws;
  u16* qh  = (u16*)(ws + 0);             // [12][2048][64] bf16
  u16* kh  = (u16*)(ws + 3145728);
  u16* vt  = (u16*)(ws + 6291456);       // [12][64][2048] bf16
  u16* rk  = (u16*)(ws + 9437184);       // [12][4095][64] bf16
  u16* qb  = (u16*)(ws + 15728640);      // [2048][768] bf16 inputs
  u16* kb  = (u16*)(ws + 18874368);
  u16* vb  = (u16*)(ws + 22020096);
  u16* WqT = (u16*)(ws + 25165824);      // [768][768] bf16 transposed weights
  u16* WkT = (u16*)(ws + 26345472);
  u16* WvT = (u16*)(ws + 27525120);
  u16* WrkT= (u16*)(ws + 28704768);
  u16* WoT = (u16*)(ws + 29884416);
  u16* peb = (u16*)(ws + 31064064);      // [4095][768] bf16
  u16* att = (u16*)(ws + 37355520);      // [2048][768] bf16
  float* gamtab = (float*)(ws + 43646976);
  unsigned* gmax = (unsigned*)(ws + 44695552);
  double* logx = (double*)(ws + 44695616);
  double* Cf   = (double*)(ws + 44712000);

  float* out0 = (float*)d_out;                     // [2048][768] f32
  float* map  = out0 + (size_t)LQ * DM;            // [12][2048][2048] f32

  hipMemsetAsync(gmax, 0, 4, stream);
  prep_kernel<<<dim3(3032), 256, 0, stream>>>(q_in, k_in, v_in,
                                              Wq, Wk, Wv, Wrk, Wo,
                                              qb, kb, vb,
                                              WqT, WkT, WvT, WrkT, WoT,
                                              logx, Cf);
  gamma_probs_kernel<<<1024, 256, 0, stream>>>(logx, Cf, gamtab, gmax);
  pe_kernel<<<(NR * DM + 255) / 256, 256, 0, stream>>>(gamtab, gmax, peb);

  proj128_kernel<<<dim3(480), 256, 0, stream>>>(qb, kb, vb, peb,
                                                WqT, WkT, WvT, WrkT,
                                                qh, kh, vt, rk);

  hipFuncSetAttribute((const void*)attn_kernel,
                      hipFuncAttributeMaxDynamicSharedMemorySize, SMEM_ATTN);
  attn_kernel<<<dim3((LQ / QB) * NH), 512, SMEM_ATTN, stream>>>(qh, kh, vt, rk, mask,
                                                                r_w, r_r, map, att);
  gemm_out_kernel<<<dim3(32, 12), 256, 0, stream>>>(att, WoT, out0, bo);
}

// Round 23
// 216.834 us; speedup vs baseline: 2.1925x; 1.2323x over previous
//
#include <hip/hip_runtime.h>
#include <hip/hip_bf16.h>
#include <math.h>

typedef unsigned short u16;
typedef __bf16 bf16x8_t __attribute__((ext_vector_type(8)));
typedef u16 u16x8 __attribute__((ext_vector_type(8)));
typedef u16 u16x4 __attribute__((ext_vector_type(4)));
typedef float f32x4 __attribute__((ext_vector_type(4)));

#define NH 12
#define LQ 2048
#define DM 768
#define DH 64
#define NR 4095           // 2L-1
#define LN2F 0.6931471805599453f

__device__ __forceinline__ u16 f2bf(float f){
  unsigned x = __float_as_uint(f);
  return (u16)((x + 0x7fffu + ((x >> 16) & 1u)) >> 16);   // RTNE
}
__device__ __forceinline__ float bf2f(u16 u){ return __uint_as_float(((unsigned)u) << 16); }

__device__ __forceinline__ f32x4 MFMA(u16x8 a, u16x8 b, f32x4 c){
  return __builtin_amdgcn_mfma_f32_16x16x32_bf16(
      __builtin_bit_cast(bf16x8_t, a), __builtin_bit_cast(bf16x8_t, b), c, 0, 0, 0);
}

// ---------------- merged prep: cvt q/k/v + transpose-cvt 5 weights + gamma tables
__launch_bounds__(256)
__global__ void prep_kernel(const float* q, const float* k, const float* v,
                            const float* W0, const float* W1, const float* W2,
                            const float* W3, const float* W4,
                            u16* qb, u16* kb, u16* vb,
                            u16* T0, u16* T1, u16* T2, u16* T3, u16* T4,
                            double* __restrict__ logx, double* __restrict__ Cf){
  __shared__ u16 tile[64 * 72];
  const int bid = blockIdx.x;
  const int t = threadIdx.x;
  if (bid < 2304){
    int z = bid / 768, b = bid - z * 768;
    const float* src = (z == 0) ? q : (z == 1) ? k : v;
    u16* dst = (z == 0) ? qb : (z == 1) ? kb : vb;
    int base = (b * 256 + t) * 8;
    f32x4 a0 = *(const f32x4*)(src + base);
    f32x4 a1 = *(const f32x4*)(src + base + 4);
    u16x8 o;
    #pragma unroll
    for (int j = 0; j < 4; j++){ o[j] = f2bf(a0[j]); o[4 + j] = f2bf(a1[j]); }
    *(u16x8*)(dst + base) = o;
  } else if (bid < 3024){
    int r = bid - 2304;
    int z = r / 144, rem = r - z * 144;
    int k0 = (rem % 12) * 64, n0 = (rem / 12) * 64;
    const float* W = (z == 0) ? W0 : (z == 1) ? W1 : (z == 2) ? W2 : (z == 3) ? W3 : W4;
    u16* T = (z == 0) ? T0 : (z == 1) ? T1 : (z == 2) ? T2 : (z == 3) ? T3 : T4;
    {
      int kr = t >> 2, ng = (t & 3) * 16;
      const float* p = W + (size_t)(k0 + kr) * DM + n0 + ng;
      u16x8 o0, o1;
      #pragma unroll
      for (int j = 0; j < 8; j++){ o0[j] = f2bf(p[j]); o1[j] = f2bf(p[8 + j]); }
      *(u16x8*)&tile[kr * 72 + ng] = o0;
      *(u16x8*)&tile[kr * 72 + ng + 8] = o1;
    }
    __syncthreads();
    {
      int nr = t >> 2, kg = (t & 3) * 16;
      u16x8 o0, o1;
      #pragma unroll
      for (int j = 0; j < 8; j++){
        o0[j] = tile[(kg + j) * 72 + nr];
        o1[j] = tile[(kg + j + 8) * 72 + nr];
      }
      u16* qp = T + (size_t)(n0 + nr) * DM + k0 + kg;
      *(u16x8*)qp = o0;
      *(u16x8*)(qp + 8) = o1;
    }
  } else {
    int i = (bid - 3024) * 256 + t;
    if (i < 2048) logx[i] = (i > 0) ? log((double)i) : 0.0;
    if (i < 128){
      double fp1 = (double)(i + 1);
      double conc = 4.0 * fp1 * fp1;
      double rate = 0.25 * fp1;
      Cf[i] = conc * log(rate) - lgamma(conc);
    }
  }
}

// ---------------- gamma pdf table + global max (f64 arg, f32 exp) ----------
__global__ void gamma_probs_kernel(const double* __restrict__ logx,
                                   const double* __restrict__ Cf,
                                   float* __restrict__ gamtab,
                                   unsigned* __restrict__ gmax){
  int idx = blockIdx.x * 256 + threadIdx.x;   // 2048*128
  int x = idx >> 7, f = idx & 127;
  double fp1 = (double)(f + 1);
  double conc = 4.0 * fp1 * fp1;
  double rate = 0.25 * fp1;
  double xl = (x > 0) ? (conc - 1.0) * logx[x] : 0.0;   // xlogy(a,0)=0
  double logp = xl - rate * (double)x + Cf[f];
  float p = __expf((float)logp);
  gamtab[idx] = p;
  float m = p;
  #pragma unroll
  for (int off = 1; off < 64; off <<= 1) m = fmaxf(m, __shfl_xor(m, off));
  if ((threadIdx.x & 63) == 0) atomicMax(gmax, __float_as_uint(m));
}

// ---------------- positional encodings -> bf16 peb[4095][768] ----------------
__global__ void pe_kernel(const float* __restrict__ gamtab,
                          const unsigned* __restrict__ gmax,
                          u16* __restrict__ peb){
  int idx = blockIdx.x * 256 + threadIdx.x;
  if (idx >= NR * DM) return;
  int p = idx / DM;
  int c = idx - p * DM;
  int f = c & 127;
  int kind = c >> 7;
  int pos = p - (LQ - 1);
  int apos = pos < 0 ? -pos : pos;
  float sgn = (pos > 0) ? 1.f : ((pos < 0) ? -1.f : 0.f);
  float v;
  int grp = kind >> 1;
  if (grp == 0){
    float hl = exp2f(3.f + 8.f * (float)f / 127.f);
    v = expf(-(LN2F / hl) * (float)apos);
  } else if (grp == 1){
    float cw = exp2f((float)(f + 1)) - 1.f;
    v = (cw > (float)apos) ? 1.f : 0.f;
  } else {
    float gm = __uint_as_float(*gmax);
    v = gamtab[apos * 128 + f] / gm;
  }
  if (kind & 1) v *= sgn;
  peb[idx] = f2bf(v);
}

// ---------------- merged 128x128-tile projections + rk GEMM, BK=64 (480 WGs) --
// Epilogues write FRAGMENT-MAJOR tiles [tile][kc][lane][8] so attn loads are
// lane-contiguous (1KB/instr, 1-2 L2 txns instead of 16).
// qhF/khF: [h][kt=128][kc=2][64][8]   (kt = LQ row / 16)
// rkF:     [h][rt=256][kc=2][64][8]   (rt = NR row / 16; row 4095 := row 4094)
// vtF:     [h][ni=4][kc=64][64][8]    (ni = d/16, kc = k/32)
#define ASTR 72
__launch_bounds__(256)
__global__ void proj128_kernel(const u16* __restrict__ qb, const u16* __restrict__ kb,
                               const u16* __restrict__ vb, const u16* __restrict__ peb,
                               const u16* __restrict__ WqT, const u16* __restrict__ WkT,
                               const u16* __restrict__ WvT, const u16* __restrict__ WrkT,
                               u16* __restrict__ qhF, u16* __restrict__ khF,
                               u16* __restrict__ vtF, u16* __restrict__ rkF){
  __shared__ u16 At[128 * ASTR];
  __shared__ u16 Wt[128 * ASTR];
  const int bid = blockIdx.x;
  int z, bx, by;
  if (bid < 288){ z = bid / 96; int t = bid - z * 96; bx = t & 15; by = t >> 4; }
  else          { z = 3; int t = bid - 288; bx = t & 31; by = t >> 5; }
  const u16* A  = (z == 0) ? qb : (z == 1) ? kb : (z == 2) ? vb : peb;
  const u16* WT = (z == 0) ? WqT : (z == 1) ? WkT : (z == 2) ? WvT : WrkT;
  const int m0 = bx * 128, n0 = by * 128;
  const int tid = threadIdx.x;
  const int w = tid >> 6, l = tid & 63, lr = l & 15, lg = l >> 4;
  const int moff = (w & 1) * 64, noff = (w >> 1) * 64;
  f32x4 acc[4][4] = {};
  const int srow = tid >> 1, sg = (tid & 1) * 32;
  for (int k0 = 0; k0 < DM; k0 += 64){
    {
      int m = m0 + srow;
      u16x8 a0 = {}, a1 = {}, a2 = {}, a3 = {};
      if (z < 3 || m < NR){
        const u16* ap = A + (size_t)m * DM + k0 + sg;
        a0 = *(const u16x8*)ap;
        a1 = *(const u16x8*)(ap + 8);
        a2 = *(const u16x8*)(ap + 16);
        a3 = *(const u16x8*)(ap + 24);
      }
      u16* sp = &At[srow * ASTR + sg];
      *(u16x8*)sp = a0;
      *(u16x8*)(sp + 8) = a1;
      *(u16x8*)(sp + 16) = a2;
      *(u16x8*)(sp + 24) = a3;
      const u16* wp = WT + (size_t)(n0 + srow) * DM + k0 + sg;
      u16* wq = &Wt[srow * ASTR + sg];
      *(u16x8*)wq = *(const u16x8*)wp;
      *(u16x8*)(wq + 8) = *(const u16x8*)(wp + 8);
      *(u16x8*)(wq + 16) = *(const u16x8*)(wp + 16);
      *(u16x8*)(wq + 24) = *(const u16x8*)(wp + 24);
    }
    __syncthreads();
    #pragma unroll
    for (int kc = 0; kc < 2; kc++){
      u16x8 af[4], bf[4];
      #pragma unroll
      for (int mi = 0; mi < 4; mi++)
        af[mi] = *(u16x8*)&At[(moff + mi * 16 + lr) * ASTR + kc * 32 + lg * 8];
      #pragma unroll
      for (int ni = 0; ni < 4; ni++)
        bf[ni] = *(u16x8*)&Wt[(noff + ni * 16 + lr) * ASTR + kc * 32 + lg * 8];
      #pragma unroll
      for (int mi = 0; mi < 4; mi++)
        #pragma unroll
        for (int ni = 0; ni < 4; ni++)
          acc[mi][ni] = MFMA(af[mi], bf[ni], acc[mi][ni]);
    }
    __syncthreads();
  }
  #pragma unroll
  for (int mi = 0; mi < 4; mi++)
    #pragma unroll
    for (int ni = 0; ni < 4; ni++)
      #pragma unroll
      for (int j = 0; j < 4; j++){
        int m = m0 + moff + mi * 16 + lg * 4 + j;
        int n = n0 + noff + ni * 16 + lr;
        int hh = n >> 6, d = n & 63;
        float val = acc[mi][ni][j];
        if (z == 0){
          size_t idx = ((((size_t)hh * 128 + (m >> 4)) * 2 + (d >> 5)) * 64
                        + ((d >> 3) & 3) * 16 + (m & 15)) * 8 + (d & 7);
          qhF[idx] = f2bf(val * 0.125f);
        } else if (z == 1){
          size_t idx = ((((size_t)hh * 128 + (m >> 4)) * 2 + (d >> 5)) * 64
                        + ((d >> 3) & 3) * 16 + (m & 15)) * 8 + (d & 7);
          khF[idx] = f2bf(val);
        } else if (z == 2){
          size_t idx = ((((size_t)hh * 4 + (d >> 4)) * 64 + (m >> 5)) * 64
                        + ((m >> 3) & 3) * 16 + (d & 15)) * 8 + (m & 7);
          vtF[idx] = f2bf(val);
        } else {
          if (m < NR){
            u16 bv = f2bf(val);
            size_t idx = ((((size_t)hh * 256 + (m >> 4)) * 2 + (d >> 5)) * 64
                          + ((d >> 3) & 3) * 16 + (m & 15)) * 8 + (d & 7);
            rkF[idx] = bv;
            if (m == NR - 1){
              size_t idx2 = ((((size_t)hh * 256 + 255) * 2 + (d >> 5)) * 64
                             + ((d >> 3) & 3) * 16 + 15) * 8 + (d & 7);
              rkF[idx2] = bv;   // phantom row 4095 := row 4094 (never gathered)
            }
          }
        }
      }
}

// ---------------- out-proj GEMM: bf16 att x WoT bf16, f32 out + bias ---------
#define GSTRB 72
__launch_bounds__(256)
__global__ void gemm_out_kernel(const u16* __restrict__ A, const u16* __restrict__ WT,
                                float* __restrict__ outf, const float* __restrict__ bias){
  __shared__ u16 At[64 * GSTRB];
  __shared__ u16 Wt[64 * GSTRB];
  const int m0 = blockIdx.x * 64, n0 = blockIdx.y * 64;
  const int tid = threadIdx.x;
  const int w = tid >> 6, l = tid & 63, lr = l & 15, lg = l >> 4;
  const int moff = (w & 1) * 32, noff = (w >> 1) * 32;
  f32x4 acc[2][2] = {};
  const int arow = tid >> 2, akg = (tid & 3) * 16;
  for (int k0 = 0; k0 < DM; k0 += 64){
    {
      const u16* ap = A + (size_t)(m0 + arow) * DM + k0 + akg;
      *(u16x8*)&At[arow * GSTRB + akg] = *(const u16x8*)ap;
      *(u16x8*)&At[arow * GSTRB + akg + 8] = *(const u16x8*)(ap + 8);
      const u16* wp = WT + (size_t)(n0 + arow) * DM + k0 + akg;
      *(u16x8*)&Wt[arow * GSTRB + akg] = *(const u16x8*)wp;
      *(u16x8*)&Wt[arow * GSTRB + akg + 8] = *(const u16x8*)(wp + 8);
    }
    __syncthreads();
    #pragma unroll
    for (int kc = 0; kc < 2; kc++){
      u16x8 af0 = *(u16x8*)&At[(moff + lr) * GSTRB + kc * 32 + lg * 8];
      u16x8 af1 = *(u16x8*)&At[(moff + 16 + lr) * GSTRB + kc * 32 + lg * 8];
      u16x8 bf0 = *(u16x8*)&Wt[(noff + lr) * GSTRB + kc * 32 + lg * 8];
      u16x8 bf1 = *(u16x8*)&Wt[(noff + 16 + lr) * GSTRB + kc * 32 + lg * 8];
      acc[0][0] = MFMA(af0, bf0, acc[0][0]);
      acc[0][1] = MFMA(af0, bf1, acc[0][1]);
      acc[1][0] = MFMA(af1, bf0, acc[1][0]);
      acc[1][1] = MFMA(af1, bf1, acc[1][1]);
    }
    __syncthreads();
  }
  #pragma unroll
  for (int mi = 0; mi < 2; mi++)
    #pragma unroll
    for (int ni = 0; ni < 2; ni++)
      #pragma unroll
      for (int j = 0; j < 4; j++){
        int m = m0 + moff + mi * 16 + lg * 4 + j;
        int n = n0 + noff + ni * 16 + lr;
        __builtin_nontemporal_store(acc[mi][ni][j] + bias[n], &outf[(size_t)m * DM + n]);
      }
}

// ---------------- fused rel-pos attention: fragment-major coalesced loads ----
#define QB 16
#define DSTR 16
#define DROWS 288
#define PSTR 264
#define SLABU (DROWS * DSTR)
#define SMEM_ATTN (8 * SLABU * 2 + 1024)
__launch_bounds__(512, 4)
__global__ void attn_kernel(const u16* __restrict__ qhF, const u16* __restrict__ khF,
                            const u16* __restrict__ vtF, const u16* __restrict__ rkF,
                            const int* __restrict__ mask,
                            const float* __restrict__ r_w, const float* __restrict__ r_r,
                            float* __restrict__ map, u16* __restrict__ att){
  extern __shared__ char smem[];
  u16* RP = (u16*)smem;
  float* redm = (float*)(smem + 8 * SLABU * 2);
  float* redl = redm + 128;
  const int bid = blockIdx.x;
  const int swz = (bid & 7) * 192 + (bid >> 3);
  const int h = swz >> 7, q0 = (swz & 127) * QB;
  const int tid = threadIdx.x, w = tid >> 6, l = tid & 63, lr = l & 15, lg = l >> 4;
  const int roff = (LQ - 1) - q0 - (QB - 1);   // 2032 - q0 (multiple of 16)
  const int kb = w * 256;
  const int kt0 = kb >> 4;                     // 16-row k-tile base for this wave
  const int rt0 = (roff + kb) >> 4;            // 16-row rk-tile base
  u16* slab = RP + w * SLABU;

  // A fragments (lane-contiguous tile reads)
  u16x8 a1[2], a2[2];
  #pragma unroll
  for (int kc = 0; kc < 2; kc++){
    u16x8 qv = *(const u16x8*)(qhF + ((((size_t)h * 128 + (q0 >> 4)) * 2 + kc) * 64 + l) * 8);
    #pragma unroll
    for (int j = 0; j < 8; j++){
      int d = kc * 32 + lg * 8 + j;
      float f = bf2f(qv[j]);
      a1[kc][j] = f2bf(f + r_w[h * DH + d]);
      a2[kc][j] = f2bf(f + r_r[h * DH + d]);
    }
  }

  unsigned mbits = 0;
  {
    #pragma unroll
    for (int i = 0; i < 4; i++){
      int nt = lg + 4 * i;
      int mv = mask[kb + nt * 16 + lr];
      mbits |= ((unsigned)(mv & 1)) << nt;
    }
    mbits |= __shfl_xor(mbits, 16);
    mbits |= __shfl_xor(mbits, 32);
  }

  __builtin_amdgcn_s_setprio(1);
  // band: 17 tiles, each = two 1KB lane-contiguous loads
  #pragma unroll 4
  for (int t = 0; t < 17; t++){
    const u16* rp = rkF + (((size_t)h * 256 + rt0 + t) * 2) * 512 + l * 8;
    u16x8 b0 = *(const u16x8*)(rp);
    u16x8 b1 = *(const u16x8*)(rp + 512);
    f32x4 racc = {};
    racc = MFMA(a2[0], b0, racc);
    racc = MFMA(a2[1], b1, racc);
    int lc = t * 16 + lr;
    #pragma unroll
    for (int j = 0; j < 4; j++){
      int ql = lg * 4 + j;
      slab[(lc + ql) * DSTR + ql] = f2bf(racc[j]);
    }
  }
  __asm__ volatile("s_waitcnt lgkmcnt(0)" ::: "memory");
  __builtin_amdgcn_sched_barrier(0);

  f32x4 s[16];
  #pragma unroll
  for (int nt = 0; nt < 16; nt++){
    const u16* kp = khF + (((size_t)h * 128 + kt0 + nt) * 2) * 512 + l * 8;
    u16x8 b0 = *(const u16x8*)(kp);
    u16x8 b1 = *(const u16x8*)(kp + 512);
    f32x4 sv = {};
    sv = MFMA(a1[0], b0, sv);
    sv = MFMA(a1[1], b1, sv);
    int mv = (mbits >> nt) & 1;
    u16x4 g = *(u16x4*)&slab[(nt * 16 + lr + (QB - 1)) * DSTR + lg * 4];
    #pragma unroll
    for (int j = 0; j < 4; j++){
      float x = sv[j] + bf2f(g[j]);
      sv[j] = mv ? -10000.f : x;
    }
    s[nt] = sv;
  }
  __builtin_amdgcn_s_setprio(0);

  float fm[4];
  #pragma unroll
  for (int j = 0; j < 4; j++){
    float mx = -3.0e38f;
    #pragma unroll
    for (int nt = 0; nt < 16; nt++) mx = fmaxf(mx, s[nt][j]);
    #pragma unroll
    for (int off = 1; off < 16; off <<= 1) mx = fmaxf(mx, __shfl_xor(mx, off));
    if (lr == 0) redm[w * QB + lg * 4 + j] = mx;
  }
  __syncthreads();
  #pragma unroll
  for (int j = 0; j < 4; j++){
    int ql = lg * 4 + j;
    float mx = redm[ql];
    #pragma unroll
    for (int w2 = 1; w2 < 8; w2++) mx = fmaxf(mx, redm[w2 * QB + ql]);
    fm[j] = mx;
  }

  float ls[4] = {0.f, 0.f, 0.f, 0.f};
  #pragma unroll
  for (int nt = 0; nt < 16; nt++)
    #pragma unroll
    for (int j = 0; j < 4; j++){
      float p = __expf(s[nt][j] - fm[j]);
      ls[j] += p;
      slab[(lg * 4 + j) * PSTR + nt * 16 + lr] = f2bf(p);
    }
  #pragma unroll
  for (int j = 0; j < 4; j++){
    float sum = ls[j];
    #pragma unroll
    for (int off = 1; off < 16; off <<= 1) sum += __shfl_xor(sum, off);
    if (lr == 0) redl[w * QB + lg * 4 + j] = sum;
  }
  __syncthreads();
  float inv[4];
  #pragma unroll
  for (int j = 0; j < 4; j++){
    int ql = lg * 4 + j;
    float d = redl[ql];
    #pragma unroll
    for (int w2 = 1; w2 < 8; w2++) d += redl[w2 * QB + ql];
    inv[j] = 1.f / d;
  }

  {
    int qrow = tid >> 5, cb = (tid & 31) * 8;
    float dsum = redl[qrow];
    #pragma unroll
    for (int w2 = 1; w2 < 8; w2++) dsum += redl[w2 * QB + qrow];
    float invr = 1.f / dsum;
    float* mrow = map + (size_t)(h * LQ + q0 + qrow) * LQ;
    #pragma unroll
    for (int it = 0; it < 8; it++){
      u16x8 pv = *(u16x8*)&RP[it * SLABU + qrow * PSTR + cb];
      f32x4 o0, o1;
      #pragma unroll
      for (int j = 0; j < 4; j++){
        o0[j] = bf2f(pv[j]) * invr;
        o1[j] = bf2f(pv[4 + j]) * invr;
      }
      int c = cb + it * 256;
      __builtin_nontemporal_store(o0, (f32x4*)(mrow + c));
      __builtin_nontemporal_store(o1, (f32x4*)(mrow + c + 4));
    }
  }

  __builtin_amdgcn_s_setprio(1);
  f32x4 o[4] = {};
  #pragma unroll
  for (int kc2 = 0; kc2 < 8; kc2++){
    u16x8 pa = *(u16x8*)&slab[lr * PSTR + kc2 * 32 + lg * 8];
    #pragma unroll
    for (int ni = 0; ni < 4; ni++){
      const u16* vp = vtF + ((((size_t)h * 4 + ni) * 64 + (kb >> 5) + kc2) * 64 + l) * 8;
      o[ni] = MFMA(pa, *(const u16x8*)vp, o[ni]);
    }
  }
  __builtin_amdgcn_s_setprio(0);
  __syncthreads();

  float* Op = (float*)smem;
  #pragma unroll
  for (int ni = 0; ni < 4; ni++)
    #pragma unroll
    for (int j = 0; j < 4; j++)
      Op[(w * QB + lg * 4 + j) * 64 + ni * 16 + lr] = o[ni][j] * inv[j];
  __syncthreads();
  {
    int q = tid >> 5, dg = (tid & 31) * 2;
    float acc0 = 0.f, acc1 = 0.f;
    #pragma unroll
    for (int w2 = 0; w2 < 8; w2++){
      acc0 += Op[(w2 * QB + q) * 64 + dg];
      acc1 += Op[(w2 * QB + q) * 64 + dg + 1];
    }
    unsigned pk = (unsigned)f2bf(acc0) | ((unsigned)f2bf(acc1) << 16);
    *(unsigned*)(att + (size_t)(q0 + q) * DM + h * DH + dg) = pk;
  }
}

extern "C" void kernel_launch(void* const* d_in, const int* in_sizes, int n_in,
                              void* d_out, int out_size, void* d_ws, size_t ws_size,
                              hipStream_t stream){
  const float* v_in = (const float*)d_in[0];
  const float* k_in = (const float*)d_in[1];
  const float* q_in = (const float*)d_in[2];
  const int*   mask = (const int*)d_in[3];
  const float* Wq   = (const float*)d_in[4];
  const float* Wk   = (const float*)d_in[5];
  const float* Wv   = (const float*)d_in[6];
  const float* Wrk  = (const float*)d_in[7];
  const float* r_w  = (const float*)d_in[8];
  const float* r_r  = (const float*)d_in[9];
  const float* Wo   = (const float*)d_in[10];
  const float* bo   = (const float*)d_in[11];

  char* ws = (char*)d_ws;
  u16* qhF = (u16*)(ws + 0);             // [12][128][2][64][8] bf16 fragment-major
  u16* khF = (u16*)(ws + 3145728);
  u16* vtF = (u16*)(ws + 6291456);       // [12][4][64][64][8]
  u16* rkF = (u16*)(ws + 9437184);       // [12][256][2][64][8]
  u16* qb  = (u16*)(ws + 15728640);      // [2048][768] bf16 inputs
  u16* kb  = (u16*)(ws + 18874368);
  u16* vb  = (u16*)(ws + 22020096);
  u16* WqT = (u16*)(ws + 25165824);      // [768][768] bf16 transposed weights
  u16* WkT = (u16*)(ws + 26345472);
  u16* WvT = (u16*)(ws + 27525120);
  u16* WrkT= (u16*)(ws + 28704768);
  u16* WoT = (u16*)(ws + 29884416);
  u16* peb = (u16*)(ws + 31064064);      // [4095][768] bf16
  u16* att = (u16*)(ws + 37355520);      // [2048][768] bf16
  float* gamtab = (float*)(ws + 43646976);
  unsigned* gmax = (unsigned*)(ws + 44695552);
  double* logx = (double*)(ws + 44695616);
  double* Cf   = (double*)(ws + 44712000);

  float* out0 = (float*)d_out;                     // [2048][768] f32
  float* map  = out0 + (size_t)LQ * DM;            // [12][2048][2048] f32

  hipMemsetAsync(gmax, 0, 4, stream);
  prep_kernel<<<dim3(3032), 256, 0, stream>>>(q_in, k_in, v_in,
                                              Wq, Wk, Wv, Wrk, Wo,
                                              qb, kb, vb,
                                              WqT, WkT, WvT, WrkT, WoT,
                                              logx, Cf);
  gamma_probs_kernel<<<1024, 256, 0, stream>>>(logx, Cf, gamtab, gmax);
  pe_kernel<<<(NR * DM + 255) / 256, 256, 0, stream>>>(gamtab, gmax, peb);

  proj128_kernel<<<dim3(480), 256, 0, stream>>>(qb, kb, vb, peb,
                                                WqT, WkT, WvT, WrkT,
                                                qhF, khF, vtF, rkF);

  hipFuncSetAttribute((const void*)attn_kernel,
                      hipFuncAttributeMaxDynamicSharedMemorySize, SMEM_ATTN);
  attn_kernel<<<dim3((LQ / QB) * NH), 512, SMEM_ATTN, stream>>>(qhF, khF, vtF, rkF, mask,
                                                                r_w, r_r, map, att);
  gemm_out_kernel<<<dim3(32, 12), 256, 0, stream>>>(att, WoT, out0, bo);
}